// Round 3
// baseline (216.739 us; speedup 1.0000x reference)
//
#include <hip/hip_runtime.h>

// MAB block, MFMA bf16, round 9: occupancy 2x for the latency-bound attention.
// r8 fixed L2-channel serialization (125->68us) but per-SIMD accounting shows
// ~2/3 of cycles are still latency stall (VALUBusy 23%, MfmaUtil 10%) at only
// 4 blocks/CU (grid 1024 = 50% max occupancy; VGPR=48 proves the compiler
// won't hold a reg pipeline, so bodies eat serialized L2 round-trips).
// r9: 16-row q-blocks, 4 waves = 4 key-quarters (512 keys / 16 bodies each),
// grid 2048 -> 8 blocks/CU, 32 waves/CU. Merge = 3-partial LDS reduction.
// L2 traffic unchanged (1.05GB, would hit ~27 TB/s at 38us, under the 34.5
// ceiling). Body, layouts, GEMMs all unchanged.

typedef float fx4 __attribute__((ext_vector_type(4)));
typedef short short8 __attribute__((ext_vector_type(8)));
typedef short shortx4 __attribute__((ext_vector_type(4)));
typedef unsigned int uint2v __attribute__((ext_vector_type(2)));

#define BB  4
#define NN  2048
#define DD  256
#define HH  4
#define DHH 64

__device__ __forceinline__ float bf2f(unsigned short u) {
    union { unsigned int i; float f; } v; v.i = ((unsigned int)u) << 16; return v.f;
}
__device__ __forceinline__ unsigned short f2bf(float f) {
    union { float f; unsigned int i; } v; v.f = f;
    unsigned int r = v.i + 0x7FFF + ((v.i >> 16) & 1);   // RNE
    return (unsigned short)(r >> 16);
}
__device__ __forceinline__ unsigned int fbits(float f) {
    union { float f; unsigned int i; } v; v.f = f; return v.i;
}
__device__ __forceinline__ unsigned int packbf(float lo, float hi) {
    unsigned int a = fbits(lo), b = fbits(hi);
    a = (a + 0x7FFF + ((a >> 16) & 1)) >> 16;
    b = (b + 0x7FFF + ((b >> 16) & 1)) & 0xFFFF0000u;
    return a | b;
}

// ---------------------------------------------------------------------------
// Weight prep: WT[n][k] = bf16(W[k][n]) for the 5 weight matrices (256x256).
// ---------------------------------------------------------------------------
__global__ __launch_bounds__(256) void wt_prep(
        const float* __restrict__ w0, const float* __restrict__ w1,
        const float* __restrict__ w2, const float* __restrict__ w3,
        const float* __restrict__ w4, unsigned short* __restrict__ dst) {
    __shared__ unsigned short T[64 * 73];
    const int tid = threadIdx.x;
    const int z = blockIdx.z;
    const float* W = (z == 0) ? w0 : (z == 1) ? w1 : (z == 2) ? w2 : (z == 3) ? w3 : w4;
    unsigned short* WT = dst + z * 65536;
    const int nb = blockIdx.x * 64, kb = blockIdx.y * 64;
    {
        int kl = tid >> 2, c0 = (tid & 3) * 16;
        const float* src = W + (size_t)(kb + kl) * DD + nb + c0;
#pragma unroll
        for (int i = 0; i < 16; ++i) T[kl * 73 + c0 + i] = f2bf(src[i]);
    }
    __syncthreads();
    {
        int nl = tid >> 2, k0 = (tid & 3) * 16;
        short8 o0, o1;
#pragma unroll
        for (int i = 0; i < 8; ++i) {
            o0[i] = (short)T[(k0 + i) * 73 + nl];
            o1[i] = (short)T[(k0 + 8 + i) * 73 + nl];
        }
        short8* d = (short8*)(WT + (size_t)(nb + nl) * DD + kb + k0);
        d[0] = o0; d[1] = o1;
    }
}

// ---------------------------------------------------------------------------
// V tile-transpose: VT2[bh][tile][d64][key32] <- Vp[b*2048+key][h*64+d].
// grid(128,4): b = bx>>5, keyb = (bx&31)*64 (2 tiles), hb = by.
// ---------------------------------------------------------------------------
__global__ __launch_bounds__(256) void vt_prep(
        const unsigned short* __restrict__ Vp, unsigned short* __restrict__ VT2) {
    __shared__ unsigned short T[64 * 73];
    const int tid = threadIdx.x;
    const int hb = blockIdx.y;
    const int b = blockIdx.x >> 5;
    const int keyb = (blockIdx.x & 31) * 64;
    const int bh = b * HH + hb;
    {
        int kl = tid >> 2, c0 = (tid & 3) * 16;
        const short8* src = (const short8*)(Vp + (size_t)(b * NN + keyb + kl) * DD + hb * DHH + c0);
        short8 v0 = src[0], v1 = src[1];
#pragma unroll
        for (int i = 0; i < 8; ++i) {
            T[kl * 73 + c0 + i]     = (unsigned short)v0[i];
            T[kl * 73 + c0 + 8 + i] = (unsigned short)v1[i];
        }
    }
    __syncthreads();
    {
        int dl = tid >> 2, k0 = (tid & 3) * 16;          // d row, key chunk (16)
        short8 o0, o1;
#pragma unroll
        for (int i = 0; i < 8; ++i) {
            o0[i] = (short)T[(k0 + i) * 73 + dl];
            o1[i] = (short)T[(k0 + 8 + i) * 73 + dl];
        }
        const int gkey = keyb + k0;                       // multiple of 16
        const int tl = gkey >> 5;                         // tile index
        const int kin = gkey & 31;                        // 0 or 16
        short8* d = (short8*)(VT2 + ((size_t)(bh * 64 + tl) * 64 + dl) * 32 + kin);
        d[0] = o0; d[1] = o1;
    }
}

// ---------------------------------------------------------------------------
// K tile-permute: KT[bh][tile][dhalf][key32][d32] <- Kp[b*2048+key][h*64+d].
// Pure 16B-chunk permutation; grid 1024 = bh*64 + tile, 256 threads.
// ---------------------------------------------------------------------------
__global__ __launch_bounds__(256) void kt_prep(
        const unsigned short* __restrict__ Kp, unsigned short* __restrict__ KT) {
    const int bh = blockIdx.x >> 6;
    const int tl = blockIdx.x & 63;
    const int b = bh >> 2, h = bh & 3;
    const int tid = threadIdx.x;
    const int key = tid >> 3, p = tid & 7;
    short8 v = *(const short8*)(Kp + (size_t)(b * NN + tl * 32 + key) * DD + h * DHH + p * 8);
    unsigned short* dst = KT + (size_t)(bh * 64 + tl) * 2048
                        + (p >> 2) * 1024 + key * 32 + (p & 3) * 8;
    *(short8*)dst = v;
}

// ---------------------------------------------------------------------------
// 32-row GEMM body: C[r0..r0+32, c-half] = A @ W + bias. 4 waves, wave =
// 32 rows x 32 cols. W-frags hoisted. AIN: 0 fp32 A, 1 bf16 A.
// EP: 0 bias->bf16, 1 relu->bf16.
// ---------------------------------------------------------------------------
template<int AIN, int EP>
__device__ __forceinline__ void gemm32_body(
        const void* __restrict__ Ain, const unsigned short* __restrict__ WT,
        const float* __restrict__ bias, void* __restrict__ Cout, int bx) {
    __shared__ unsigned short As[32 * 264];
    const int tid = threadIdx.x;
    const int lane = tid & 63, w = tid >> 6;
    const int l15 = lane & 15, quad = lane >> 4;
    const int r0 = (bx >> 1) * 32;
    const int c0w = (bx & 1) * 128 + w * 32;
    short8 wf[8][2];
#pragma unroll
    for (int kc = 0; kc < 8; ++kc)
#pragma unroll
        for (int dt = 0; dt < 2; ++dt)
            wf[kc][dt] = *(const short8*)(WT + (size_t)(c0w + dt * 16 + l15) * DD + kc * 32 + 8 * quad);
    float bv[2];
#pragma unroll
    for (int dt = 0; dt < 2; ++dt) bv[dt] = bias[c0w + dt * 16 + l15];
    {   // stage A tile (32 x 256) as bf16; thread: 32 elems
        int row = tid >> 3, c0 = (tid & 7) * 32;
        short8 o[4];
        if (AIN == 0) {
            const fx4* s4 = (const fx4*)((const float*)Ain + (size_t)(r0 + row) * DD + c0);
#pragma unroll
            for (int j = 0; j < 4; ++j) {
                fx4 v0 = s4[2 * j], v1 = s4[2 * j + 1];
#pragma unroll
                for (int i = 0; i < 4; ++i) {
                    o[j][i]     = (short)f2bf(v0[i]);
                    o[j][i + 4] = (short)f2bf(v1[i]);
                }
            }
        } else {
            const short8* s8 = (const short8*)((const unsigned short*)Ain + (size_t)(r0 + row) * DD + c0);
#pragma unroll
            for (int j = 0; j < 4; ++j) o[j] = s8[j];
        }
        short8* d = (short8*)(As + row * 264 + c0);
#pragma unroll
        for (int j = 0; j < 4; ++j) d[j] = o[j];
    }
    __syncthreads();
    fx4 acc[2][2];
#pragma unroll
    for (int mt = 0; mt < 2; ++mt)
#pragma unroll
        for (int dt = 0; dt < 2; ++dt) acc[mt][dt] = (fx4){0.f, 0.f, 0.f, 0.f};
#pragma unroll
    for (int kc = 0; kc < 8; ++kc) {
        short8 a0 = *(const short8*)(As + l15 * 264 + kc * 32 + 8 * quad);
        short8 a1 = *(const short8*)(As + (16 + l15) * 264 + kc * 32 + 8 * quad);
#pragma unroll
        for (int dt = 0; dt < 2; ++dt) {
            acc[0][dt] = __builtin_amdgcn_mfma_f32_16x16x32_bf16(a0, wf[kc][dt], acc[0][dt], 0, 0, 0);
            acc[1][dt] = __builtin_amdgcn_mfma_f32_16x16x32_bf16(a1, wf[kc][dt], acc[1][dt], 0, 0, 0);
        }
    }
#pragma unroll
    for (int mt = 0; mt < 2; ++mt)
#pragma unroll
        for (int r = 0; r < 4; ++r) {
            const size_t grow = r0 + mt * 16 + 4 * quad + r;
#pragma unroll
            for (int dt = 0; dt < 2; ++dt) {
                float v = acc[mt][dt][r] + bv[dt];
                if (EP == 1) v = fmaxf(v, 0.0f);
                ((unsigned short*)Cout)[grow * DD + c0w + dt * 16 + l15] = f2bf(v);
            }
        }
}

// Fused QKV projections: grid (512, 3); y selects {Q->Qp, K->Kp, K->Vp}.
__global__ __launch_bounds__(256, 4) void qkv_mfma(
        const float* __restrict__ Q, const float* __restrict__ K,
        const unsigned short* __restrict__ WT5,
        const float* __restrict__ bq, const float* __restrict__ bk,
        const float* __restrict__ bv,
        unsigned short* __restrict__ Qp, unsigned short* __restrict__ Kp,
        unsigned short* __restrict__ Vp) {
    const int z = blockIdx.y;
    const float* A = (z == 0) ? Q : K;
    const float* bias = (z == 0) ? bq : (z == 1) ? bk : bv;
    unsigned short* C = (z == 0) ? Qp : (z == 1) ? Kp : Vp;
    gemm32_body<0, 0>(A, WT5 + z * 65536, bias, C, blockIdx.x);
}

// FFN1: H1 = relu(O @ W1 + b1), O fp32.
__global__ __launch_bounds__(256, 4) void ffn1_mfma(
        const float* __restrict__ O, const unsigned short* __restrict__ WT1,
        const float* __restrict__ b1, unsigned short* __restrict__ H1) {
    gemm32_body<0, 1>(O, WT1, b1, H1, blockIdx.x);
}

// ---------------------------------------------------------------------------
// FFN2 + residual + LayerNorm fused: out = LN(R + A@W2 + b2), fp32 out.
// Block = 16 rows x 256 cols, 8 waves (wave = 16x32), W-frags hoisted.
// ---------------------------------------------------------------------------
__global__ __launch_bounds__(512, 4) void gemm_ffn2_ln(
        const unsigned short* __restrict__ Ain, const unsigned short* __restrict__ WT,
        const float* __restrict__ bias, const float* __restrict__ R,
        const float* __restrict__ g, const float* __restrict__ be,
        float* __restrict__ out) {
    __shared__ unsigned short As[16 * 264];
    __shared__ float lnb[2][8][16];
    const int tid = threadIdx.x;
    const int lane = tid & 63, w = tid >> 6;          // w in 0..7
    const int l15 = lane & 15, quad = lane >> 4;
    const int r0 = blockIdx.x * 16;
    const int c0w = w * 32;
    short8 wf[8][2];
#pragma unroll
    for (int kc = 0; kc < 8; ++kc)
#pragma unroll
        for (int dt = 0; dt < 2; ++dt)
            wf[kc][dt] = *(const short8*)(WT + (size_t)(c0w + dt * 16 + l15) * DD + kc * 32 + 8 * quad);
    float bv[2], gv[2], ev[2];
#pragma unroll
    for (int dt = 0; dt < 2; ++dt) {
        int col = c0w + dt * 16 + l15;
        bv[dt] = bias[col]; gv[dt] = g[col]; ev[dt] = be[col];
    }
    {   // stage A: 512 threads x 16B
        int row = tid >> 5, c0 = (tid & 31) * 8;
        *(short8*)(As + row * 264 + c0) = *(const short8*)(Ain + (size_t)(r0 + row) * DD + c0);
    }
    __syncthreads();
    fx4 acc[2];
#pragma unroll
    for (int i = 0; i < 2; ++i) acc[i] = (fx4){0.f, 0.f, 0.f, 0.f};
#pragma unroll
    for (int kc = 0; kc < 8; ++kc) {
        short8 a = *(const short8*)(As + l15 * 264 + kc * 32 + 8 * quad);
#pragma unroll
        for (int dt = 0; dt < 2; ++dt)
            acc[dt] = __builtin_amdgcn_mfma_f32_16x16x32_bf16(a, wf[kc][dt], acc[dt], 0, 0, 0);
    }
    float v[4][2], p1[4], p2[4];
#pragma unroll
    for (int r = 0; r < 4; ++r) {
        p1[r] = 0.f; p2[r] = 0.f;
        const size_t grow = r0 + 4 * quad + r;
#pragma unroll
        for (int dt = 0; dt < 2; ++dt) {
            float x = acc[dt][r] + bv[dt] + R[grow * DD + c0w + dt * 16 + l15];
            v[r][dt] = x; p1[r] += x; p2[r] += x * x;
        }
    }
#pragma unroll
    for (int r = 0; r < 4; ++r) {
#pragma unroll
        for (int off = 1; off <= 8; off <<= 1) {
            p1[r] += __shfl_xor(p1[r], off);
            p2[r] += __shfl_xor(p2[r], off);
        }
    }
    if (l15 == 0) {
#pragma unroll
        for (int r = 0; r < 4; ++r) {
            lnb[0][w][4 * quad + r] = p1[r];
            lnb[1][w][4 * quad + r] = p2[r];
        }
    }
    __syncthreads();
#pragma unroll
    for (int r = 0; r < 4; ++r) {
        const int row = 4 * quad + r;
        float s1 = 0.f, s2 = 0.f;
#pragma unroll
        for (int ww = 0; ww < 8; ++ww) { s1 += lnb[0][ww][row]; s2 += lnb[1][ww][row]; }
        float mean = s1 * (1.0f / 256.0f);
        float var  = s2 * (1.0f / 256.0f) - mean * mean;
        float rstd = rsqrtf(var + 1e-5f);
        const size_t grow = r0 + row;
#pragma unroll
        for (int dt = 0; dt < 2; ++dt)
            out[grow * DD + c0w + dt * 16 + l15] = (v[r][dt] - mean) * rstd * gv[dt] + ev[dt];
    }
}

// ---------------------------------------------------------------------------
// Flash attention, O^T form, no-max softmax (|s| <= ~2 by construction).
// r9: block = 16 q-rows, 4 waves = 4 key-quarters (kq in 0..3, 512 keys =
// 16 bodies each); grid 2048 -> 8 blocks/CU, 32 waves/CU for latency hiding.
// Per 32-key tile: S^T = K.Q^T (C col = q = l15) -> p = exp(s/8) per-thread
// -> pack -> XOR-swizzled LDS exchange -> od^T += V^T.P^T (od col = q).
// Merge: waves kq=0..2 park partial O^T/l in LDS; wave kq=3 reduces + writes.
// ---------------------------------------------------------------------------
__global__ __launch_bounds__(256, 8) void attn_mfma(
        const unsigned short* __restrict__ Qp, const unsigned short* __restrict__ KT,
        const unsigned short* __restrict__ VT2, float* __restrict__ Opre) {
    __shared__ unsigned int pbuf[4][256];     // per-wave P exchange, pitch 16 dw
    __shared__ float macc[3][16][68];         // kq 0..2 partial O^T [q][d]
    __shared__ float lbuf[3][16];             // kq 0..2 partial l    [q]
    const int tid = threadIdx.x;
    const int lane = tid & 63, w = tid >> 6;  // w = kq (key quarter)
    const int l15 = lane & 15, quad = lane >> 4;
    const int kq = w;
    const int gb = blockIdx.x;
    const int bh = ((gb & 7) << 1) | ((gb >> 10) & 1);  // XCD-locality swizzle
    const int qc = (gb >> 3) & 127;
    const int h  = bh & 3;
    const int b  = bh >> 2;
    const int qrow = qc * 16;
    const int sw = 4 * ((l15 >> 1) & 3);                // bank swizzle (per l15)

    short8 aq0, aq1;
    {
        const unsigned short* qptr = Qp + ((size_t)(b * NN + qrow + l15) * DD + h * DHH + 8 * quad);
        aq0 = *(const short8*)qptr;
        aq1 = *(const short8*)(qptr + 32);
    }
    fx4 od0 = (fx4){0.f, 0.f, 0.f, 0.f};
    fx4 od1 = (fx4){0.f, 0.f, 0.f, 0.f};
    fx4 od2 = (fx4){0.f, 0.f, 0.f, 0.f};
    fx4 od3 = (fx4){0.f, 0.f, 0.f, 0.f};
    float lsum = 0.0f;

    unsigned int* pw = &pbuf[w][0];
    const int wcol = (2 * quad) ^ sw;         // write cols (pairs t=2q,2q+1 / +8)
    const int rcol = (4 * quad) ^ sw;         // read col group (t=4Q..4Q+3)
    // per-(bh, key-quarter) tile bases, incl. per-lane offset l15*32 + 8*quad
    const unsigned short* kthead = KT  + ((size_t)(bh * 64) + kq * 16) * 2048 + l15 * 32 + 8 * quad;
    const unsigned short* vthead = VT2 + ((size_t)(bh * 64) + kq * 16) * 2048 + l15 * 32 + 8 * quad;

    // loop state: named registers only
    short8 ka0, ka1, ka2, ka3;     // K frags, buffer A
    short8 kb0, kb1, kb2, kb3;     // K frags, buffer B
    short8 v0, v1, v2, v3;         // V frags, current tile

#define PREF_K(K0, K1, K2, K3, T) do {                                        \
        const unsigned short* kb_ = kthead + (size_t)(T) * 2048;              \
        K0 = *(const short8*)(kb_);          /* keys l15,    d 8q..8q+7  */   \
        K1 = *(const short8*)(kb_ + 1024);   /* keys l15,    d 32+8q..   */   \
        K2 = *(const short8*)(kb_ + 512);    /* keys 16+l15, d 8q..      */   \
        K3 = *(const short8*)(kb_ + 1536);   /* keys 16+l15, d 32+8q..   */   \
    } while (0)

#define PREF_V(T) do {                                                        \
        const unsigned short* vb_ = vthead + (size_t)(T) * 2048;              \
        v0 = *(const short8*)(vb_);          /* d l15,    keys 8q..8q+7 */    \
        v1 = *(const short8*)(vb_ + 512);    /* d 16+l15                */    \
        v2 = *(const short8*)(vb_ + 1024);   /* d 32+l15                */    \
        v3 = *(const short8*)(vb_ + 1536);   /* d 48+l15                */    \
    } while (0)

#define BODY(CK0, CK1, CK2, CK3, NK0, NK1, NK2, NK3, T) do {                  \
        PREF_V(T);                            /* V for THIS tile (used last) */\
        const int tn_ = ((T) + 1 < 16) ? (T) + 1 : 15;                        \
        PREF_K(NK0, NK1, NK2, NK3, tn_);      /* K for NEXT tile */           \
        const fx4 z_ = (fx4){0.f, 0.f, 0.f, 0.f};                             \
        fx4 s0_ = __builtin_amdgcn_mfma_f32_16x16x32_bf16(CK0, aq0, z_, 0, 0, 0); \
        s0_     = __builtin_amdgcn_mfma_f32_16x16x32_bf16(CK1, aq1, s0_, 0, 0, 0); \
        fx4 s1_ = __builtin_amdgcn_mfma_f32_16x16x32_bf16(CK2, aq0, z_, 0, 0, 0); \
        s1_     = __builtin_amdgcn_mfma_f32_16x16x32_bf16(CK3, aq1, s1_, 0, 0, 0); \
        s0_[0] = __expf(s0_[0] * 0.125f); s0_[1] = __expf(s0_[1] * 0.125f);   \
        s0_[2] = __expf(s0_[2] * 0.125f); s0_[3] = __expf(s0_[3] * 0.125f);   \
        s1_[0] = __expf(s1_[0] * 0.125f); s1_[1] = __expf(s1_[1] * 0.125f);   \
        s1_[2] = __expf(s1_[2] * 0.125f); s1_[3] = __expf(s1_[3] * 0.125f);   \
        lsum += s0_[0] + s0_[1] + s0_[2] + s0_[3];                            \
        lsum += s1_[0] + s1_[1] + s1_[2] + s1_[3];                            \
        uint2v w1_ = (uint2v){packbf(s0_[0], s0_[1]), packbf(s0_[2], s0_[3])};\
        uint2v w2_ = (uint2v){packbf(s1_[0], s1_[1]), packbf(s1_[2], s1_[3])};\
        *(uint2v*)(pw + l15 * 16 + wcol)       = w1_;   /* pairs t=2q,2q+1 */ \
        *(uint2v*)(pw + l15 * 16 + (wcol ^ 8)) = w2_;   /* pairs t=8+2q..  */ \
        short8 bp_ = *(const short8*)(pw + l15 * 16 + rcol); /* keys 8q..+7 */\
        od0 = __builtin_amdgcn_mfma_f32_16x16x32_bf16(v0, bp_, od0, 0, 0, 0); \
        od1 = __builtin_amdgcn_mfma_f32_16x16x32_bf16(v1, bp_, od1, 0, 0, 0); \
        od2 = __builtin_amdgcn_mfma_f32_16x16x32_bf16(v2, bp_, od2, 0, 0, 0); \
        od3 = __builtin_amdgcn_mfma_f32_16x16x32_bf16(v3, bp_, od3, 0, 0, 0); \
    } while (0)

    PREF_K(ka0, ka1, ka2, ka3, 0);
    for (int tt = 0; tt < 8; ++tt) {
        BODY(ka0, ka1, ka2, ka3, kb0, kb1, kb2, kb3, 2 * tt);
        BODY(kb0, kb1, kb2, kb3, ka0, ka1, ka2, ka3, 2 * tt + 1);
    }
#undef BODY
#undef PREF_V
#undef PREF_K

    // per-q total l for this wave (sum over quads)
    lsum += __shfl_xor(lsum, 16);
    lsum += __shfl_xor(lsum, 32);
    // ---- merge the four key-quarters (plain adds; no max state) ----
    if (kq < 3) {
        *(fx4*)&macc[kq][l15][0 * 16 + 4 * quad] = od0;
        *(fx4*)&macc[kq][l15][1 * 16 + 4 * quad] = od1;
        *(fx4*)&macc[kq][l15][2 * 16 + 4 * quad] = od2;
        *(fx4*)&macc[kq][l15][3 * 16 + 4 * quad] = od3;
        if (quad == 0) lbuf[kq][l15] = lsum;
    }
    __syncthreads();
    if (kq == 3) {
        const float inv = 1.0f / (lsum + lbuf[0][l15] + lbuf[1][l15] + lbuf[2][l15]);
        const size_t grow = (size_t)(b * NN) + qrow + l15;
        float* obase = Opre + grow * DD + h * DHH;
        const unsigned short* qpb = Qp + grow * DD + h * DHH;
#define OUT_DT(DT, OD) do {                                                   \
        fx4 m0_ = *(const fx4*)&macc[0][l15][(DT) * 16 + 4 * quad];           \
        fx4 m1_ = *(const fx4*)&macc[1][l15][(DT) * 16 + 4 * quad];           \
        fx4 m2_ = *(const fx4*)&macc[2][l15][(DT) * 16 + 4 * quad];           \
        shortx4 rv_ = *(const shortx4*)(qpb + (DT) * 16 + 4 * quad);          \
        fx4 o_;                                                               \
        o_[0] = (OD[0] + m0_[0] + m1_[0] + m2_[0]) * inv + bf2f((unsigned short)rv_[0]); \
        o_[1] = (OD[1] + m0_[1] + m1_[1] + m2_[1]) * inv + bf2f((unsigned short)rv_[1]); \
        o_[2] = (OD[2] + m0_[2] + m1_[2] + m2_[2]) * inv + bf2f((unsigned short)rv_[2]); \
        o_[3] = (OD[3] + m0_[3] + m1_[3] + m2_[3]) * inv + bf2f((unsigned short)rv_[3]); \
        *(fx4*)(obase + (DT) * 16 + 4 * quad) = o_;                           \
    } while (0)
        OUT_DT(0, od0);
        OUT_DT(1, od1);
        OUT_DT(2, od2);
        OUT_DT(3, od3);
#undef OUT_DT
    }
}

// row LayerNorm: Y = LN(X)*g+be (fp32)
__global__ __launch_bounds__(64) void ln_rows(
        const float* __restrict__ X, const float* __restrict__ g,
        const float* __restrict__ be, float* __restrict__ Y) {
    const int lane = threadIdx.x;
    const size_t row = blockIdx.x;
    fx4 v = ((const fx4*)(X + row * DD))[lane];
    float s1 = v[0]+v[1]+v[2]+v[3];
    float s2 = v[0]*v[0]+v[1]*v[1]+v[2]*v[2]+v[3]*v[3];
#pragma unroll
    for (int off = 32; off >= 1; off >>= 1) {
        s1 += __shfl_xor(s1, off); s2 += __shfl_xor(s2, off);
    }
    float mean = s1 * (1.0f/256.0f);
    float var  = s2 * (1.0f/256.0f) - mean * mean;
    float rstd = rsqrtf(var + 1e-5f);
    fx4 gv = ((const fx4*)g)[lane];
    fx4 ev = ((const fx4*)be)[lane];
    fx4 o;
#pragma unroll
    for (int i = 0; i < 4; ++i) o[i] = (v[i]-mean)*rstd*gv[i] + ev[i];
    ((fx4*)(Y + row * DD))[lane] = o;
}

extern "C" void kernel_launch(void* const* d_in, const int* in_sizes, int n_in,
                              void* d_out, int out_size, void* d_ws, size_t ws_size,
                              hipStream_t stream) {
    (void)in_sizes; (void)n_in; (void)out_size; (void)ws_size;
    const float* Q     = (const float*)d_in[0];
    const float* K     = (const float*)d_in[1];
    const float* Wq    = (const float*)d_in[2];
    const float* bq    = (const float*)d_in[3];
    const float* Wk    = (const float*)d_in[4];
    const float* bk    = (const float*)d_in[5];
    const float* Wv    = (const float*)d_in[6];
    const float* bv    = (const float*)d_in[7];
    const float* W1    = (const float*)d_in[8];
    const float* b1    = (const float*)d_in[9];
    const float* W2    = (const float*)d_in[10];
    const float* b2    = (const float*)d_in[11];
    const float* g0    = (const float*)d_in[12];
    const float* beta0 = (const float*)d_in[13];
    const float* g1    = (const float*)d_in[14];
    const float* beta1 = (const float*)d_in[15];

    // Workspace: [0,4)Mi Qp bf16 (later H1 bf16); [4,8)Mi Kp; [8,12)Mi Vp
    // (reused as KT after vt_prep); [12,16)Mi VT2; [16,24)Mi Opre f32;
    // [24,32)Mi O f32; [32Mi,+640K) WT x5
    char* ws = (char*)d_ws;
    unsigned short* Qp  = (unsigned short*)(ws);
    unsigned short* Kp  = (unsigned short*)(ws + (4u  << 20));
    unsigned short* Vp  = (unsigned short*)(ws + (8u  << 20));
    unsigned short* KT  = Vp;                       // overlays Vp (dead after vt_prep)
    unsigned short* VT2 = (unsigned short*)(ws + (12u << 20));
    float*          Opre= (float*)(ws + (16u << 20));
    float*          O   = (float*)(ws + (24u << 20));
    unsigned short* WT5 = (unsigned short*)(ws + (32u << 20));
    unsigned short* H1  = Qp;
    float*          out = (float*)d_out;

    const unsigned short* WT1 = WT5 + 3 * 65536;
    const unsigned short* WT2 = WT5 + 4 * 65536;

    const int M = BB * NN;                        // 8192 rows

    wt_prep<<<dim3(4, 4, 5), 256, 0, stream>>>(Wq, Wk, Wv, W1, W2, WT5);
    qkv_mfma<<<dim3(M / 16, 3), 256, 0, stream>>>(Q, K, WT5, bq, bk, bv, Qp, Kp, Vp);
    vt_prep<<<dim3(128, 4), 256, 0, stream>>>(Vp, VT2);
    kt_prep<<<1024, 256, 0, stream>>>(Kp, KT);    // overwrites Vp slot (Vp dead)
    attn_mfma<<<BB * HH * (NN / 16), 256, 0, stream>>>(Qp, KT, VT2, Opre);
    ln_rows<<<M, 64, 0, stream>>>(Opre, g0, beta0, O);
    ffn1_mfma<<<M / 16, 256, 0, stream>>>(O, WT1, b1, H1);
    gemm_ffn2_ln<<<M / 16, 512, 0, stream>>>(H1, WT2, b2, O, g1, beta1, out);
}

// Round 4
// 214.532 us; speedup vs baseline: 1.0103x; 1.0103x over previous
//
#include <hip/hip_runtime.h>

// MAB block, MFMA bf16, round 10: r9 structure at 6 waves/EU (no spills).
// r9 post-mortem: occupancy rose 37->77% but __launch_bounds__(256,8) capped
// VGPR at 64 -> allocator spilled (VGPR_Count=32, WRITE_SIZE 8.2->20.5MB of
// scratch traffic, 184us first-dispatch scratch-init anomaly) -> net regress
// 68->77us. The allocator wants ~48-52 regs for this body (r8 evidence).
// r10: same 16-row/4-key-quarter kernel, launch_bounds (256,6) -> VGPR cap 85,
// 6 blocks/CU (LDS 17.4KB x 6 = 104KB < 160KB). One variable vs r9.

typedef float fx4 __attribute__((ext_vector_type(4)));
typedef short short8 __attribute__((ext_vector_type(8)));
typedef short shortx4 __attribute__((ext_vector_type(4)));
typedef unsigned int uint2v __attribute__((ext_vector_type(2)));

#define BB  4
#define NN  2048
#define DD  256
#define HH  4
#define DHH 64

__device__ __forceinline__ float bf2f(unsigned short u) {
    union { unsigned int i; float f; } v; v.i = ((unsigned int)u) << 16; return v.f;
}
__device__ __forceinline__ unsigned short f2bf(float f) {
    union { float f; unsigned int i; } v; v.f = f;
    unsigned int r = v.i + 0x7FFF + ((v.i >> 16) & 1);   // RNE
    return (unsigned short)(r >> 16);
}
__device__ __forceinline__ unsigned int fbits(float f) {
    union { float f; unsigned int i; } v; v.f = f; return v.i;
}
__device__ __forceinline__ unsigned int packbf(float lo, float hi) {
    unsigned int a = fbits(lo), b = fbits(hi);
    a = (a + 0x7FFF + ((a >> 16) & 1)) >> 16;
    b = (b + 0x7FFF + ((b >> 16) & 1)) & 0xFFFF0000u;
    return a | b;
}

// ---------------------------------------------------------------------------
// Weight prep: WT[n][k] = bf16(W[k][n]) for the 5 weight matrices (256x256).
// ---------------------------------------------------------------------------
__global__ __launch_bounds__(256) void wt_prep(
        const float* __restrict__ w0, const float* __restrict__ w1,
        const float* __restrict__ w2, const float* __restrict__ w3,
        const float* __restrict__ w4, unsigned short* __restrict__ dst) {
    __shared__ unsigned short T[64 * 73];
    const int tid = threadIdx.x;
    const int z = blockIdx.z;
    const float* W = (z == 0) ? w0 : (z == 1) ? w1 : (z == 2) ? w2 : (z == 3) ? w3 : w4;
    unsigned short* WT = dst + z * 65536;
    const int nb = blockIdx.x * 64, kb = blockIdx.y * 64;
    {
        int kl = tid >> 2, c0 = (tid & 3) * 16;
        const float* src = W + (size_t)(kb + kl) * DD + nb + c0;
#pragma unroll
        for (int i = 0; i < 16; ++i) T[kl * 73 + c0 + i] = f2bf(src[i]);
    }
    __syncthreads();
    {
        int nl = tid >> 2, k0 = (tid & 3) * 16;
        short8 o0, o1;
#pragma unroll
        for (int i = 0; i < 8; ++i) {
            o0[i] = (short)T[(k0 + i) * 73 + nl];
            o1[i] = (short)T[(k0 + 8 + i) * 73 + nl];
        }
        short8* d = (short8*)(WT + (size_t)(nb + nl) * DD + kb + k0);
        d[0] = o0; d[1] = o1;
    }
}

// ---------------------------------------------------------------------------
// V tile-transpose: VT2[bh][tile][d64][key32] <- Vp[b*2048+key][h*64+d].
// grid(128,4): b = bx>>5, keyb = (bx&31)*64 (2 tiles), hb = by.
// ---------------------------------------------------------------------------
__global__ __launch_bounds__(256) void vt_prep(
        const unsigned short* __restrict__ Vp, unsigned short* __restrict__ VT2) {
    __shared__ unsigned short T[64 * 73];
    const int tid = threadIdx.x;
    const int hb = blockIdx.y;
    const int b = blockIdx.x >> 5;
    const int keyb = (blockIdx.x & 31) * 64;
    const int bh = b * HH + hb;
    {
        int kl = tid >> 2, c0 = (tid & 3) * 16;
        const short8* src = (const short8*)(Vp + (size_t)(b * NN + keyb + kl) * DD + hb * DHH + c0);
        short8 v0 = src[0], v1 = src[1];
#pragma unroll
        for (int i = 0; i < 8; ++i) {
            T[kl * 73 + c0 + i]     = (unsigned short)v0[i];
            T[kl * 73 + c0 + 8 + i] = (unsigned short)v1[i];
        }
    }
    __syncthreads();
    {
        int dl = tid >> 2, k0 = (tid & 3) * 16;          // d row, key chunk (16)
        short8 o0, o1;
#pragma unroll
        for (int i = 0; i < 8; ++i) {
            o0[i] = (short)T[(k0 + i) * 73 + dl];
            o1[i] = (short)T[(k0 + 8 + i) * 73 + dl];
        }
        const int gkey = keyb + k0;                       // multiple of 16
        const int tl = gkey >> 5;                         // tile index
        const int kin = gkey & 31;                        // 0 or 16
        short8* d = (short8*)(VT2 + ((size_t)(bh * 64 + tl) * 64 + dl) * 32 + kin);
        d[0] = o0; d[1] = o1;
    }
}

// ---------------------------------------------------------------------------
// K tile-permute: KT[bh][tile][dhalf][key32][d32] <- Kp[b*2048+key][h*64+d].
// Pure 16B-chunk permutation; grid 1024 = bh*64 + tile, 256 threads.
// ---------------------------------------------------------------------------
__global__ __launch_bounds__(256) void kt_prep(
        const unsigned short* __restrict__ Kp, unsigned short* __restrict__ KT) {
    const int bh = blockIdx.x >> 6;
    const int tl = blockIdx.x & 63;
    const int b = bh >> 2, h = bh & 3;
    const int tid = threadIdx.x;
    const int key = tid >> 3, p = tid & 7;
    short8 v = *(const short8*)(Kp + (size_t)(b * NN + tl * 32 + key) * DD + h * DHH + p * 8);
    unsigned short* dst = KT + (size_t)(bh * 64 + tl) * 2048
                        + (p >> 2) * 1024 + key * 32 + (p & 3) * 8;
    *(short8*)dst = v;
}

// ---------------------------------------------------------------------------
// 32-row GEMM body: C[r0..r0+32, c-half] = A @ W + bias. 4 waves, wave =
// 32 rows x 32 cols. W-frags hoisted. AIN: 0 fp32 A, 1 bf16 A.
// EP: 0 bias->bf16, 1 relu->bf16.
// ---------------------------------------------------------------------------
template<int AIN, int EP>
__device__ __forceinline__ void gemm32_body(
        const void* __restrict__ Ain, const unsigned short* __restrict__ WT,
        const float* __restrict__ bias, void* __restrict__ Cout, int bx) {
    __shared__ unsigned short As[32 * 264];
    const int tid = threadIdx.x;
    const int lane = tid & 63, w = tid >> 6;
    const int l15 = lane & 15, quad = lane >> 4;
    const int r0 = (bx >> 1) * 32;
    const int c0w = (bx & 1) * 128 + w * 32;
    short8 wf[8][2];
#pragma unroll
    for (int kc = 0; kc < 8; ++kc)
#pragma unroll
        for (int dt = 0; dt < 2; ++dt)
            wf[kc][dt] = *(const short8*)(WT + (size_t)(c0w + dt * 16 + l15) * DD + kc * 32 + 8 * quad);
    float bv[2];
#pragma unroll
    for (int dt = 0; dt < 2; ++dt) bv[dt] = bias[c0w + dt * 16 + l15];
    {   // stage A tile (32 x 256) as bf16; thread: 32 elems
        int row = tid >> 3, c0 = (tid & 7) * 32;
        short8 o[4];
        if (AIN == 0) {
            const fx4* s4 = (const fx4*)((const float*)Ain + (size_t)(r0 + row) * DD + c0);
#pragma unroll
            for (int j = 0; j < 4; ++j) {
                fx4 v0 = s4[2 * j], v1 = s4[2 * j + 1];
#pragma unroll
                for (int i = 0; i < 4; ++i) {
                    o[j][i]     = (short)f2bf(v0[i]);
                    o[j][i + 4] = (short)f2bf(v1[i]);
                }
            }
        } else {
            const short8* s8 = (const short8*)((const unsigned short*)Ain + (size_t)(r0 + row) * DD + c0);
#pragma unroll
            for (int j = 0; j < 4; ++j) o[j] = s8[j];
        }
        short8* d = (short8*)(As + row * 264 + c0);
#pragma unroll
        for (int j = 0; j < 4; ++j) d[j] = o[j];
    }
    __syncthreads();
    fx4 acc[2][2];
#pragma unroll
    for (int mt = 0; mt < 2; ++mt)
#pragma unroll
        for (int dt = 0; dt < 2; ++dt) acc[mt][dt] = (fx4){0.f, 0.f, 0.f, 0.f};
#pragma unroll
    for (int kc = 0; kc < 8; ++kc) {
        short8 a0 = *(const short8*)(As + l15 * 264 + kc * 32 + 8 * quad);
        short8 a1 = *(const short8*)(As + (16 + l15) * 264 + kc * 32 + 8 * quad);
#pragma unroll
        for (int dt = 0; dt < 2; ++dt) {
            acc[0][dt] = __builtin_amdgcn_mfma_f32_16x16x32_bf16(a0, wf[kc][dt], acc[0][dt], 0, 0, 0);
            acc[1][dt] = __builtin_amdgcn_mfma_f32_16x16x32_bf16(a1, wf[kc][dt], acc[1][dt], 0, 0, 0);
        }
    }
#pragma unroll
    for (int mt = 0; mt < 2; ++mt)
#pragma unroll
        for (int r = 0; r < 4; ++r) {
            const size_t grow = r0 + mt * 16 + 4 * quad + r;
#pragma unroll
            for (int dt = 0; dt < 2; ++dt) {
                float v = acc[mt][dt][r] + bv[dt];
                if (EP == 1) v = fmaxf(v, 0.0f);
                ((unsigned short*)Cout)[grow * DD + c0w + dt * 16 + l15] = f2bf(v);
            }
        }
}

// Fused QKV projections: grid (512, 3); y selects {Q->Qp, K->Kp, K->Vp}.
__global__ __launch_bounds__(256, 4) void qkv_mfma(
        const float* __restrict__ Q, const float* __restrict__ K,
        const unsigned short* __restrict__ WT5,
        const float* __restrict__ bq, const float* __restrict__ bk,
        const float* __restrict__ bv,
        unsigned short* __restrict__ Qp, unsigned short* __restrict__ Kp,
        unsigned short* __restrict__ Vp) {
    const int z = blockIdx.y;
    const float* A = (z == 0) ? Q : K;
    const float* bias = (z == 0) ? bq : (z == 1) ? bk : bv;
    unsigned short* C = (z == 0) ? Qp : (z == 1) ? Kp : Vp;
    gemm32_body<0, 0>(A, WT5 + z * 65536, bias, C, blockIdx.x);
}

// FFN1: H1 = relu(O @ W1 + b1), O fp32.
__global__ __launch_bounds__(256, 4) void ffn1_mfma(
        const float* __restrict__ O, const unsigned short* __restrict__ WT1,
        const float* __restrict__ b1, unsigned short* __restrict__ H1) {
    gemm32_body<0, 1>(O, WT1, b1, H1, blockIdx.x);
}

// ---------------------------------------------------------------------------
// FFN2 + residual + LayerNorm fused: out = LN(R + A@W2 + b2), fp32 out.
// Block = 16 rows x 256 cols, 8 waves (wave = 16x32), W-frags hoisted.
// ---------------------------------------------------------------------------
__global__ __launch_bounds__(512, 4) void gemm_ffn2_ln(
        const unsigned short* __restrict__ Ain, const unsigned short* __restrict__ WT,
        const float* __restrict__ bias, const float* __restrict__ R,
        const float* __restrict__ g, const float* __restrict__ be,
        float* __restrict__ out) {
    __shared__ unsigned short As[16 * 264];
    __shared__ float lnb[2][8][16];
    const int tid = threadIdx.x;
    const int lane = tid & 63, w = tid >> 6;          // w in 0..7
    const int l15 = lane & 15, quad = lane >> 4;
    const int r0 = blockIdx.x * 16;
    const int c0w = w * 32;
    short8 wf[8][2];
#pragma unroll
    for (int kc = 0; kc < 8; ++kc)
#pragma unroll
        for (int dt = 0; dt < 2; ++dt)
            wf[kc][dt] = *(const short8*)(WT + (size_t)(c0w + dt * 16 + l15) * DD + kc * 32 + 8 * quad);
    float bv[2], gv[2], ev[2];
#pragma unroll
    for (int dt = 0; dt < 2; ++dt) {
        int col = c0w + dt * 16 + l15;
        bv[dt] = bias[col]; gv[dt] = g[col]; ev[dt] = be[col];
    }
    {   // stage A: 512 threads x 16B
        int row = tid >> 5, c0 = (tid & 31) * 8;
        *(short8*)(As + row * 264 + c0) = *(const short8*)(Ain + (size_t)(r0 + row) * DD + c0);
    }
    __syncthreads();
    fx4 acc[2];
#pragma unroll
    for (int i = 0; i < 2; ++i) acc[i] = (fx4){0.f, 0.f, 0.f, 0.f};
#pragma unroll
    for (int kc = 0; kc < 8; ++kc) {
        short8 a = *(const short8*)(As + l15 * 264 + kc * 32 + 8 * quad);
#pragma unroll
        for (int dt = 0; dt < 2; ++dt)
            acc[dt] = __builtin_amdgcn_mfma_f32_16x16x32_bf16(a, wf[kc][dt], acc[dt], 0, 0, 0);
    }
    float v[4][2], p1[4], p2[4];
#pragma unroll
    for (int r = 0; r < 4; ++r) {
        p1[r] = 0.f; p2[r] = 0.f;
        const size_t grow = r0 + 4 * quad + r;
#pragma unroll
        for (int dt = 0; dt < 2; ++dt) {
            float x = acc[dt][r] + bv[dt] + R[grow * DD + c0w + dt * 16 + l15];
            v[r][dt] = x; p1[r] += x; p2[r] += x * x;
        }
    }
#pragma unroll
    for (int r = 0; r < 4; ++r) {
#pragma unroll
        for (int off = 1; off <= 8; off <<= 1) {
            p1[r] += __shfl_xor(p1[r], off);
            p2[r] += __shfl_xor(p2[r], off);
        }
    }
    if (l15 == 0) {
#pragma unroll
        for (int r = 0; r < 4; ++r) {
            lnb[0][w][4 * quad + r] = p1[r];
            lnb[1][w][4 * quad + r] = p2[r];
        }
    }
    __syncthreads();
#pragma unroll
    for (int r = 0; r < 4; ++r) {
        const int row = 4 * quad + r;
        float s1 = 0.f, s2 = 0.f;
#pragma unroll
        for (int ww = 0; ww < 8; ++ww) { s1 += lnb[0][ww][row]; s2 += lnb[1][ww][row]; }
        float mean = s1 * (1.0f / 256.0f);
        float var  = s2 * (1.0f / 256.0f) - mean * mean;
        float rstd = rsqrtf(var + 1e-5f);
        const size_t grow = r0 + row;
#pragma unroll
        for (int dt = 0; dt < 2; ++dt)
            out[grow * DD + c0w + dt * 16 + l15] = (v[r][dt] - mean) * rstd * gv[dt] + ev[dt];
    }
}

// ---------------------------------------------------------------------------
// Flash attention, O^T form, no-max softmax (|s| <= ~2 by construction).
// Block = 16 q-rows, 4 waves = 4 key-quarters (kq in 0..3, 512 keys =
// 16 bodies each); grid 2048, 6 blocks/CU (launch_bounds 256,6 -> VGPR cap 85,
// allocator needs ~48-52 -> no spill, unlike r9's (256,8) cap-64 spill).
// Per 32-key tile: S^T = K.Q^T (C col = q = l15) -> p = exp(s/8) per-thread
// -> pack -> XOR-swizzled LDS exchange -> od^T += V^T.P^T (od col = q).
// Merge: waves kq=0..2 park partial O^T/l in LDS; wave kq=3 reduces + writes.
// ---------------------------------------------------------------------------
__global__ __launch_bounds__(256, 6) void attn_mfma(
        const unsigned short* __restrict__ Qp, const unsigned short* __restrict__ KT,
        const unsigned short* __restrict__ VT2, float* __restrict__ Opre) {
    __shared__ unsigned int pbuf[4][256];     // per-wave P exchange, pitch 16 dw
    __shared__ float macc[3][16][68];         // kq 0..2 partial O^T [q][d]
    __shared__ float lbuf[3][16];             // kq 0..2 partial l    [q]
    const int tid = threadIdx.x;
    const int lane = tid & 63, w = tid >> 6;  // w = kq (key quarter)
    const int l15 = lane & 15, quad = lane >> 4;
    const int kq = w;
    const int gb = blockIdx.x;
    const int bh = ((gb & 7) << 1) | ((gb >> 10) & 1);  // XCD-locality swizzle
    const int qc = (gb >> 3) & 127;
    const int h  = bh & 3;
    const int b  = bh >> 2;
    const int qrow = qc * 16;
    const int sw = 4 * ((l15 >> 1) & 3);                // bank swizzle (per l15)

    short8 aq0, aq1;
    {
        const unsigned short* qptr = Qp + ((size_t)(b * NN + qrow + l15) * DD + h * DHH + 8 * quad);
        aq0 = *(const short8*)qptr;
        aq1 = *(const short8*)(qptr + 32);
    }
    fx4 od0 = (fx4){0.f, 0.f, 0.f, 0.f};
    fx4 od1 = (fx4){0.f, 0.f, 0.f, 0.f};
    fx4 od2 = (fx4){0.f, 0.f, 0.f, 0.f};
    fx4 od3 = (fx4){0.f, 0.f, 0.f, 0.f};
    float lsum = 0.0f;

    unsigned int* pw = &pbuf[w][0];
    const int wcol = (2 * quad) ^ sw;         // write cols (pairs t=2q,2q+1 / +8)
    const int rcol = (4 * quad) ^ sw;         // read col group (t=4Q..4Q+3)
    // per-(bh, key-quarter) tile bases, incl. per-lane offset l15*32 + 8*quad
    const unsigned short* kthead = KT  + ((size_t)(bh * 64) + kq * 16) * 2048 + l15 * 32 + 8 * quad;
    const unsigned short* vthead = VT2 + ((size_t)(bh * 64) + kq * 16) * 2048 + l15 * 32 + 8 * quad;

    // loop state: named registers only
    short8 ka0, ka1, ka2, ka3;     // K frags, buffer A
    short8 kb0, kb1, kb2, kb3;     // K frags, buffer B
    short8 v0, v1, v2, v3;         // V frags, current tile

#define PREF_K(K0, K1, K2, K3, T) do {                                        \
        const unsigned short* kb_ = kthead + (size_t)(T) * 2048;              \
        K0 = *(const short8*)(kb_);          /* keys l15,    d 8q..8q+7  */   \
        K1 = *(const short8*)(kb_ + 1024);   /* keys l15,    d 32+8q..   */   \
        K2 = *(const short8*)(kb_ + 512);    /* keys 16+l15, d 8q..      */   \
        K3 = *(const short8*)(kb_ + 1536);   /* keys 16+l15, d 32+8q..   */   \
    } while (0)

#define PREF_V(T) do {                                                        \
        const unsigned short* vb_ = vthead + (size_t)(T) * 2048;              \
        v0 = *(const short8*)(vb_);          /* d l15,    keys 8q..8q+7 */    \
        v1 = *(const short8*)(vb_ + 512);    /* d 16+l15                */    \
        v2 = *(const short8*)(vb_ + 1024);   /* d 32+l15                */    \
        v3 = *(const short8*)(vb_ + 1536);   /* d 48+l15                */    \
    } while (0)

#define BODY(CK0, CK1, CK2, CK3, NK0, NK1, NK2, NK3, T) do {                  \
        PREF_V(T);                            /* V for THIS tile (used last) */\
        const int tn_ = ((T) + 1 < 16) ? (T) + 1 : 15;                        \
        PREF_K(NK0, NK1, NK2, NK3, tn_);      /* K for NEXT tile */           \
        const fx4 z_ = (fx4){0.f, 0.f, 0.f, 0.f};                             \
        fx4 s0_ = __builtin_amdgcn_mfma_f32_16x16x32_bf16(CK0, aq0, z_, 0, 0, 0); \
        s0_     = __builtin_amdgcn_mfma_f32_16x16x32_bf16(CK1, aq1, s0_, 0, 0, 0); \
        fx4 s1_ = __builtin_amdgcn_mfma_f32_16x16x32_bf16(CK2, aq0, z_, 0, 0, 0); \
        s1_     = __builtin_amdgcn_mfma_f32_16x16x32_bf16(CK3, aq1, s1_, 0, 0, 0); \
        s0_[0] = __expf(s0_[0] * 0.125f); s0_[1] = __expf(s0_[1] * 0.125f);   \
        s0_[2] = __expf(s0_[2] * 0.125f); s0_[3] = __expf(s0_[3] * 0.125f);   \
        s1_[0] = __expf(s1_[0] * 0.125f); s1_[1] = __expf(s1_[1] * 0.125f);   \
        s1_[2] = __expf(s1_[2] * 0.125f); s1_[3] = __expf(s1_[3] * 0.125f);   \
        lsum += s0_[0] + s0_[1] + s0_[2] + s0_[3];                            \
        lsum += s1_[0] + s1_[1] + s1_[2] + s1_[3];                            \
        uint2v w1_ = (uint2v){packbf(s0_[0], s0_[1]), packbf(s0_[2], s0_[3])};\
        uint2v w2_ = (uint2v){packbf(s1_[0], s1_[1]), packbf(s1_[2], s1_[3])};\
        *(uint2v*)(pw + l15 * 16 + wcol)       = w1_;   /* pairs t=2q,2q+1 */ \
        *(uint2v*)(pw + l15 * 16 + (wcol ^ 8)) = w2_;   /* pairs t=8+2q..  */ \
        short8 bp_ = *(const short8*)(pw + l15 * 16 + rcol); /* keys 8q..+7 */\
        od0 = __builtin_amdgcn_mfma_f32_16x16x32_bf16(v0, bp_, od0, 0, 0, 0); \
        od1 = __builtin_amdgcn_mfma_f32_16x16x32_bf16(v1, bp_, od1, 0, 0, 0); \
        od2 = __builtin_amdgcn_mfma_f32_16x16x32_bf16(v2, bp_, od2, 0, 0, 0); \
        od3 = __builtin_amdgcn_mfma_f32_16x16x32_bf16(v3, bp_, od3, 0, 0, 0); \
    } while (0)

    PREF_K(ka0, ka1, ka2, ka3, 0);
    for (int tt = 0; tt < 8; ++tt) {
        BODY(ka0, ka1, ka2, ka3, kb0, kb1, kb2, kb3, 2 * tt);
        BODY(kb0, kb1, kb2, kb3, ka0, ka1, ka2, ka3, 2 * tt + 1);
    }
#undef BODY
#undef PREF_V
#undef PREF_K

    // per-q total l for this wave (sum over quads)
    lsum += __shfl_xor(lsum, 16);
    lsum += __shfl_xor(lsum, 32);
    // ---- merge the four key-quarters (plain adds; no max state) ----
    if (kq < 3) {
        *(fx4*)&macc[kq][l15][0 * 16 + 4 * quad] = od0;
        *(fx4*)&macc[kq][l15][1 * 16 + 4 * quad] = od1;
        *(fx4*)&macc[kq][l15][2 * 16 + 4 * quad] = od2;
        *(fx4*)&macc[kq][l15][3 * 16 + 4 * quad] = od3;
        if (quad == 0) lbuf[kq][l15] = lsum;
    }
    __syncthreads();
    if (kq == 3) {
        const float inv = 1.0f / (lsum + lbuf[0][l15] + lbuf[1][l15] + lbuf[2][l15]);
        const size_t grow = (size_t)(b * NN) + qrow + l15;
        float* obase = Opre + grow * DD + h * DHH;
        const unsigned short* qpb = Qp + grow * DD + h * DHH;
#define OUT_DT(DT, OD) do {                                                   \
        fx4 m0_ = *(const fx4*)&macc[0][l15][(DT) * 16 + 4 * quad];           \
        fx4 m1_ = *(const fx4*)&macc[1][l15][(DT) * 16 + 4 * quad];           \
        fx4 m2_ = *(const fx4*)&macc[2][l15][(DT) * 16 + 4 * quad];           \
        shortx4 rv_ = *(const shortx4*)(qpb + (DT) * 16 + 4 * quad);          \
        fx4 o_;                                                               \
        o_[0] = (OD[0] + m0_[0] + m1_[0] + m2_[0]) * inv + bf2f((unsigned short)rv_[0]); \
        o_[1] = (OD[1] + m0_[1] + m1_[1] + m2_[1]) * inv + bf2f((unsigned short)rv_[1]); \
        o_[2] = (OD[2] + m0_[2] + m1_[2] + m2_[2]) * inv + bf2f((unsigned short)rv_[2]); \
        o_[3] = (OD[3] + m0_[3] + m1_[3] + m2_[3]) * inv + bf2f((unsigned short)rv_[3]); \
        *(fx4*)(obase + (DT) * 16 + 4 * quad) = o_;                           \
    } while (0)
        OUT_DT(0, od0);
        OUT_DT(1, od1);
        OUT_DT(2, od2);
        OUT_DT(3, od3);
#undef OUT_DT
    }
}

// row LayerNorm: Y = LN(X)*g+be (fp32)
__global__ __launch_bounds__(64) void ln_rows(
        const float* __restrict__ X, const float* __restrict__ g,
        const float* __restrict__ be, float* __restrict__ Y) {
    const int lane = threadIdx.x;
    const size_t row = blockIdx.x;
    fx4 v = ((const fx4*)(X + row * DD))[lane];
    float s1 = v[0]+v[1]+v[2]+v[3];
    float s2 = v[0]*v[0]+v[1]*v[1]+v[2]*v[2]+v[3]*v[3];
#pragma unroll
    for (int off = 32; off >= 1; off >>= 1) {
        s1 += __shfl_xor(s1, off); s2 += __shfl_xor(s2, off);
    }
    float mean = s1 * (1.0f/256.0f);
    float var  = s2 * (1.0f/256.0f) - mean * mean;
    float rstd = rsqrtf(var + 1e-5f);
    fx4 gv = ((const fx4*)g)[lane];
    fx4 ev = ((const fx4*)be)[lane];
    fx4 o;
#pragma unroll
    for (int i = 0; i < 4; ++i) o[i] = (v[i]-mean)*rstd*gv[i] + ev[i];
    ((fx4*)(Y + row * DD))[lane] = o;
}

extern "C" void kernel_launch(void* const* d_in, const int* in_sizes, int n_in,
                              void* d_out, int out_size, void* d_ws, size_t ws_size,
                              hipStream_t stream) {
    (void)in_sizes; (void)n_in; (void)out_size; (void)ws_size;
    const float* Q     = (const float*)d_in[0];
    const float* K     = (const float*)d_in[1];
    const float* Wq    = (const float*)d_in[2];
    const float* bq    = (const float*)d_in[3];
    const float* Wk    = (const float*)d_in[4];
    const float* bk    = (const float*)d_in[5];
    const float* Wv    = (const float*)d_in[6];
    const float* bv    = (const float*)d_in[7];
    const float* W1    = (const float*)d_in[8];
    const float* b1    = (const float*)d_in[9];
    const float* W2    = (const float*)d_in[10];
    const float* b2    = (const float*)d_in[11];
    const float* g0    = (const float*)d_in[12];
    const float* beta0 = (const float*)d_in[13];
    const float* g1    = (const float*)d_in[14];
    const float* beta1 = (const float*)d_in[15];

    // Workspace: [0,4)Mi Qp bf16 (later H1 bf16); [4,8)Mi Kp; [8,12)Mi Vp
    // (reused as KT after vt_prep); [12,16)Mi VT2; [16,24)Mi Opre f32;
    // [24,32)Mi O f32; [32Mi,+640K) WT x5
    char* ws = (char*)d_ws;
    unsigned short* Qp  = (unsigned short*)(ws);
    unsigned short* Kp  = (unsigned short*)(ws + (4u  << 20));
    unsigned short* Vp  = (unsigned short*)(ws + (8u  << 20));
    unsigned short* KT  = Vp;                       // overlays Vp (dead after vt_prep)
    unsigned short* VT2 = (unsigned short*)(ws + (12u << 20));
    float*          Opre= (float*)(ws + (16u << 20));
    float*          O   = (float*)(ws + (24u << 20));
    unsigned short* WT5 = (unsigned short*)(ws + (32u << 20));
    unsigned short* H1  = Qp;
    float*          out = (float*)d_out;

    const unsigned short* WT1 = WT5 + 3 * 65536;
    const unsigned short* WT2 = WT5 + 4 * 65536;

    const int M = BB * NN;                        // 8192 rows

    wt_prep<<<dim3(4, 4, 5), 256, 0, stream>>>(Wq, Wk, Wv, W1, W2, WT5);
    qkv_mfma<<<dim3(M / 16, 3), 256, 0, stream>>>(Q, K, WT5, bq, bk, bv, Qp, Kp, Vp);
    vt_prep<<<dim3(128, 4), 256, 0, stream>>>(Vp, VT2);
    kt_prep<<<1024, 256, 0, stream>>>(Kp, KT);    // overwrites Vp slot (Vp dead)
    attn_mfma<<<BB * HH * (NN / 16), 256, 0, stream>>>(Qp, KT, VT2, Opre);
    ln_rows<<<M, 64, 0, stream>>>(Opre, g0, beta0, O);
    ffn1_mfma<<<M / 16, 256, 0, stream>>>(O, WT1, b1, H1);
    gemm_ffn2_ln<<<M / 16, 512, 0, stream>>>(H1, WT2, b2, O, g1, beta1, out);
}

// Round 5
// 204.855 us; speedup vs baseline: 1.0580x; 1.0472x over previous
//
#include <hip/hip_runtime.h>

// MAB block, MFMA bf16, round 11: grid-2048 structure + r8's register regime.
// r9/r10 post-mortem: ANY waves-per-eu hint >4 makes the allocator spill
// (r9: cap64/VGPR32/heavy; r10: cap85/VGPR40/5MB scratch + 41ms anomaly).
// But r8 proved this body allocates 48 VGPR when minimally constrained, and
// 48 VGPR ALREADY admits 8 blocks/CU in hardware (floor(512/48)=10 waves/EU,
// LDS 17.4KB*8=139KB<160KB). r9's occupancy shortfall was its register cap,
// not a hardware limit; r8's was its 1024-block grid.
// r11: 16-row/4-key-quarter kernel (grid 2048) with launch_bounds(256,4).
// Hardware occupancy comes from resource math, not from the hint.

typedef float fx4 __attribute__((ext_vector_type(4)));
typedef short short8 __attribute__((ext_vector_type(8)));
typedef short shortx4 __attribute__((ext_vector_type(4)));
typedef unsigned int uint2v __attribute__((ext_vector_type(2)));

#define BB  4
#define NN  2048
#define DD  256
#define HH  4
#define DHH 64

__device__ __forceinline__ float bf2f(unsigned short u) {
    union { unsigned int i; float f; } v; v.i = ((unsigned int)u) << 16; return v.f;
}
__device__ __forceinline__ unsigned short f2bf(float f) {
    union { float f; unsigned int i; } v; v.f = f;
    unsigned int r = v.i + 0x7FFF + ((v.i >> 16) & 1);   // RNE
    return (unsigned short)(r >> 16);
}
__device__ __forceinline__ unsigned int fbits(float f) {
    union { float f; unsigned int i; } v; v.f = f; return v.i;
}
__device__ __forceinline__ unsigned int packbf(float lo, float hi) {
    unsigned int a = fbits(lo), b = fbits(hi);
    a = (a + 0x7FFF + ((a >> 16) & 1)) >> 16;
    b = (b + 0x7FFF + ((b >> 16) & 1)) & 0xFFFF0000u;
    return a | b;
}

// ---------------------------------------------------------------------------
// Weight prep: WT[n][k] = bf16(W[k][n]) for the 5 weight matrices (256x256).
// ---------------------------------------------------------------------------
__global__ __launch_bounds__(256) void wt_prep(
        const float* __restrict__ w0, const float* __restrict__ w1,
        const float* __restrict__ w2, const float* __restrict__ w3,
        const float* __restrict__ w4, unsigned short* __restrict__ dst) {
    __shared__ unsigned short T[64 * 73];
    const int tid = threadIdx.x;
    const int z = blockIdx.z;
    const float* W = (z == 0) ? w0 : (z == 1) ? w1 : (z == 2) ? w2 : (z == 3) ? w3 : w4;
    unsigned short* WT = dst + z * 65536;
    const int nb = blockIdx.x * 64, kb = blockIdx.y * 64;
    {
        int kl = tid >> 2, c0 = (tid & 3) * 16;
        const float* src = W + (size_t)(kb + kl) * DD + nb + c0;
#pragma unroll
        for (int i = 0; i < 16; ++i) T[kl * 73 + c0 + i] = f2bf(src[i]);
    }
    __syncthreads();
    {
        int nl = tid >> 2, k0 = (tid & 3) * 16;
        short8 o0, o1;
#pragma unroll
        for (int i = 0; i < 8; ++i) {
            o0[i] = (short)T[(k0 + i) * 73 + nl];
            o1[i] = (short)T[(k0 + 8 + i) * 73 + nl];
        }
        short8* d = (short8*)(WT + (size_t)(nb + nl) * DD + kb + k0);
        d[0] = o0; d[1] = o1;
    }
}

// ---------------------------------------------------------------------------
// V tile-transpose: VT2[bh][tile][d64][key32] <- Vp[b*2048+key][h*64+d].
// grid(128,4): b = bx>>5, keyb = (bx&31)*64 (2 tiles), hb = by.
// ---------------------------------------------------------------------------
__global__ __launch_bounds__(256) void vt_prep(
        const unsigned short* __restrict__ Vp, unsigned short* __restrict__ VT2) {
    __shared__ unsigned short T[64 * 73];
    const int tid = threadIdx.x;
    const int hb = blockIdx.y;
    const int b = blockIdx.x >> 5;
    const int keyb = (blockIdx.x & 31) * 64;
    const int bh = b * HH + hb;
    {
        int kl = tid >> 2, c0 = (tid & 3) * 16;
        const short8* src = (const short8*)(Vp + (size_t)(b * NN + keyb + kl) * DD + hb * DHH + c0);
        short8 v0 = src[0], v1 = src[1];
#pragma unroll
        for (int i = 0; i < 8; ++i) {
            T[kl * 73 + c0 + i]     = (unsigned short)v0[i];
            T[kl * 73 + c0 + 8 + i] = (unsigned short)v1[i];
        }
    }
    __syncthreads();
    {
        int dl = tid >> 2, k0 = (tid & 3) * 16;          // d row, key chunk (16)
        short8 o0, o1;
#pragma unroll
        for (int i = 0; i < 8; ++i) {
            o0[i] = (short)T[(k0 + i) * 73 + dl];
            o1[i] = (short)T[(k0 + 8 + i) * 73 + dl];
        }
        const int gkey = keyb + k0;                       // multiple of 16
        const int tl = gkey >> 5;                         // tile index
        const int kin = gkey & 31;                        // 0 or 16
        short8* d = (short8*)(VT2 + ((size_t)(bh * 64 + tl) * 64 + dl) * 32 + kin);
        d[0] = o0; d[1] = o1;
    }
}

// ---------------------------------------------------------------------------
// K tile-permute: KT[bh][tile][dhalf][key32][d32] <- Kp[b*2048+key][h*64+d].
// Pure 16B-chunk permutation; grid 1024 = bh*64 + tile, 256 threads.
// ---------------------------------------------------------------------------
__global__ __launch_bounds__(256) void kt_prep(
        const unsigned short* __restrict__ Kp, unsigned short* __restrict__ KT) {
    const int bh = blockIdx.x >> 6;
    const int tl = blockIdx.x & 63;
    const int b = bh >> 2, h = bh & 3;
    const int tid = threadIdx.x;
    const int key = tid >> 3, p = tid & 7;
    short8 v = *(const short8*)(Kp + (size_t)(b * NN + tl * 32 + key) * DD + h * DHH + p * 8);
    unsigned short* dst = KT + (size_t)(bh * 64 + tl) * 2048
                        + (p >> 2) * 1024 + key * 32 + (p & 3) * 8;
    *(short8*)dst = v;
}

// ---------------------------------------------------------------------------
// 32-row GEMM body: C[r0..r0+32, c-half] = A @ W + bias. 4 waves, wave =
// 32 rows x 32 cols. W-frags hoisted. AIN: 0 fp32 A, 1 bf16 A.
// EP: 0 bias->bf16, 1 relu->bf16.
// ---------------------------------------------------------------------------
template<int AIN, int EP>
__device__ __forceinline__ void gemm32_body(
        const void* __restrict__ Ain, const unsigned short* __restrict__ WT,
        const float* __restrict__ bias, void* __restrict__ Cout, int bx) {
    __shared__ unsigned short As[32 * 264];
    const int tid = threadIdx.x;
    const int lane = tid & 63, w = tid >> 6;
    const int l15 = lane & 15, quad = lane >> 4;
    const int r0 = (bx >> 1) * 32;
    const int c0w = (bx & 1) * 128 + w * 32;
    short8 wf[8][2];
#pragma unroll
    for (int kc = 0; kc < 8; ++kc)
#pragma unroll
        for (int dt = 0; dt < 2; ++dt)
            wf[kc][dt] = *(const short8*)(WT + (size_t)(c0w + dt * 16 + l15) * DD + kc * 32 + 8 * quad);
    float bv[2];
#pragma unroll
    for (int dt = 0; dt < 2; ++dt) bv[dt] = bias[c0w + dt * 16 + l15];
    {   // stage A tile (32 x 256) as bf16; thread: 32 elems
        int row = tid >> 3, c0 = (tid & 7) * 32;
        short8 o[4];
        if (AIN == 0) {
            const fx4* s4 = (const fx4*)((const float*)Ain + (size_t)(r0 + row) * DD + c0);
#pragma unroll
            for (int j = 0; j < 4; ++j) {
                fx4 v0 = s4[2 * j], v1 = s4[2 * j + 1];
#pragma unroll
                for (int i = 0; i < 4; ++i) {
                    o[j][i]     = (short)f2bf(v0[i]);
                    o[j][i + 4] = (short)f2bf(v1[i]);
                }
            }
        } else {
            const short8* s8 = (const short8*)((const unsigned short*)Ain + (size_t)(r0 + row) * DD + c0);
#pragma unroll
            for (int j = 0; j < 4; ++j) o[j] = s8[j];
        }
        short8* d = (short8*)(As + row * 264 + c0);
#pragma unroll
        for (int j = 0; j < 4; ++j) d[j] = o[j];
    }
    __syncthreads();
    fx4 acc[2][2];
#pragma unroll
    for (int mt = 0; mt < 2; ++mt)
#pragma unroll
        for (int dt = 0; dt < 2; ++dt) acc[mt][dt] = (fx4){0.f, 0.f, 0.f, 0.f};
#pragma unroll
    for (int kc = 0; kc < 8; ++kc) {
        short8 a0 = *(const short8*)(As + l15 * 264 + kc * 32 + 8 * quad);
        short8 a1 = *(const short8*)(As + (16 + l15) * 264 + kc * 32 + 8 * quad);
#pragma unroll
        for (int dt = 0; dt < 2; ++dt) {
            acc[0][dt] = __builtin_amdgcn_mfma_f32_16x16x32_bf16(a0, wf[kc][dt], acc[0][dt], 0, 0, 0);
            acc[1][dt] = __builtin_amdgcn_mfma_f32_16x16x32_bf16(a1, wf[kc][dt], acc[1][dt], 0, 0, 0);
        }
    }
#pragma unroll
    for (int mt = 0; mt < 2; ++mt)
#pragma unroll
        for (int r = 0; r < 4; ++r) {
            const size_t grow = r0 + mt * 16 + 4 * quad + r;
#pragma unroll
            for (int dt = 0; dt < 2; ++dt) {
                float v = acc[mt][dt][r] + bv[dt];
                if (EP == 1) v = fmaxf(v, 0.0f);
                ((unsigned short*)Cout)[grow * DD + c0w + dt * 16 + l15] = f2bf(v);
            }
        }
}

// Fused QKV projections: grid (512, 3); y selects {Q->Qp, K->Kp, K->Vp}.
__global__ __launch_bounds__(256, 4) void qkv_mfma(
        const float* __restrict__ Q, const float* __restrict__ K,
        const unsigned short* __restrict__ WT5,
        const float* __restrict__ bq, const float* __restrict__ bk,
        const float* __restrict__ bv,
        unsigned short* __restrict__ Qp, unsigned short* __restrict__ Kp,
        unsigned short* __restrict__ Vp) {
    const int z = blockIdx.y;
    const float* A = (z == 0) ? Q : K;
    const float* bias = (z == 0) ? bq : (z == 1) ? bk : bv;
    unsigned short* C = (z == 0) ? Qp : (z == 1) ? Kp : Vp;
    gemm32_body<0, 0>(A, WT5 + z * 65536, bias, C, blockIdx.x);
}

// FFN1: H1 = relu(O @ W1 + b1), O fp32.
__global__ __launch_bounds__(256, 4) void ffn1_mfma(
        const float* __restrict__ O, const unsigned short* __restrict__ WT1,
        const float* __restrict__ b1, unsigned short* __restrict__ H1) {
    gemm32_body<0, 1>(O, WT1, b1, H1, blockIdx.x);
}

// ---------------------------------------------------------------------------
// FFN2 + residual + LayerNorm fused: out = LN(R + A@W2 + b2), fp32 out.
// Block = 16 rows x 256 cols, 8 waves (wave = 16x32), W-frags hoisted.
// ---------------------------------------------------------------------------
__global__ __launch_bounds__(512, 4) void gemm_ffn2_ln(
        const unsigned short* __restrict__ Ain, const unsigned short* __restrict__ WT,
        const float* __restrict__ bias, const float* __restrict__ R,
        const float* __restrict__ g, const float* __restrict__ be,
        float* __restrict__ out) {
    __shared__ unsigned short As[16 * 264];
    __shared__ float lnb[2][8][16];
    const int tid = threadIdx.x;
    const int lane = tid & 63, w = tid >> 6;          // w in 0..7
    const int l15 = lane & 15, quad = lane >> 4;
    const int r0 = blockIdx.x * 16;
    const int c0w = w * 32;
    short8 wf[8][2];
#pragma unroll
    for (int kc = 0; kc < 8; ++kc)
#pragma unroll
        for (int dt = 0; dt < 2; ++dt)
            wf[kc][dt] = *(const short8*)(WT + (size_t)(c0w + dt * 16 + l15) * DD + kc * 32 + 8 * quad);
    float bv[2], gv[2], ev[2];
#pragma unroll
    for (int dt = 0; dt < 2; ++dt) {
        int col = c0w + dt * 16 + l15;
        bv[dt] = bias[col]; gv[dt] = g[col]; ev[dt] = be[col];
    }
    {   // stage A: 512 threads x 16B
        int row = tid >> 5, c0 = (tid & 31) * 8;
        *(short8*)(As + row * 264 + c0) = *(const short8*)(Ain + (size_t)(r0 + row) * DD + c0);
    }
    __syncthreads();
    fx4 acc[2];
#pragma unroll
    for (int i = 0; i < 2; ++i) acc[i] = (fx4){0.f, 0.f, 0.f, 0.f};
#pragma unroll
    for (int kc = 0; kc < 8; ++kc) {
        short8 a = *(const short8*)(As + l15 * 264 + kc * 32 + 8 * quad);
#pragma unroll
        for (int dt = 0; dt < 2; ++dt)
            acc[dt] = __builtin_amdgcn_mfma_f32_16x16x32_bf16(a, wf[kc][dt], acc[dt], 0, 0, 0);
    }
    float v[4][2], p1[4], p2[4];
#pragma unroll
    for (int r = 0; r < 4; ++r) {
        p1[r] = 0.f; p2[r] = 0.f;
        const size_t grow = r0 + 4 * quad + r;
#pragma unroll
        for (int dt = 0; dt < 2; ++dt) {
            float x = acc[dt][r] + bv[dt] + R[grow * DD + c0w + dt * 16 + l15];
            v[r][dt] = x; p1[r] += x; p2[r] += x * x;
        }
    }
#pragma unroll
    for (int r = 0; r < 4; ++r) {
#pragma unroll
        for (int off = 1; off <= 8; off <<= 1) {
            p1[r] += __shfl_xor(p1[r], off);
            p2[r] += __shfl_xor(p2[r], off);
        }
    }
    if (l15 == 0) {
#pragma unroll
        for (int r = 0; r < 4; ++r) {
            lnb[0][w][4 * quad + r] = p1[r];
            lnb[1][w][4 * quad + r] = p2[r];
        }
    }
    __syncthreads();
#pragma unroll
    for (int r = 0; r < 4; ++r) {
        const int row = 4 * quad + r;
        float s1 = 0.f, s2 = 0.f;
#pragma unroll
        for (int ww = 0; ww < 8; ++ww) { s1 += lnb[0][ww][row]; s2 += lnb[1][ww][row]; }
        float mean = s1 * (1.0f / 256.0f);
        float var  = s2 * (1.0f / 256.0f) - mean * mean;
        float rstd = rsqrtf(var + 1e-5f);
        const size_t grow = r0 + row;
#pragma unroll
        for (int dt = 0; dt < 2; ++dt)
            out[grow * DD + c0w + dt * 16 + l15] = (v[r][dt] - mean) * rstd * gv[dt] + ev[dt];
    }
}

// ---------------------------------------------------------------------------
// Flash attention, O^T form, no-max softmax (|s| <= ~2 by construction).
// Block = 16 q-rows, 4 waves = 4 key-quarters (kq in 0..3, 512 keys =
// 16 bodies each); grid 2048. launch_bounds(256,4): allocator unconstrained
// (lands ~48 VGPR, r8 evidence) -> hardware fits 8 blocks/CU on its own
// (floor(512/48)=10 waves/EU, LDS 17.4KB*8=139KB).
// Per 32-key tile: S^T = K.Q^T (C col = q = l15) -> p = exp(s/8) per-thread
// -> pack -> XOR-swizzled LDS exchange -> od^T += V^T.P^T (od col = q).
// Merge: waves kq=0..2 park partial O^T/l in LDS; wave kq=3 reduces + writes.
// ---------------------------------------------------------------------------
__global__ __launch_bounds__(256, 4) void attn_mfma(
        const unsigned short* __restrict__ Qp, const unsigned short* __restrict__ KT,
        const unsigned short* __restrict__ VT2, float* __restrict__ Opre) {
    __shared__ unsigned int pbuf[4][256];     // per-wave P exchange, pitch 16 dw
    __shared__ float macc[3][16][68];         // kq 0..2 partial O^T [q][d]
    __shared__ float lbuf[3][16];             // kq 0..2 partial l    [q]
    const int tid = threadIdx.x;
    const int lane = tid & 63, w = tid >> 6;  // w = kq (key quarter)
    const int l15 = lane & 15, quad = lane >> 4;
    const int kq = w;
    const int gb = blockIdx.x;
    const int bh = ((gb & 7) << 1) | ((gb >> 10) & 1);  // XCD-locality swizzle
    const int qc = (gb >> 3) & 127;
    const int h  = bh & 3;
    const int b  = bh >> 2;
    const int qrow = qc * 16;
    const int sw = 4 * ((l15 >> 1) & 3);                // bank swizzle (per l15)

    short8 aq0, aq1;
    {
        const unsigned short* qptr = Qp + ((size_t)(b * NN + qrow + l15) * DD + h * DHH + 8 * quad);
        aq0 = *(const short8*)qptr;
        aq1 = *(const short8*)(qptr + 32);
    }
    fx4 od0 = (fx4){0.f, 0.f, 0.f, 0.f};
    fx4 od1 = (fx4){0.f, 0.f, 0.f, 0.f};
    fx4 od2 = (fx4){0.f, 0.f, 0.f, 0.f};
    fx4 od3 = (fx4){0.f, 0.f, 0.f, 0.f};
    float lsum = 0.0f;

    unsigned int* pw = &pbuf[w][0];
    const int wcol = (2 * quad) ^ sw;         // write cols (pairs t=2q,2q+1 / +8)
    const int rcol = (4 * quad) ^ sw;         // read col group (t=4Q..4Q+3)
    // per-(bh, key-quarter) tile bases, incl. per-lane offset l15*32 + 8*quad
    const unsigned short* kthead = KT  + ((size_t)(bh * 64) + kq * 16) * 2048 + l15 * 32 + 8 * quad;
    const unsigned short* vthead = VT2 + ((size_t)(bh * 64) + kq * 16) * 2048 + l15 * 32 + 8 * quad;

    // loop state: named registers only
    short8 ka0, ka1, ka2, ka3;     // K frags, buffer A
    short8 kb0, kb1, kb2, kb3;     // K frags, buffer B
    short8 v0, v1, v2, v3;         // V frags, current tile

#define PREF_K(K0, K1, K2, K3, T) do {                                        \
        const unsigned short* kb_ = kthead + (size_t)(T) * 2048;              \
        K0 = *(const short8*)(kb_);          /* keys l15,    d 8q..8q+7  */   \
        K1 = *(const short8*)(kb_ + 1024);   /* keys l15,    d 32+8q..   */   \
        K2 = *(const short8*)(kb_ + 512);    /* keys 16+l15, d 8q..      */   \
        K3 = *(const short8*)(kb_ + 1536);   /* keys 16+l15, d 32+8q..   */   \
    } while (0)

#define PREF_V(T) do {                                                        \
        const unsigned short* vb_ = vthead + (size_t)(T) * 2048;              \
        v0 = *(const short8*)(vb_);          /* d l15,    keys 8q..8q+7 */    \
        v1 = *(const short8*)(vb_ + 512);    /* d 16+l15                */    \
        v2 = *(const short8*)(vb_ + 1024);   /* d 32+l15                */    \
        v3 = *(const short8*)(vb_ + 1536);   /* d 48+l15                */    \
    } while (0)

#define BODY(CK0, CK1, CK2, CK3, NK0, NK1, NK2, NK3, T) do {                  \
        PREF_V(T);                            /* V for THIS tile (used last) */\
        const int tn_ = ((T) + 1 < 16) ? (T) + 1 : 15;                        \
        PREF_K(NK0, NK1, NK2, NK3, tn_);      /* K for NEXT tile */           \
        const fx4 z_ = (fx4){0.f, 0.f, 0.f, 0.f};                             \
        fx4 s0_ = __builtin_amdgcn_mfma_f32_16x16x32_bf16(CK0, aq0, z_, 0, 0, 0); \
        s0_     = __builtin_amdgcn_mfma_f32_16x16x32_bf16(CK1, aq1, s0_, 0, 0, 0); \
        fx4 s1_ = __builtin_amdgcn_mfma_f32_16x16x32_bf16(CK2, aq0, z_, 0, 0, 0); \
        s1_     = __builtin_amdgcn_mfma_f32_16x16x32_bf16(CK3, aq1, s1_, 0, 0, 0); \
        s0_[0] = __expf(s0_[0] * 0.125f); s0_[1] = __expf(s0_[1] * 0.125f);   \
        s0_[2] = __expf(s0_[2] * 0.125f); s0_[3] = __expf(s0_[3] * 0.125f);   \
        s1_[0] = __expf(s1_[0] * 0.125f); s1_[1] = __expf(s1_[1] * 0.125f);   \
        s1_[2] = __expf(s1_[2] * 0.125f); s1_[3] = __expf(s1_[3] * 0.125f);   \
        lsum += s0_[0] + s0_[1] + s0_[2] + s0_[3];                            \
        lsum += s1_[0] + s1_[1] + s1_[2] + s1_[3];                            \
        uint2v w1_ = (uint2v){packbf(s0_[0], s0_[1]), packbf(s0_[2], s0_[3])};\
        uint2v w2_ = (uint2v){packbf(s1_[0], s1_[1]), packbf(s1_[2], s1_[3])};\
        *(uint2v*)(pw + l15 * 16 + wcol)       = w1_;   /* pairs t=2q,2q+1 */ \
        *(uint2v*)(pw + l15 * 16 + (wcol ^ 8)) = w2_;   /* pairs t=8+2q..  */ \
        short8 bp_ = *(const short8*)(pw + l15 * 16 + rcol); /* keys 8q..+7 */\
        od0 = __builtin_amdgcn_mfma_f32_16x16x32_bf16(v0, bp_, od0, 0, 0, 0); \
        od1 = __builtin_amdgcn_mfma_f32_16x16x32_bf16(v1, bp_, od1, 0, 0, 0); \
        od2 = __builtin_amdgcn_mfma_f32_16x16x32_bf16(v2, bp_, od2, 0, 0, 0); \
        od3 = __builtin_amdgcn_mfma_f32_16x16x32_bf16(v3, bp_, od3, 0, 0, 0); \
    } while (0)

    PREF_K(ka0, ka1, ka2, ka3, 0);
    for (int tt = 0; tt < 8; ++tt) {
        BODY(ka0, ka1, ka2, ka3, kb0, kb1, kb2, kb3, 2 * tt);
        BODY(kb0, kb1, kb2, kb3, ka0, ka1, ka2, ka3, 2 * tt + 1);
    }
#undef BODY
#undef PREF_V
#undef PREF_K

    // per-q total l for this wave (sum over quads)
    lsum += __shfl_xor(lsum, 16);
    lsum += __shfl_xor(lsum, 32);
    // ---- merge the four key-quarters (plain adds; no max state) ----
    if (kq < 3) {
        *(fx4*)&macc[kq][l15][0 * 16 + 4 * quad] = od0;
        *(fx4*)&macc[kq][l15][1 * 16 + 4 * quad] = od1;
        *(fx4*)&macc[kq][l15][2 * 16 + 4 * quad] = od2;
        *(fx4*)&macc[kq][l15][3 * 16 + 4 * quad] = od3;
        if (quad == 0) lbuf[kq][l15] = lsum;
    }
    __syncthreads();
    if (kq == 3) {
        const float inv = 1.0f / (lsum + lbuf[0][l15] + lbuf[1][l15] + lbuf[2][l15]);
        const size_t grow = (size_t)(b * NN) + qrow + l15;
        float* obase = Opre + grow * DD + h * DHH;
        const unsigned short* qpb = Qp + grow * DD + h * DHH;
#define OUT_DT(DT, OD) do {                                                   \
        fx4 m0_ = *(const fx4*)&macc[0][l15][(DT) * 16 + 4 * quad];           \
        fx4 m1_ = *(const fx4*)&macc[1][l15][(DT) * 16 + 4 * quad];           \
        fx4 m2_ = *(const fx4*)&macc[2][l15][(DT) * 16 + 4 * quad];           \
        shortx4 rv_ = *(const shortx4*)(qpb + (DT) * 16 + 4 * quad);          \
        fx4 o_;                                                               \
        o_[0] = (OD[0] + m0_[0] + m1_[0] + m2_[0]) * inv + bf2f((unsigned short)rv_[0]); \
        o_[1] = (OD[1] + m0_[1] + m1_[1] + m2_[1]) * inv + bf2f((unsigned short)rv_[1]); \
        o_[2] = (OD[2] + m0_[2] + m1_[2] + m2_[2]) * inv + bf2f((unsigned short)rv_[2]); \
        o_[3] = (OD[3] + m0_[3] + m1_[3] + m2_[3]) * inv + bf2f((unsigned short)rv_[3]); \
        *(fx4*)(obase + (DT) * 16 + 4 * quad) = o_;                           \
    } while (0)
        OUT_DT(0, od0);
        OUT_DT(1, od1);
        OUT_DT(2, od2);
        OUT_DT(3, od3);
#undef OUT_DT
    }
}

// row LayerNorm: Y = LN(X)*g+be (fp32)
__global__ __launch_bounds__(64) void ln_rows(
        const float* __restrict__ X, const float* __restrict__ g,
        const float* __restrict__ be, float* __restrict__ Y) {
    const int lane = threadIdx.x;
    const size_t row = blockIdx.x;
    fx4 v = ((const fx4*)(X + row * DD))[lane];
    float s1 = v[0]+v[1]+v[2]+v[3];
    float s2 = v[0]*v[0]+v[1]*v[1]+v[2]*v[2]+v[3]*v[3];
#pragma unroll
    for (int off = 32; off >= 1; off >>= 1) {
        s1 += __shfl_xor(s1, off); s2 += __shfl_xor(s2, off);
    }
    float mean = s1 * (1.0f/256.0f);
    float var  = s2 * (1.0f/256.0f) - mean * mean;
    float rstd = rsqrtf(var + 1e-5f);
    fx4 gv = ((const fx4*)g)[lane];
    fx4 ev = ((const fx4*)be)[lane];
    fx4 o;
#pragma unroll
    for (int i = 0; i < 4; ++i) o[i] = (v[i]-mean)*rstd*gv[i] + ev[i];
    ((fx4*)(Y + row * DD))[lane] = o;
}

extern "C" void kernel_launch(void* const* d_in, const int* in_sizes, int n_in,
                              void* d_out, int out_size, void* d_ws, size_t ws_size,
                              hipStream_t stream) {
    (void)in_sizes; (void)n_in; (void)out_size; (void)ws_size;
    const float* Q     = (const float*)d_in[0];
    const float* K     = (const float*)d_in[1];
    const float* Wq    = (const float*)d_in[2];
    const float* bq    = (const float*)d_in[3];
    const float* Wk    = (const float*)d_in[4];
    const float* bk    = (const float*)d_in[5];
    const float* Wv    = (const float*)d_in[6];
    const float* bv    = (const float*)d_in[7];
    const float* W1    = (const float*)d_in[8];
    const float* b1    = (const float*)d_in[9];
    const float* W2    = (const float*)d_in[10];
    const float* b2    = (const float*)d_in[11];
    const float* g0    = (const float*)d_in[12];
    const float* beta0 = (const float*)d_in[13];
    const float* g1    = (const float*)d_in[14];
    const float* beta1 = (const float*)d_in[15];

    // Workspace: [0,4)Mi Qp bf16 (later H1 bf16); [4,8)Mi Kp; [8,12)Mi Vp
    // (reused as KT after vt_prep); [12,16)Mi VT2; [16,24)Mi Opre f32;
    // [24,32)Mi O f32; [32Mi,+640K) WT x5
    char* ws = (char*)d_ws;
    unsigned short* Qp  = (unsigned short*)(ws);
    unsigned short* Kp  = (unsigned short*)(ws + (4u  << 20));
    unsigned short* Vp  = (unsigned short*)(ws + (8u  << 20));
    unsigned short* KT  = Vp;                       // overlays Vp (dead after vt_prep)
    unsigned short* VT2 = (unsigned short*)(ws + (12u << 20));
    float*          Opre= (float*)(ws + (16u << 20));
    float*          O   = (float*)(ws + (24u << 20));
    unsigned short* WT5 = (unsigned short*)(ws + (32u << 20));
    unsigned short* H1  = Qp;
    float*          out = (float*)d_out;

    const unsigned short* WT1 = WT5 + 3 * 65536;
    const unsigned short* WT2 = WT5 + 4 * 65536;

    const int M = BB * NN;                        // 8192 rows

    wt_prep<<<dim3(4, 4, 5), 256, 0, stream>>>(Wq, Wk, Wv, W1, W2, WT5);
    qkv_mfma<<<dim3(M / 16, 3), 256, 0, stream>>>(Q, K, WT5, bq, bk, bv, Qp, Kp, Vp);
    vt_prep<<<dim3(128, 4), 256, 0, stream>>>(Vp, VT2);
    kt_prep<<<1024, 256, 0, stream>>>(Kp, KT);    // overwrites Vp slot (Vp dead)
    attn_mfma<<<BB * HH * (NN / 16), 256, 0, stream>>>(Qp, KT, VT2, Opre);
    ln_rows<<<M, 64, 0, stream>>>(Opre, g0, beta0, O);
    ffn1_mfma<<<M / 16, 256, 0, stream>>>(O, WT1, b1, H1);
    gemm_ffn2_ln<<<M / 16, 512, 0, stream>>>(H1, WT2, b2, O, g1, beta1, out);
}

// Round 6
// 193.576 us; speedup vs baseline: 1.1197x; 1.0583x over previous
//
#include <hip/hip_runtime.h>

// MAB block, MFMA bf16, round 12: cut L2 traffic 4x via LDS-shared K/V tiles.
// r11 post-mortem: wall time invariant under occupancy (r8 16w/CU=68us,
// r11 ~16w/CU=70us, r9 77%occ=77us) -> throughput-bound, not latency-bound.
// Aggregate L2 reads 1.05GB/70us = 15 TB/s = ~1.9 TB/s/XCD = pure-L2 ceiling.
// 128 q-blocks per (b,h) re-read the same 512KB of K/V from L2.
// r12: block = 64 q-rows (4 waves x 16), every wave sweeps ALL 64 key-tiles;
// block stages each K-tile (4KB) + V-tile (4KB) into double-buffered LDS
// (reg-staged: load at loop top, ds_write after compute, barrier). L2 traffic
// 1.05GB -> 268MB. No kq merge epilogue (each wave owns its rows fully).
// Grid 512, LDS 20.5KB, launch_bounds(256,2) (hints>4 proved to force spill).

typedef float fx4 __attribute__((ext_vector_type(4)));
typedef short short8 __attribute__((ext_vector_type(8)));
typedef short shortx4 __attribute__((ext_vector_type(4)));
typedef unsigned int uint2v __attribute__((ext_vector_type(2)));
typedef unsigned int uint4v __attribute__((ext_vector_type(4)));

#define BB  4
#define NN  2048
#define DD  256
#define HH  4
#define DHH 64

__device__ __forceinline__ float bf2f(unsigned short u) {
    union { unsigned int i; float f; } v; v.i = ((unsigned int)u) << 16; return v.f;
}
__device__ __forceinline__ unsigned short f2bf(float f) {
    union { float f; unsigned int i; } v; v.f = f;
    unsigned int r = v.i + 0x7FFF + ((v.i >> 16) & 1);   // RNE
    return (unsigned short)(r >> 16);
}
__device__ __forceinline__ unsigned int fbits(float f) {
    union { float f; unsigned int i; } v; v.f = f; return v.i;
}
__device__ __forceinline__ unsigned int packbf(float lo, float hi) {
    unsigned int a = fbits(lo), b = fbits(hi);
    a = (a + 0x7FFF + ((a >> 16) & 1)) >> 16;
    b = (b + 0x7FFF + ((b >> 16) & 1)) & 0xFFFF0000u;
    return a | b;
}

// ---------------------------------------------------------------------------
// Weight prep: WT[n][k] = bf16(W[k][n]) for the 5 weight matrices (256x256).
// ---------------------------------------------------------------------------
__global__ __launch_bounds__(256) void wt_prep(
        const float* __restrict__ w0, const float* __restrict__ w1,
        const float* __restrict__ w2, const float* __restrict__ w3,
        const float* __restrict__ w4, unsigned short* __restrict__ dst) {
    __shared__ unsigned short T[64 * 73];
    const int tid = threadIdx.x;
    const int z = blockIdx.z;
    const float* W = (z == 0) ? w0 : (z == 1) ? w1 : (z == 2) ? w2 : (z == 3) ? w3 : w4;
    unsigned short* WT = dst + z * 65536;
    const int nb = blockIdx.x * 64, kb = blockIdx.y * 64;
    {
        int kl = tid >> 2, c0 = (tid & 3) * 16;
        const float* src = W + (size_t)(kb + kl) * DD + nb + c0;
#pragma unroll
        for (int i = 0; i < 16; ++i) T[kl * 73 + c0 + i] = f2bf(src[i]);
    }
    __syncthreads();
    {
        int nl = tid >> 2, k0 = (tid & 3) * 16;
        short8 o0, o1;
#pragma unroll
        for (int i = 0; i < 8; ++i) {
            o0[i] = (short)T[(k0 + i) * 73 + nl];
            o1[i] = (short)T[(k0 + 8 + i) * 73 + nl];
        }
        short8* d = (short8*)(WT + (size_t)(nb + nl) * DD + kb + k0);
        d[0] = o0; d[1] = o1;
    }
}

// ---------------------------------------------------------------------------
// V tile-transpose: VT2[bh][tile][d64][key32] <- Vp[b*2048+key][h*64+d].
// grid(128,4): b = bx>>5, keyb = (bx&31)*64 (2 tiles), hb = by.
// ---------------------------------------------------------------------------
__global__ __launch_bounds__(256) void vt_prep(
        const unsigned short* __restrict__ Vp, unsigned short* __restrict__ VT2) {
    __shared__ unsigned short T[64 * 73];
    const int tid = threadIdx.x;
    const int hb = blockIdx.y;
    const int b = blockIdx.x >> 5;
    const int keyb = (blockIdx.x & 31) * 64;
    const int bh = b * HH + hb;
    {
        int kl = tid >> 2, c0 = (tid & 3) * 16;
        const short8* src = (const short8*)(Vp + (size_t)(b * NN + keyb + kl) * DD + hb * DHH + c0);
        short8 v0 = src[0], v1 = src[1];
#pragma unroll
        for (int i = 0; i < 8; ++i) {
            T[kl * 73 + c0 + i]     = (unsigned short)v0[i];
            T[kl * 73 + c0 + 8 + i] = (unsigned short)v1[i];
        }
    }
    __syncthreads();
    {
        int dl = tid >> 2, k0 = (tid & 3) * 16;          // d row, key chunk (16)
        short8 o0, o1;
#pragma unroll
        for (int i = 0; i < 8; ++i) {
            o0[i] = (short)T[(k0 + i) * 73 + dl];
            o1[i] = (short)T[(k0 + 8 + i) * 73 + dl];
        }
        const int gkey = keyb + k0;                       // multiple of 16
        const int tl = gkey >> 5;                         // tile index
        const int kin = gkey & 31;                        // 0 or 16
        short8* d = (short8*)(VT2 + ((size_t)(bh * 64 + tl) * 64 + dl) * 32 + kin);
        d[0] = o0; d[1] = o1;
    }
}

// ---------------------------------------------------------------------------
// K tile-permute: KT[bh][tile][dhalf][key32][d32] <- Kp[b*2048+key][h*64+d].
// Pure 16B-chunk permutation; grid 1024 = bh*64 + tile, 256 threads.
// ---------------------------------------------------------------------------
__global__ __launch_bounds__(256) void kt_prep(
        const unsigned short* __restrict__ Kp, unsigned short* __restrict__ KT) {
    const int bh = blockIdx.x >> 6;
    const int tl = blockIdx.x & 63;
    const int b = bh >> 2, h = bh & 3;
    const int tid = threadIdx.x;
    const int key = tid >> 3, p = tid & 7;
    short8 v = *(const short8*)(Kp + (size_t)(b * NN + tl * 32 + key) * DD + h * DHH + p * 8);
    unsigned short* dst = KT + (size_t)(bh * 64 + tl) * 2048
                        + (p >> 2) * 1024 + key * 32 + (p & 3) * 8;
    *(short8*)dst = v;
}

// ---------------------------------------------------------------------------
// 32-row GEMM body: C[r0..r0+32, c-half] = A @ W + bias. 4 waves, wave =
// 32 rows x 32 cols. W-frags hoisted. AIN: 0 fp32 A, 1 bf16 A.
// EP: 0 bias->bf16, 1 relu->bf16.
// ---------------------------------------------------------------------------
template<int AIN, int EP>
__device__ __forceinline__ void gemm32_body(
        const void* __restrict__ Ain, const unsigned short* __restrict__ WT,
        const float* __restrict__ bias, void* __restrict__ Cout, int bx) {
    __shared__ unsigned short As[32 * 264];
    const int tid = threadIdx.x;
    const int lane = tid & 63, w = tid >> 6;
    const int l15 = lane & 15, quad = lane >> 4;
    const int r0 = (bx >> 1) * 32;
    const int c0w = (bx & 1) * 128 + w * 32;
    short8 wf[8][2];
#pragma unroll
    for (int kc = 0; kc < 8; ++kc)
#pragma unroll
        for (int dt = 0; dt < 2; ++dt)
            wf[kc][dt] = *(const short8*)(WT + (size_t)(c0w + dt * 16 + l15) * DD + kc * 32 + 8 * quad);
    float bv[2];
#pragma unroll
    for (int dt = 0; dt < 2; ++dt) bv[dt] = bias[c0w + dt * 16 + l15];
    {   // stage A tile (32 x 256) as bf16; thread: 32 elems
        int row = tid >> 3, c0 = (tid & 7) * 32;
        short8 o[4];
        if (AIN == 0) {
            const fx4* s4 = (const fx4*)((const float*)Ain + (size_t)(r0 + row) * DD + c0);
#pragma unroll
            for (int j = 0; j < 4; ++j) {
                fx4 v0 = s4[2 * j], v1 = s4[2 * j + 1];
#pragma unroll
                for (int i = 0; i < 4; ++i) {
                    o[j][i]     = (short)f2bf(v0[i]);
                    o[j][i + 4] = (short)f2bf(v1[i]);
                }
            }
        } else {
            const short8* s8 = (const short8*)((const unsigned short*)Ain + (size_t)(r0 + row) * DD + c0);
#pragma unroll
            for (int j = 0; j < 4; ++j) o[j] = s8[j];
        }
        short8* d = (short8*)(As + row * 264 + c0);
#pragma unroll
        for (int j = 0; j < 4; ++j) d[j] = o[j];
    }
    __syncthreads();
    fx4 acc[2][2];
#pragma unroll
    for (int mt = 0; mt < 2; ++mt)
#pragma unroll
        for (int dt = 0; dt < 2; ++dt) acc[mt][dt] = (fx4){0.f, 0.f, 0.f, 0.f};
#pragma unroll
    for (int kc = 0; kc < 8; ++kc) {
        short8 a0 = *(const short8*)(As + l15 * 264 + kc * 32 + 8 * quad);
        short8 a1 = *(const short8*)(As + (16 + l15) * 264 + kc * 32 + 8 * quad);
#pragma unroll
        for (int dt = 0; dt < 2; ++dt) {
            acc[0][dt] = __builtin_amdgcn_mfma_f32_16x16x32_bf16(a0, wf[kc][dt], acc[0][dt], 0, 0, 0);
            acc[1][dt] = __builtin_amdgcn_mfma_f32_16x16x32_bf16(a1, wf[kc][dt], acc[1][dt], 0, 0, 0);
        }
    }
#pragma unroll
    for (int mt = 0; mt < 2; ++mt)
#pragma unroll
        for (int r = 0; r < 4; ++r) {
            const size_t grow = r0 + mt * 16 + 4 * quad + r;
#pragma unroll
            for (int dt = 0; dt < 2; ++dt) {
                float v = acc[mt][dt][r] + bv[dt];
                if (EP == 1) v = fmaxf(v, 0.0f);
                ((unsigned short*)Cout)[grow * DD + c0w + dt * 16 + l15] = f2bf(v);
            }
        }
}

// Fused QKV projections: grid (512, 3); y selects {Q->Qp, K->Kp, K->Vp}.
__global__ __launch_bounds__(256, 4) void qkv_mfma(
        const float* __restrict__ Q, const float* __restrict__ K,
        const unsigned short* __restrict__ WT5,
        const float* __restrict__ bq, const float* __restrict__ bk,
        const float* __restrict__ bv,
        unsigned short* __restrict__ Qp, unsigned short* __restrict__ Kp,
        unsigned short* __restrict__ Vp) {
    const int z = blockIdx.y;
    const float* A = (z == 0) ? Q : K;
    const float* bias = (z == 0) ? bq : (z == 1) ? bk : bv;
    unsigned short* C = (z == 0) ? Qp : (z == 1) ? Kp : Vp;
    gemm32_body<0, 0>(A, WT5 + z * 65536, bias, C, blockIdx.x);
}

// FFN1: H1 = relu(O @ W1 + b1), O fp32.
__global__ __launch_bounds__(256, 4) void ffn1_mfma(
        const float* __restrict__ O, const unsigned short* __restrict__ WT1,
        const float* __restrict__ b1, unsigned short* __restrict__ H1) {
    gemm32_body<0, 1>(O, WT1, b1, H1, blockIdx.x);
}

// ---------------------------------------------------------------------------
// FFN2 + residual + LayerNorm fused: out = LN(R + A@W2 + b2), fp32 out.
// Block = 16 rows x 256 cols, 8 waves (wave = 16x32), W-frags hoisted.
// ---------------------------------------------------------------------------
__global__ __launch_bounds__(512, 4) void gemm_ffn2_ln(
        const unsigned short* __restrict__ Ain, const unsigned short* __restrict__ WT,
        const float* __restrict__ bias, const float* __restrict__ R,
        const float* __restrict__ g, const float* __restrict__ be,
        float* __restrict__ out) {
    __shared__ unsigned short As[16 * 264];
    __shared__ float lnb[2][8][16];
    const int tid = threadIdx.x;
    const int lane = tid & 63, w = tid >> 6;          // w in 0..7
    const int l15 = lane & 15, quad = lane >> 4;
    const int r0 = blockIdx.x * 16;
    const int c0w = w * 32;
    short8 wf[8][2];
#pragma unroll
    for (int kc = 0; kc < 8; ++kc)
#pragma unroll
        for (int dt = 0; dt < 2; ++dt)
            wf[kc][dt] = *(const short8*)(WT + (size_t)(c0w + dt * 16 + l15) * DD + kc * 32 + 8 * quad);
    float bv[2], gv[2], ev[2];
#pragma unroll
    for (int dt = 0; dt < 2; ++dt) {
        int col = c0w + dt * 16 + l15;
        bv[dt] = bias[col]; gv[dt] = g[col]; ev[dt] = be[col];
    }
    {   // stage A: 512 threads x 16B
        int row = tid >> 5, c0 = (tid & 31) * 8;
        *(short8*)(As + row * 264 + c0) = *(const short8*)(Ain + (size_t)(r0 + row) * DD + c0);
    }
    __syncthreads();
    fx4 acc[2];
#pragma unroll
    for (int i = 0; i < 2; ++i) acc[i] = (fx4){0.f, 0.f, 0.f, 0.f};
#pragma unroll
    for (int kc = 0; kc < 8; ++kc) {
        short8 a = *(const short8*)(As + l15 * 264 + kc * 32 + 8 * quad);
#pragma unroll
        for (int dt = 0; dt < 2; ++dt)
            acc[dt] = __builtin_amdgcn_mfma_f32_16x16x32_bf16(a, wf[kc][dt], acc[dt], 0, 0, 0);
    }
    float v[4][2], p1[4], p2[4];
#pragma unroll
    for (int r = 0; r < 4; ++r) {
        p1[r] = 0.f; p2[r] = 0.f;
        const size_t grow = r0 + 4 * quad + r;
#pragma unroll
        for (int dt = 0; dt < 2; ++dt) {
            float x = acc[dt][r] + bv[dt] + R[grow * DD + c0w + dt * 16 + l15];
            v[r][dt] = x; p1[r] += x; p2[r] += x * x;
        }
    }
#pragma unroll
    for (int r = 0; r < 4; ++r) {
#pragma unroll
        for (int off = 1; off <= 8; off <<= 1) {
            p1[r] += __shfl_xor(p1[r], off);
            p2[r] += __shfl_xor(p2[r], off);
        }
    }
    if (l15 == 0) {
#pragma unroll
        for (int r = 0; r < 4; ++r) {
            lnb[0][w][4 * quad + r] = p1[r];
            lnb[1][w][4 * quad + r] = p2[r];
        }
    }
    __syncthreads();
#pragma unroll
    for (int r = 0; r < 4; ++r) {
        const int row = 4 * quad + r;
        float s1 = 0.f, s2 = 0.f;
#pragma unroll
        for (int ww = 0; ww < 8; ++ww) { s1 += lnb[0][ww][row]; s2 += lnb[1][ww][row]; }
        float mean = s1 * (1.0f / 256.0f);
        float var  = s2 * (1.0f / 256.0f) - mean * mean;
        float rstd = rsqrtf(var + 1e-5f);
        const size_t grow = r0 + row;
#pragma unroll
        for (int dt = 0; dt < 2; ++dt)
            out[grow * DD + c0w + dt * 16 + l15] = (v[r][dt] - mean) * rstd * gv[dt] + ev[dt];
    }
}

// ---------------------------------------------------------------------------
// Flash attention, O^T form, no-max softmax. r12: LDS-shared K/V tiles.
// Block = 64 q-rows, 4 waves = 4 q-subtiles (w*16 rows each); every wave
// sweeps all 64 key-tiles. Per tile: block stages K (4KB) + V (4KB) into
// double-buffered LDS (reg-staged: global load at loop top, ds_write after
// compute, one barrier per tile). L2 traffic /4 vs r11. No merge epilogue.
// Per 32-key tile: S^T = K.Q^T (C col = q = l15) -> p = exp(s/8) per-thread
// -> pack -> XOR-swizzled LDS exchange -> od^T += V^T.P^T (od col = q).
// ---------------------------------------------------------------------------
__global__ __launch_bounds__(256, 2) void attn_mfma(
        const unsigned short* __restrict__ Qp, const unsigned short* __restrict__ KT,
        const unsigned short* __restrict__ VT2, float* __restrict__ Opre) {
    __shared__ unsigned short kbuf[2][2048];  // K tile double buffer (4KB ea)
    __shared__ unsigned short vbuf[2][2048];  // V tile double buffer
    __shared__ unsigned int pbuf[4][256];     // per-wave P exchange, pitch 16 dw
    const int tid = threadIdx.x;
    const int lane = tid & 63, w = tid >> 6;  // w = q-subtile
    const int l15 = lane & 15, quad = lane >> 4;
    const int gb = blockIdx.x;                // 0..511
    const int bh = ((gb & 7) << 1) | ((gb >> 8) & 1);   // XCD-locality swizzle
    const int qc = (gb >> 3) & 31;
    const int h  = bh & 3;
    const int b  = bh >> 2;
    const int qrow = qc * 64 + w * 16;
    const int sw = 4 * ((l15 >> 1) & 3);                // bank swizzle (per l15)

    short8 aq0, aq1;
    {
        const unsigned short* qptr = Qp + ((size_t)(b * NN + qrow + l15) * DD + h * DHH + 8 * quad);
        aq0 = *(const short8*)qptr;
        aq1 = *(const short8*)(qptr + 32);
    }
    fx4 od0 = (fx4){0.f, 0.f, 0.f, 0.f};
    fx4 od1 = (fx4){0.f, 0.f, 0.f, 0.f};
    fx4 od2 = (fx4){0.f, 0.f, 0.f, 0.f};
    fx4 od3 = (fx4){0.f, 0.f, 0.f, 0.f};
    float lsum = 0.0f;

    unsigned int* pw = &pbuf[w][0];
    const int wcol = (2 * quad) ^ sw;         // write cols (pairs t=2q,2q+1 / +8)
    const int rcol = (4 * quad) ^ sw;         // read col group (t=4Q..4Q+3)
    const unsigned short* ktb = KT  + (size_t)bh * 64 * 2048 + tid * 8;  // stage src
    const unsigned short* vtb = VT2 + (size_t)bh * 64 * 2048 + tid * 8;
    const int fo = l15 * 32 + 8 * quad;       // frag base offset within tile

    // prologue: stage tile 0 into buffer 0
    {
        uint4v kr = *(const uint4v*)ktb;
        uint4v vr = *(const uint4v*)vtb;
        *(uint4v*)&kbuf[0][tid * 8] = kr;
        *(uint4v*)&vbuf[0][tid * 8] = vr;
    }
    __syncthreads();

    for (int t = 0; t < 64; ++t) {
        const int cur = t & 1;
        const int tn = (t < 63) ? t + 1 : 63;           // clamp (last redundant)
        // issue next-tile global loads FIRST (T14 async split: write after compute)
        uint4v kr = *(const uint4v*)(ktb + (size_t)tn * 2048);
        uint4v vr = *(const uint4v*)(vtb + (size_t)tn * 2048);

        // ---- compute tile t from LDS ----
        const unsigned short* kb = &kbuf[cur][fo];
        short8 ck0 = *(const short8*)(kb);          // keys l15,    d 8q..8q+7
        short8 ck1 = *(const short8*)(kb + 1024);   // keys l15,    d 32+8q..
        short8 ck2 = *(const short8*)(kb + 512);    // keys 16+l15, d 8q..
        short8 ck3 = *(const short8*)(kb + 1536);   // keys 16+l15, d 32+8q..
        const unsigned short* vb = &vbuf[cur][fo];
        short8 cv0 = *(const short8*)(vb);          // d l15,    keys 8q..8q+7
        short8 cv1 = *(const short8*)(vb + 512);    // d 16+l15
        short8 cv2 = *(const short8*)(vb + 1024);   // d 32+l15
        short8 cv3 = *(const short8*)(vb + 1536);   // d 48+l15

        const fx4 z_ = (fx4){0.f, 0.f, 0.f, 0.f};
        fx4 s0 = __builtin_amdgcn_mfma_f32_16x16x32_bf16(ck0, aq0, z_, 0, 0, 0);
        s0     = __builtin_amdgcn_mfma_f32_16x16x32_bf16(ck1, aq1, s0, 0, 0, 0);
        fx4 s1 = __builtin_amdgcn_mfma_f32_16x16x32_bf16(ck2, aq0, z_, 0, 0, 0);
        s1     = __builtin_amdgcn_mfma_f32_16x16x32_bf16(ck3, aq1, s1, 0, 0, 0);
        s0[0] = __expf(s0[0] * 0.125f); s0[1] = __expf(s0[1] * 0.125f);
        s0[2] = __expf(s0[2] * 0.125f); s0[3] = __expf(s0[3] * 0.125f);
        s1[0] = __expf(s1[0] * 0.125f); s1[1] = __expf(s1[1] * 0.125f);
        s1[2] = __expf(s1[2] * 0.125f); s1[3] = __expf(s1[3] * 0.125f);
        lsum += s0[0] + s0[1] + s0[2] + s0[3];
        lsum += s1[0] + s1[1] + s1[2] + s1[3];
        uint2v w1_ = (uint2v){packbf(s0[0], s0[1]), packbf(s0[2], s0[3])};
        uint2v w2_ = (uint2v){packbf(s1[0], s1[1]), packbf(s1[2], s1[3])};
        *(uint2v*)(pw + l15 * 16 + wcol)       = w1_;   // pairs t=2q,2q+1
        *(uint2v*)(pw + l15 * 16 + (wcol ^ 8)) = w2_;   // pairs t=8+2q,8+2q+1
        short8 bp = *(const short8*)(pw + l15 * 16 + rcol);  // keys 8*quad..+7
        od0 = __builtin_amdgcn_mfma_f32_16x16x32_bf16(cv0, bp, od0, 0, 0, 0);
        od1 = __builtin_amdgcn_mfma_f32_16x16x32_bf16(cv1, bp, od1, 0, 0, 0);
        od2 = __builtin_amdgcn_mfma_f32_16x16x32_bf16(cv2, bp, od2, 0, 0, 0);
        od3 = __builtin_amdgcn_mfma_f32_16x16x32_bf16(cv3, bp, od3, 0, 0, 0);

        // ---- land next tile into the other buffer, then sync ----
        *(uint4v*)&kbuf[cur ^ 1][tid * 8] = kr;
        *(uint4v*)&vbuf[cur ^ 1][tid * 8] = vr;
        __syncthreads();
    }

    // per-q total l (sum over quads); each wave owns its rows completely
    lsum += __shfl_xor(lsum, 16);
    lsum += __shfl_xor(lsum, 32);
    const float inv = 1.0f / lsum;
    const size_t grow = (size_t)(b * NN) + qrow + l15;
    float* obase = Opre + grow * DD + h * DHH;
    const unsigned short* qpb = Qp + grow * DD + h * DHH;
#define OUT_DT(DT, OD) do {                                                   \
        shortx4 rv_ = *(const shortx4*)(qpb + (DT) * 16 + 4 * quad);          \
        fx4 o_;                                                               \
        o_[0] = OD[0] * inv + bf2f((unsigned short)rv_[0]);                   \
        o_[1] = OD[1] * inv + bf2f((unsigned short)rv_[1]);                   \
        o_[2] = OD[2] * inv + bf2f((unsigned short)rv_[2]);                   \
        o_[3] = OD[3] * inv + bf2f((unsigned short)rv_[3]);                   \
        *(fx4*)(obase + (DT) * 16 + 4 * quad) = o_;                           \
    } while (0)
    OUT_DT(0, od0);
    OUT_DT(1, od1);
    OUT_DT(2, od2);
    OUT_DT(3, od3);
#undef OUT_DT
}

// row LayerNorm: Y = LN(X)*g+be (fp32)
__global__ __launch_bounds__(64) void ln_rows(
        const float* __restrict__ X, const float* __restrict__ g,
        const float* __restrict__ be, float* __restrict__ Y) {
    const int lane = threadIdx.x;
    const size_t row = blockIdx.x;
    fx4 v = ((const fx4*)(X + row * DD))[lane];
    float s1 = v[0]+v[1]+v[2]+v[3];
    float s2 = v[0]*v[0]+v[1]*v[1]+v[2]*v[2]+v[3]*v[3];
#pragma unroll
    for (int off = 32; off >= 1; off >>= 1) {
        s1 += __shfl_xor(s1, off); s2 += __shfl_xor(s2, off);
    }
    float mean = s1 * (1.0f/256.0f);
    float var  = s2 * (1.0f/256.0f) - mean * mean;
    float rstd = rsqrtf(var + 1e-5f);
    fx4 gv = ((const fx4*)g)[lane];
    fx4 ev = ((const fx4*)be)[lane];
    fx4 o;
#pragma unroll
    for (int i = 0; i < 4; ++i) o[i] = (v[i]-mean)*rstd*gv[i] + ev[i];
    ((fx4*)(Y + row * DD))[lane] = o;
}

extern "C" void kernel_launch(void* const* d_in, const int* in_sizes, int n_in,
                              void* d_out, int out_size, void* d_ws, size_t ws_size,
                              hipStream_t stream) {
    (void)in_sizes; (void)n_in; (void)out_size; (void)ws_size;
    const float* Q     = (const float*)d_in[0];
    const float* K     = (const float*)d_in[1];
    const float* Wq    = (const float*)d_in[2];
    const float* bq    = (const float*)d_in[3];
    const float* Wk    = (const float*)d_in[4];
    const float* bk    = (const float*)d_in[5];
    const float* Wv    = (const float*)d_in[6];
    const float* bv    = (const float*)d_in[7];
    const float* W1    = (const float*)d_in[8];
    const float* b1    = (const float*)d_in[9];
    const float* W2    = (const float*)d_in[10];
    const float* b2    = (const float*)d_in[11];
    const float* g0    = (const float*)d_in[12];
    const float* beta0 = (const float*)d_in[13];
    const float* g1    = (const float*)d_in[14];
    const float* beta1 = (const float*)d_in[15];

    // Workspace: [0,4)Mi Qp bf16 (later H1 bf16); [4,8)Mi Kp; [8,12)Mi Vp
    // (reused as KT after vt_prep); [12,16)Mi VT2; [16,24)Mi Opre f32;
    // [24,32)Mi O f32; [32Mi,+640K) WT x5
    char* ws = (char*)d_ws;
    unsigned short* Qp  = (unsigned short*)(ws);
    unsigned short* Kp  = (unsigned short*)(ws + (4u  << 20));
    unsigned short* Vp  = (unsigned short*)(ws + (8u  << 20));
    unsigned short* KT  = Vp;                       // overlays Vp (dead after vt_prep)
    unsigned short* VT2 = (unsigned short*)(ws + (12u << 20));
    float*          Opre= (float*)(ws + (16u << 20));
    float*          O   = (float*)(ws + (24u << 20));
    unsigned short* WT5 = (unsigned short*)(ws + (32u << 20));
    unsigned short* H1  = Qp;
    float*          out = (float*)d_out;

    const unsigned short* WT1 = WT5 + 3 * 65536;
    const unsigned short* WT2 = WT5 + 4 * 65536;

    const int M = BB * NN;                        // 8192 rows

    wt_prep<<<dim3(4, 4, 5), 256, 0, stream>>>(Wq, Wk, Wv, W1, W2, WT5);
    qkv_mfma<<<dim3(M / 16, 3), 256, 0, stream>>>(Q, K, WT5, bq, bk, bv, Qp, Kp, Vp);
    vt_prep<<<dim3(128, 4), 256, 0, stream>>>(Vp, VT2);
    kt_prep<<<1024, 256, 0, stream>>>(Kp, KT);    // overwrites Vp slot (Vp dead)
    attn_mfma<<<512, 256, 0, stream>>>(Qp, KT, VT2, Opre);
    ln_rows<<<M, 64, 0, stream>>>(Opre, g0, beta0, O);
    ffn1_mfma<<<M / 16, 256, 0, stream>>>(O, WT1, b1, H1);
    gemm_ffn2_ln<<<M / 16, 512, 0, stream>>>(H1, WT2, b2, O, g1, beta1, out);
}

// Round 7
// 193.040 us; speedup vs baseline: 1.1228x; 1.0028x over previous
//
#include <hip/hip_runtime.h>

// MAB block, MFMA bf16, round 13: XOR-swizzle the K/V LDS tiles (T2).
// r12 post-mortem: LDS staging cut L2 traffic 4x (70->53us) but the K/V
// fragment reads (byte l15*64+quad*16) are an 8-way bank conflict: bank base
// (l15&1)*16+quad*4 -> 8 same-parity l15 lanes share 4 banks. CONFLICT count
// 1.08M->5.24M; LDS-unit budget ~1300cy/tile/block = the measured wall.
// r13: swizzle both stage-write and frag-read addresses with
// e' = e ^ (((e>>6)&3)<<3)  (byte[5:4] ^= byte[8:7]).
// Write side stays conflict-free (constant perm per 8-lane phase); read side
// becomes bank base (l15&1)*16 + ((quad^(l15>>1))&3)*4 -> conflict-free.
// Single variable vs r12.

typedef float fx4 __attribute__((ext_vector_type(4)));
typedef short short8 __attribute__((ext_vector_type(8)));
typedef short shortx4 __attribute__((ext_vector_type(4)));
typedef unsigned int uint2v __attribute__((ext_vector_type(2)));
typedef unsigned int uint4v __attribute__((ext_vector_type(4)));

#define BB  4
#define NN  2048
#define DD  256
#define HH  4
#define DHH 64

__device__ __forceinline__ float bf2f(unsigned short u) {
    union { unsigned int i; float f; } v; v.i = ((unsigned int)u) << 16; return v.f;
}
__device__ __forceinline__ unsigned short f2bf(float f) {
    union { float f; unsigned int i; } v; v.f = f;
    unsigned int r = v.i + 0x7FFF + ((v.i >> 16) & 1);   // RNE
    return (unsigned short)(r >> 16);
}
__device__ __forceinline__ unsigned int fbits(float f) {
    union { float f; unsigned int i; } v; v.f = f; return v.i;
}
__device__ __forceinline__ unsigned int packbf(float lo, float hi) {
    unsigned int a = fbits(lo), b = fbits(hi);
    a = (a + 0x7FFF + ((a >> 16) & 1)) >> 16;
    b = (b + 0x7FFF + ((b >> 16) & 1)) & 0xFFFF0000u;
    return a | b;
}

// ---------------------------------------------------------------------------
// Weight prep: WT[n][k] = bf16(W[k][n]) for the 5 weight matrices (256x256).
// ---------------------------------------------------------------------------
__global__ __launch_bounds__(256) void wt_prep(
        const float* __restrict__ w0, const float* __restrict__ w1,
        const float* __restrict__ w2, const float* __restrict__ w3,
        const float* __restrict__ w4, unsigned short* __restrict__ dst) {
    __shared__ unsigned short T[64 * 73];
    const int tid = threadIdx.x;
    const int z = blockIdx.z;
    const float* W = (z == 0) ? w0 : (z == 1) ? w1 : (z == 2) ? w2 : (z == 3) ? w3 : w4;
    unsigned short* WT = dst + z * 65536;
    const int nb = blockIdx.x * 64, kb = blockIdx.y * 64;
    {
        int kl = tid >> 2, c0 = (tid & 3) * 16;
        const float* src = W + (size_t)(kb + kl) * DD + nb + c0;
#pragma unroll
        for (int i = 0; i < 16; ++i) T[kl * 73 + c0 + i] = f2bf(src[i]);
    }
    __syncthreads();
    {
        int nl = tid >> 2, k0 = (tid & 3) * 16;
        short8 o0, o1;
#pragma unroll
        for (int i = 0; i < 8; ++i) {
            o0[i] = (short)T[(k0 + i) * 73 + nl];
            o1[i] = (short)T[(k0 + 8 + i) * 73 + nl];
        }
        short8* d = (short8*)(WT + (size_t)(nb + nl) * DD + kb + k0);
        d[0] = o0; d[1] = o1;
    }
}

// ---------------------------------------------------------------------------
// V tile-transpose: VT2[bh][tile][d64][key32] <- Vp[b*2048+key][h*64+d].
// grid(128,4): b = bx>>5, keyb = (bx&31)*64 (2 tiles), hb = by.
// ---------------------------------------------------------------------------
__global__ __launch_bounds__(256) void vt_prep(
        const unsigned short* __restrict__ Vp, unsigned short* __restrict__ VT2) {
    __shared__ unsigned short T[64 * 73];
    const int tid = threadIdx.x;
    const int hb = blockIdx.y;
    const int b = blockIdx.x >> 5;
    const int keyb = (blockIdx.x & 31) * 64;
    const int bh = b * HH + hb;
    {
        int kl = tid >> 2, c0 = (tid & 3) * 16;
        const short8* src = (const short8*)(Vp + (size_t)(b * NN + keyb + kl) * DD + hb * DHH + c0);
        short8 v0 = src[0], v1 = src[1];
#pragma unroll
        for (int i = 0; i < 8; ++i) {
            T[kl * 73 + c0 + i]     = (unsigned short)v0[i];
            T[kl * 73 + c0 + 8 + i] = (unsigned short)v1[i];
        }
    }
    __syncthreads();
    {
        int dl = tid >> 2, k0 = (tid & 3) * 16;          // d row, key chunk (16)
        short8 o0, o1;
#pragma unroll
        for (int i = 0; i < 8; ++i) {
            o0[i] = (short)T[(k0 + i) * 73 + dl];
            o1[i] = (short)T[(k0 + 8 + i) * 73 + dl];
        }
        const int gkey = keyb + k0;                       // multiple of 16
        const int tl = gkey >> 5;                         // tile index
        const int kin = gkey & 31;                        // 0 or 16
        short8* d = (short8*)(VT2 + ((size_t)(bh * 64 + tl) * 64 + dl) * 32 + kin);
        d[0] = o0; d[1] = o1;
    }
}

// ---------------------------------------------------------------------------
// K tile-permute: KT[bh][tile][dhalf][key32][d32] <- Kp[b*2048+key][h*64+d].
// Pure 16B-chunk permutation; grid 1024 = bh*64 + tile, 256 threads.
// ---------------------------------------------------------------------------
__global__ __launch_bounds__(256) void kt_prep(
        const unsigned short* __restrict__ Kp, unsigned short* __restrict__ KT) {
    const int bh = blockIdx.x >> 6;
    const int tl = blockIdx.x & 63;
    const int b = bh >> 2, h = bh & 3;
    const int tid = threadIdx.x;
    const int key = tid >> 3, p = tid & 7;
    short8 v = *(const short8*)(Kp + (size_t)(b * NN + tl * 32 + key) * DD + h * DHH + p * 8);
    unsigned short* dst = KT + (size_t)(bh * 64 + tl) * 2048
                        + (p >> 2) * 1024 + key * 32 + (p & 3) * 8;
    *(short8*)dst = v;
}

// ---------------------------------------------------------------------------
// 32-row GEMM body: C[r0..r0+32, c-half] = A @ W + bias. 4 waves, wave =
// 32 rows x 32 cols. W-frags hoisted. AIN: 0 fp32 A, 1 bf16 A.
// EP: 0 bias->bf16, 1 relu->bf16.
// ---------------------------------------------------------------------------
template<int AIN, int EP>
__device__ __forceinline__ void gemm32_body(
        const void* __restrict__ Ain, const unsigned short* __restrict__ WT,
        const float* __restrict__ bias, void* __restrict__ Cout, int bx) {
    __shared__ unsigned short As[32 * 264];
    const int tid = threadIdx.x;
    const int lane = tid & 63, w = tid >> 6;
    const int l15 = lane & 15, quad = lane >> 4;
    const int r0 = (bx >> 1) * 32;
    const int c0w = (bx & 1) * 128 + w * 32;
    short8 wf[8][2];
#pragma unroll
    for (int kc = 0; kc < 8; ++kc)
#pragma unroll
        for (int dt = 0; dt < 2; ++dt)
            wf[kc][dt] = *(const short8*)(WT + (size_t)(c0w + dt * 16 + l15) * DD + kc * 32 + 8 * quad);
    float bv[2];
#pragma unroll
    for (int dt = 0; dt < 2; ++dt) bv[dt] = bias[c0w + dt * 16 + l15];
    {   // stage A tile (32 x 256) as bf16; thread: 32 elems
        int row = tid >> 3, c0 = (tid & 7) * 32;
        short8 o[4];
        if (AIN == 0) {
            const fx4* s4 = (const fx4*)((const float*)Ain + (size_t)(r0 + row) * DD + c0);
#pragma unroll
            for (int j = 0; j < 4; ++j) {
                fx4 v0 = s4[2 * j], v1 = s4[2 * j + 1];
#pragma unroll
                for (int i = 0; i < 4; ++i) {
                    o[j][i]     = (short)f2bf(v0[i]);
                    o[j][i + 4] = (short)f2bf(v1[i]);
                }
            }
        } else {
            const short8* s8 = (const short8*)((const unsigned short*)Ain + (size_t)(r0 + row) * DD + c0);
#pragma unroll
            for (int j = 0; j < 4; ++j) o[j] = s8[j];
        }
        short8* d = (short8*)(As + row * 264 + c0);
#pragma unroll
        for (int j = 0; j < 4; ++j) d[j] = o[j];
    }
    __syncthreads();
    fx4 acc[2][2];
#pragma unroll
    for (int mt = 0; mt < 2; ++mt)
#pragma unroll
        for (int dt = 0; dt < 2; ++dt) acc[mt][dt] = (fx4){0.f, 0.f, 0.f, 0.f};
#pragma unroll
    for (int kc = 0; kc < 8; ++kc) {
        short8 a0 = *(const short8*)(As + l15 * 264 + kc * 32 + 8 * quad);
        short8 a1 = *(const short8*)(As + (16 + l15) * 264 + kc * 32 + 8 * quad);
#pragma unroll
        for (int dt = 0; dt < 2; ++dt) {
            acc[0][dt] = __builtin_amdgcn_mfma_f32_16x16x32_bf16(a0, wf[kc][dt], acc[0][dt], 0, 0, 0);
            acc[1][dt] = __builtin_amdgcn_mfma_f32_16x16x32_bf16(a1, wf[kc][dt], acc[1][dt], 0, 0, 0);
        }
    }
#pragma unroll
    for (int mt = 0; mt < 2; ++mt)
#pragma unroll
        for (int r = 0; r < 4; ++r) {
            const size_t grow = r0 + mt * 16 + 4 * quad + r;
#pragma unroll
            for (int dt = 0; dt < 2; ++dt) {
                float v = acc[mt][dt][r] + bv[dt];
                if (EP == 1) v = fmaxf(v, 0.0f);
                ((unsigned short*)Cout)[grow * DD + c0w + dt * 16 + l15] = f2bf(v);
            }
        }
}

// Fused QKV projections: grid (512, 3); y selects {Q->Qp, K->Kp, K->Vp}.
__global__ __launch_bounds__(256, 4) void qkv_mfma(
        const float* __restrict__ Q, const float* __restrict__ K,
        const unsigned short* __restrict__ WT5,
        const float* __restrict__ bq, const float* __restrict__ bk,
        const float* __restrict__ bv,
        unsigned short* __restrict__ Qp, unsigned short* __restrict__ Kp,
        unsigned short* __restrict__ Vp) {
    const int z = blockIdx.y;
    const float* A = (z == 0) ? Q : K;
    const float* bias = (z == 0) ? bq : (z == 1) ? bk : bv;
    unsigned short* C = (z == 0) ? Qp : (z == 1) ? Kp : Vp;
    gemm32_body<0, 0>(A, WT5 + z * 65536, bias, C, blockIdx.x);
}

// FFN1: H1 = relu(O @ W1 + b1), O fp32.
__global__ __launch_bounds__(256, 4) void ffn1_mfma(
        const float* __restrict__ O, const unsigned short* __restrict__ WT1,
        const float* __restrict__ b1, unsigned short* __restrict__ H1) {
    gemm32_body<0, 1>(O, WT1, b1, H1, blockIdx.x);
}

// ---------------------------------------------------------------------------
// FFN2 + residual + LayerNorm fused: out = LN(R + A@W2 + b2), fp32 out.
// Block = 16 rows x 256 cols, 8 waves (wave = 16x32), W-frags hoisted.
// ---------------------------------------------------------------------------
__global__ __launch_bounds__(512, 4) void gemm_ffn2_ln(
        const unsigned short* __restrict__ Ain, const unsigned short* __restrict__ WT,
        const float* __restrict__ bias, const float* __restrict__ R,
        const float* __restrict__ g, const float* __restrict__ be,
        float* __restrict__ out) {
    __shared__ unsigned short As[16 * 264];
    __shared__ float lnb[2][8][16];
    const int tid = threadIdx.x;
    const int lane = tid & 63, w = tid >> 6;          // w in 0..7
    const int l15 = lane & 15, quad = lane >> 4;
    const int r0 = blockIdx.x * 16;
    const int c0w = w * 32;
    short8 wf[8][2];
#pragma unroll
    for (int kc = 0; kc < 8; ++kc)
#pragma unroll
        for (int dt = 0; dt < 2; ++dt)
            wf[kc][dt] = *(const short8*)(WT + (size_t)(c0w + dt * 16 + l15) * DD + kc * 32 + 8 * quad);
    float bv[2], gv[2], ev[2];
#pragma unroll
    for (int dt = 0; dt < 2; ++dt) {
        int col = c0w + dt * 16 + l15;
        bv[dt] = bias[col]; gv[dt] = g[col]; ev[dt] = be[col];
    }
    {   // stage A: 512 threads x 16B
        int row = tid >> 5, c0 = (tid & 31) * 8;
        *(short8*)(As + row * 264 + c0) = *(const short8*)(Ain + (size_t)(r0 + row) * DD + c0);
    }
    __syncthreads();
    fx4 acc[2];
#pragma unroll
    for (int i = 0; i < 2; ++i) acc[i] = (fx4){0.f, 0.f, 0.f, 0.f};
#pragma unroll
    for (int kc = 0; kc < 8; ++kc) {
        short8 a = *(const short8*)(As + l15 * 264 + kc * 32 + 8 * quad);
#pragma unroll
        for (int dt = 0; dt < 2; ++dt)
            acc[dt] = __builtin_amdgcn_mfma_f32_16x16x32_bf16(a, wf[kc][dt], acc[dt], 0, 0, 0);
    }
    float v[4][2], p1[4], p2[4];
#pragma unroll
    for (int r = 0; r < 4; ++r) {
        p1[r] = 0.f; p2[r] = 0.f;
        const size_t grow = r0 + 4 * quad + r;
#pragma unroll
        for (int dt = 0; dt < 2; ++dt) {
            float x = acc[dt][r] + bv[dt] + R[grow * DD + c0w + dt * 16 + l15];
            v[r][dt] = x; p1[r] += x; p2[r] += x * x;
        }
    }
#pragma unroll
    for (int r = 0; r < 4; ++r) {
#pragma unroll
        for (int off = 1; off <= 8; off <<= 1) {
            p1[r] += __shfl_xor(p1[r], off);
            p2[r] += __shfl_xor(p2[r], off);
        }
    }
    if (l15 == 0) {
#pragma unroll
        for (int r = 0; r < 4; ++r) {
            lnb[0][w][4 * quad + r] = p1[r];
            lnb[1][w][4 * quad + r] = p2[r];
        }
    }
    __syncthreads();
#pragma unroll
    for (int r = 0; r < 4; ++r) {
        const int row = 4 * quad + r;
        float s1 = 0.f, s2 = 0.f;
#pragma unroll
        for (int ww = 0; ww < 8; ++ww) { s1 += lnb[0][ww][row]; s2 += lnb[1][ww][row]; }
        float mean = s1 * (1.0f / 256.0f);
        float var  = s2 * (1.0f / 256.0f) - mean * mean;
        float rstd = rsqrtf(var + 1e-5f);
        const size_t grow = r0 + row;
#pragma unroll
        for (int dt = 0; dt < 2; ++dt)
            out[grow * DD + c0w + dt * 16 + l15] = (v[r][dt] - mean) * rstd * gv[dt] + ev[dt];
    }
}

// ---------------------------------------------------------------------------
// Flash attention, O^T form, no-max softmax. r13: LDS-shared K/V tiles with
// XOR swizzle e' = e ^ (((e>>6)&3)<<3) on BOTH stage-write and frag-read.
// Block = 64 q-rows, 4 waves = 4 q-subtiles; every wave sweeps all 64
// key-tiles; double-buffered LDS staging, one barrier per tile.
// ---------------------------------------------------------------------------
__global__ __launch_bounds__(256, 2) void attn_mfma(
        const unsigned short* __restrict__ Qp, const unsigned short* __restrict__ KT,
        const unsigned short* __restrict__ VT2, float* __restrict__ Opre) {
    __shared__ unsigned short kbuf[2][2048];  // K tile double buffer (4KB ea)
    __shared__ unsigned short vbuf[2][2048];  // V tile double buffer
    __shared__ unsigned int pbuf[4][256];     // per-wave P exchange, pitch 16 dw
    const int tid = threadIdx.x;
    const int lane = tid & 63, w = tid >> 6;  // w = q-subtile
    const int l15 = lane & 15, quad = lane >> 4;
    const int gb = blockIdx.x;                // 0..511
    const int bh = ((gb & 7) << 1) | ((gb >> 8) & 1);   // XCD-locality swizzle
    const int qc = (gb >> 3) & 31;
    const int h  = bh & 3;
    const int b  = bh >> 2;
    const int qrow = qc * 64 + w * 16;
    const int sw = 4 * ((l15 >> 1) & 3);                // pbuf bank swizzle

    short8 aq0, aq1;
    {
        const unsigned short* qptr = Qp + ((size_t)(b * NN + qrow + l15) * DD + h * DHH + 8 * quad);
        aq0 = *(const short8*)qptr;
        aq1 = *(const short8*)(qptr + 32);
    }
    fx4 od0 = (fx4){0.f, 0.f, 0.f, 0.f};
    fx4 od1 = (fx4){0.f, 0.f, 0.f, 0.f};
    fx4 od2 = (fx4){0.f, 0.f, 0.f, 0.f};
    fx4 od3 = (fx4){0.f, 0.f, 0.f, 0.f};
    float lsum = 0.0f;

    unsigned int* pw = &pbuf[w][0];
    const int wcol = (2 * quad) ^ sw;         // write cols (pairs t=2q,2q+1 / +8)
    const int rcol = (4 * quad) ^ sw;         // read col group (t=4Q..4Q+3)
    const unsigned short* ktb = KT  + (size_t)bh * 64 * 2048 + tid * 8;  // stage src
    const unsigned short* vtb = VT2 + (size_t)bh * 64 * 2048 + tid * 8;
    // K/V tile swizzle: element e -> e ^ (((e>>6)&3)<<3)  (byte[5:4]^=byte[8:7])
    const int ew = (tid * 8) ^ (((tid >> 3) & 3) << 3);          // stage-write dst
    const int fo = (l15 * 32 + 8 * quad) ^ (((l15 >> 1) & 3) << 3); // frag-read base

    // prologue: stage tile 0 into buffer 0
    {
        uint4v kr = *(const uint4v*)ktb;
        uint4v vr = *(const uint4v*)vtb;
        *(uint4v*)&kbuf[0][ew] = kr;
        *(uint4v*)&vbuf[0][ew] = vr;
    }
    __syncthreads();

    for (int t = 0; t < 64; ++t) {
        const int cur = t & 1;
        const int tn = (t < 63) ? t + 1 : 63;           // clamp (last redundant)
        // issue next-tile global loads FIRST (T14 async split: write after compute)
        uint4v kr = *(const uint4v*)(ktb + (size_t)tn * 2048);
        uint4v vr = *(const uint4v*)(vtb + (size_t)tn * 2048);

        // ---- compute tile t from LDS ----
        const unsigned short* kb = &kbuf[cur][fo];
        short8 ck0 = *(const short8*)(kb);          // keys l15,    d 8q..8q+7
        short8 ck1 = *(const short8*)(kb + 1024);   // keys l15,    d 32+8q..
        short8 ck2 = *(const short8*)(kb + 512);    // keys 16+l15, d 8q..
        short8 ck3 = *(const short8*)(kb + 1536);   // keys 16+l15, d 32+8q..
        const unsigned short* vb = &vbuf[cur][fo];
        short8 cv0 = *(const short8*)(vb);          // d l15,    keys 8q..8q+7
        short8 cv1 = *(const short8*)(vb + 512);    // d 16+l15
        short8 cv2 = *(const short8*)(vb + 1024);   // d 32+l15
        short8 cv3 = *(const short8*)(vb + 1536);   // d 48+l15

        const fx4 z_ = (fx4){0.f, 0.f, 0.f, 0.f};
        fx4 s0 = __builtin_amdgcn_mfma_f32_16x16x32_bf16(ck0, aq0, z_, 0, 0, 0);
        s0     = __builtin_amdgcn_mfma_f32_16x16x32_bf16(ck1, aq1, s0, 0, 0, 0);
        fx4 s1 = __builtin_amdgcn_mfma_f32_16x16x32_bf16(ck2, aq0, z_, 0, 0, 0);
        s1     = __builtin_amdgcn_mfma_f32_16x16x32_bf16(ck3, aq1, s1, 0, 0, 0);
        s0[0] = __expf(s0[0] * 0.125f); s0[1] = __expf(s0[1] * 0.125f);
        s0[2] = __expf(s0[2] * 0.125f); s0[3] = __expf(s0[3] * 0.125f);
        s1[0] = __expf(s1[0] * 0.125f); s1[1] = __expf(s1[1] * 0.125f);
        s1[2] = __expf(s1[2] * 0.125f); s1[3] = __expf(s1[3] * 0.125f);
        lsum += s0[0] + s0[1] + s0[2] + s0[3];
        lsum += s1[0] + s1[1] + s1[2] + s1[3];
        uint2v w1_ = (uint2v){packbf(s0[0], s0[1]), packbf(s0[2], s0[3])};
        uint2v w2_ = (uint2v){packbf(s1[0], s1[1]), packbf(s1[2], s1[3])};
        *(uint2v*)(pw + l15 * 16 + wcol)       = w1_;   // pairs t=2q,2q+1
        *(uint2v*)(pw + l15 * 16 + (wcol ^ 8)) = w2_;   // pairs t=8+2q,8+2q+1
        short8 bp = *(const short8*)(pw + l15 * 16 + rcol);  // keys 8*quad..+7
        od0 = __builtin_amdgcn_mfma_f32_16x16x32_bf16(cv0, bp, od0, 0, 0, 0);
        od1 = __builtin_amdgcn_mfma_f32_16x16x32_bf16(cv1, bp, od1, 0, 0, 0);
        od2 = __builtin_amdgcn_mfma_f32_16x16x32_bf16(cv2, bp, od2, 0, 0, 0);
        od3 = __builtin_amdgcn_mfma_f32_16x16x32_bf16(cv3, bp, od3, 0, 0, 0);

        // ---- land next tile into the other buffer, then sync ----
        *(uint4v*)&kbuf[cur ^ 1][ew] = kr;
        *(uint4v*)&vbuf[cur ^ 1][ew] = vr;
        __syncthreads();
    }

    // per-q total l (sum over quads); each wave owns its rows completely
    lsum += __shfl_xor(lsum, 16);
    lsum += __shfl_xor(lsum, 32);
    const float inv = 1.0f / lsum;
    const size_t grow = (size_t)(b * NN) + qrow + l15;
    float* obase = Opre + grow * DD + h * DHH;
    const unsigned short* qpb = Qp + grow * DD + h * DHH;
#define OUT_DT(DT, OD) do {                                                   \
        shortx4 rv_ = *(const shortx4*)(qpb + (DT) * 16 + 4 * quad);          \
        fx4 o_;                                                               \
        o_[0] = OD[0] * inv + bf2f((unsigned short)rv_[0]);                   \
        o_[1] = OD[1] * inv + bf2f((unsigned short)rv_[1]);                   \
        o_[2] = OD[2] * inv + bf2f((unsigned short)rv_[2]);                   \
        o_[3] = OD[3] * inv + bf2f((unsigned short)rv_[3]);                   \
        *(fx4*)(obase + (DT) * 16 + 4 * quad) = o_;                           \
    } while (0)
    OUT_DT(0, od0);
    OUT_DT(1, od1);
    OUT_DT(2, od2);
    OUT_DT(3, od3);
#undef OUT_DT
}

// row LayerNorm: Y = LN(X)*g+be (fp32)
__global__ __launch_bounds__(64) void ln_rows(
        const float* __restrict__ X, const float* __restrict__ g,
        const float* __restrict__ be, float* __restrict__ Y) {
    const int lane = threadIdx.x;
    const size_t row = blockIdx.x;
    fx4 v = ((const fx4*)(X + row * DD))[lane];
    float s1 = v[0]+v[1]+v[2]+v[3];
    float s2 = v[0]*v[0]+v[1]*v[1]+v[2]*v[2]+v[3]*v[3];
#pragma unroll
    for (int off = 32; off >= 1; off >>= 1) {
        s1 += __shfl_xor(s1, off); s2 += __shfl_xor(s2, off);
    }
    float mean = s1 * (1.0f/256.0f);
    float var  = s2 * (1.0f/256.0f) - mean * mean;
    float rstd = rsqrtf(var + 1e-5f);
    fx4 gv = ((const fx4*)g)[lane];
    fx4 ev = ((const fx4*)be)[lane];
    fx4 o;
#pragma unroll
    for (int i = 0; i < 4; ++i) o[i] = (v[i]-mean)*rstd*gv[i] + ev[i];
    ((fx4*)(Y + row * DD))[lane] = o;
}

extern "C" void kernel_launch(void* const* d_in, const int* in_sizes, int n_in,
                              void* d_out, int out_size, void* d_ws, size_t ws_size,
                              hipStream_t stream) {
    (void)in_sizes; (void)n_in; (void)out_size; (void)ws_size;
    const float* Q     = (const float*)d_in[0];
    const float* K     = (const float*)d_in[1];
    const float* Wq    = (const float*)d_in[2];
    const float* bq    = (const float*)d_in[3];
    const float* Wk    = (const float*)d_in[4];
    const float* bk    = (const float*)d_in[5];
    const float* Wv    = (const float*)d_in[6];
    const float* bv    = (const float*)d_in[7];
    const float* W1    = (const float*)d_in[8];
    const float* b1    = (const float*)d_in[9];
    const float* W2    = (const float*)d_in[10];
    const float* b2    = (const float*)d_in[11];
    const float* g0    = (const float*)d_in[12];
    const float* beta0 = (const float*)d_in[13];
    const float* g1    = (const float*)d_in[14];
    const float* beta1 = (const float*)d_in[15];

    // Workspace: [0,4)Mi Qp bf16 (later H1 bf16); [4,8)Mi Kp; [8,12)Mi Vp
    // (reused as KT after vt_prep); [12,16)Mi VT2; [16,24)Mi Opre f32;
    // [24,32)Mi O f32; [32Mi,+640K) WT x5
    char* ws = (char*)d_ws;
    unsigned short* Qp  = (unsigned short*)(ws);
    unsigned short* Kp  = (unsigned short*)(ws + (4u  << 20));
    unsigned short* Vp  = (unsigned short*)(ws + (8u  << 20));
    unsigned short* KT  = Vp;                       // overlays Vp (dead after vt_prep)
    unsigned short* VT2 = (unsigned short*)(ws + (12u << 20));
    float*          Opre= (float*)(ws + (16u << 20));
    float*          O   = (float*)(ws + (24u << 20));
    unsigned short* WT5 = (unsigned short*)(ws + (32u << 20));
    unsigned short* H1  = Qp;
    float*          out = (float*)d_out;

    const unsigned short* WT1 = WT5 + 3 * 65536;
    const unsigned short* WT2 = WT5 + 4 * 65536;

    const int M = BB * NN;                        // 8192 rows

    wt_prep<<<dim3(4, 4, 5), 256, 0, stream>>>(Wq, Wk, Wv, W1, W2, WT5);
    qkv_mfma<<<dim3(M / 16, 3), 256, 0, stream>>>(Q, K, WT5, bq, bk, bv, Qp, Kp, Vp);
    vt_prep<<<dim3(128, 4), 256, 0, stream>>>(Vp, VT2);
    kt_prep<<<1024, 256, 0, stream>>>(Kp, KT);    // overwrites Vp slot (Vp dead)
    attn_mfma<<<512, 256, 0, stream>>>(Qp, KT, VT2, Opre);
    ln_rows<<<M, 64, 0, stream>>>(Opre, g0, beta0, O);
    ffn1_mfma<<<M / 16, 256, 0, stream>>>(O, WT1, b1, H1);
    gemm_ffn2_ln<<<M / 16, 512, 0, stream>>>(H1, WT2, b2, O, g1, beta1, out);
}

// Round 8
// 178.775 us; speedup vs baseline: 1.2124x; 1.0798x over previous
//
#include <hip/hip_runtime.h>

// MAB block, MFMA bf16, round 14: key-split grid 1024 + merge in ln_rows.
// r13 post-mortem: K/V swizzle killed the bank conflicts (5.24M->1.05M) but
// time barely moved (53.2->51.5us) -> conflicts were off the critical path.
// Occupancy 19% (grid 512 = 2 blocks/CU) with a barrier-serialized per-tile
// chain (~500-700cy) = latency-bound with only 2-way overlap.
// r14: block = 64 q-rows x 1024 keys (kh half), grid 1024 -> 4 blocks/CU,
// 16 waves/CU; L2 stage traffic unchanged (each block stages its 32 tiles).
// kh partials (unnormalized od, per-head l) land in the Opre/O slots + dead
// Kp region; ln_rows merges (od0+od1)/(l0+l1) + Qp residual, then LN.

typedef float fx4 __attribute__((ext_vector_type(4)));
typedef short short8 __attribute__((ext_vector_type(8)));
typedef short shortx4 __attribute__((ext_vector_type(4)));
typedef unsigned int uint2v __attribute__((ext_vector_type(2)));
typedef unsigned int uint4v __attribute__((ext_vector_type(4)));

#define BB  4
#define NN  2048
#define DD  256
#define HH  4
#define DHH 64

__device__ __forceinline__ float bf2f(unsigned short u) {
    union { unsigned int i; float f; } v; v.i = ((unsigned int)u) << 16; return v.f;
}
__device__ __forceinline__ unsigned short f2bf(float f) {
    union { float f; unsigned int i; } v; v.f = f;
    unsigned int r = v.i + 0x7FFF + ((v.i >> 16) & 1);   // RNE
    return (unsigned short)(r >> 16);
}
__device__ __forceinline__ unsigned int fbits(float f) {
    union { float f; unsigned int i; } v; v.f = f; return v.i;
}
__device__ __forceinline__ unsigned int packbf(float lo, float hi) {
    unsigned int a = fbits(lo), b = fbits(hi);
    a = (a + 0x7FFF + ((a >> 16) & 1)) >> 16;
    b = (b + 0x7FFF + ((b >> 16) & 1)) & 0xFFFF0000u;
    return a | b;
}

// ---------------------------------------------------------------------------
// Weight prep: WT[n][k] = bf16(W[k][n]) for the 5 weight matrices (256x256).
// ---------------------------------------------------------------------------
__global__ __launch_bounds__(256) void wt_prep(
        const float* __restrict__ w0, const float* __restrict__ w1,
        const float* __restrict__ w2, const float* __restrict__ w3,
        const float* __restrict__ w4, unsigned short* __restrict__ dst) {
    __shared__ unsigned short T[64 * 73];
    const int tid = threadIdx.x;
    const int z = blockIdx.z;
    const float* W = (z == 0) ? w0 : (z == 1) ? w1 : (z == 2) ? w2 : (z == 3) ? w3 : w4;
    unsigned short* WT = dst + z * 65536;
    const int nb = blockIdx.x * 64, kb = blockIdx.y * 64;
    {
        int kl = tid >> 2, c0 = (tid & 3) * 16;
        const float* src = W + (size_t)(kb + kl) * DD + nb + c0;
#pragma unroll
        for (int i = 0; i < 16; ++i) T[kl * 73 + c0 + i] = f2bf(src[i]);
    }
    __syncthreads();
    {
        int nl = tid >> 2, k0 = (tid & 3) * 16;
        short8 o0, o1;
#pragma unroll
        for (int i = 0; i < 8; ++i) {
            o0[i] = (short)T[(k0 + i) * 73 + nl];
            o1[i] = (short)T[(k0 + 8 + i) * 73 + nl];
        }
        short8* d = (short8*)(WT + (size_t)(nb + nl) * DD + kb + k0);
        d[0] = o0; d[1] = o1;
    }
}

// ---------------------------------------------------------------------------
// V tile-transpose: VT2[bh][tile][d64][key32] <- Vp[b*2048+key][h*64+d].
// grid(128,4): b = bx>>5, keyb = (bx&31)*64 (2 tiles), hb = by.
// ---------------------------------------------------------------------------
__global__ __launch_bounds__(256) void vt_prep(
        const unsigned short* __restrict__ Vp, unsigned short* __restrict__ VT2) {
    __shared__ unsigned short T[64 * 73];
    const int tid = threadIdx.x;
    const int hb = blockIdx.y;
    const int b = blockIdx.x >> 5;
    const int keyb = (blockIdx.x & 31) * 64;
    const int bh = b * HH + hb;
    {
        int kl = tid >> 2, c0 = (tid & 3) * 16;
        const short8* src = (const short8*)(Vp + (size_t)(b * NN + keyb + kl) * DD + hb * DHH + c0);
        short8 v0 = src[0], v1 = src[1];
#pragma unroll
        for (int i = 0; i < 8; ++i) {
            T[kl * 73 + c0 + i]     = (unsigned short)v0[i];
            T[kl * 73 + c0 + 8 + i] = (unsigned short)v1[i];
        }
    }
    __syncthreads();
    {
        int dl = tid >> 2, k0 = (tid & 3) * 16;          // d row, key chunk (16)
        short8 o0, o1;
#pragma unroll
        for (int i = 0; i < 8; ++i) {
            o0[i] = (short)T[(k0 + i) * 73 + dl];
            o1[i] = (short)T[(k0 + 8 + i) * 73 + dl];
        }
        const int gkey = keyb + k0;                       // multiple of 16
        const int tl = gkey >> 5;                         // tile index
        const int kin = gkey & 31;                        // 0 or 16
        short8* d = (short8*)(VT2 + ((size_t)(bh * 64 + tl) * 64 + dl) * 32 + kin);
        d[0] = o0; d[1] = o1;
    }
}

// ---------------------------------------------------------------------------
// K tile-permute: KT[bh][tile][dhalf][key32][d32] <- Kp[b*2048+key][h*64+d].
// Pure 16B-chunk permutation; grid 1024 = bh*64 + tile, 256 threads.
// ---------------------------------------------------------------------------
__global__ __launch_bounds__(256) void kt_prep(
        const unsigned short* __restrict__ Kp, unsigned short* __restrict__ KT) {
    const int bh = blockIdx.x >> 6;
    const int tl = blockIdx.x & 63;
    const int b = bh >> 2, h = bh & 3;
    const int tid = threadIdx.x;
    const int key = tid >> 3, p = tid & 7;
    short8 v = *(const short8*)(Kp + (size_t)(b * NN + tl * 32 + key) * DD + h * DHH + p * 8);
    unsigned short* dst = KT + (size_t)(bh * 64 + tl) * 2048
                        + (p >> 2) * 1024 + key * 32 + (p & 3) * 8;
    *(short8*)dst = v;
}

// ---------------------------------------------------------------------------
// 32-row GEMM body: C[r0..r0+32, c-half] = A @ W + bias. 4 waves, wave =
// 32 rows x 32 cols. W-frags hoisted. AIN: 0 fp32 A, 1 bf16 A.
// EP: 0 bias->bf16, 1 relu->bf16.
// ---------------------------------------------------------------------------
template<int AIN, int EP>
__device__ __forceinline__ void gemm32_body(
        const void* __restrict__ Ain, const unsigned short* __restrict__ WT,
        const float* __restrict__ bias, void* __restrict__ Cout, int bx) {
    __shared__ unsigned short As[32 * 264];
    const int tid = threadIdx.x;
    const int lane = tid & 63, w = tid >> 6;
    const int l15 = lane & 15, quad = lane >> 4;
    const int r0 = (bx >> 1) * 32;
    const int c0w = (bx & 1) * 128 + w * 32;
    short8 wf[8][2];
#pragma unroll
    for (int kc = 0; kc < 8; ++kc)
#pragma unroll
        for (int dt = 0; dt < 2; ++dt)
            wf[kc][dt] = *(const short8*)(WT + (size_t)(c0w + dt * 16 + l15) * DD + kc * 32 + 8 * quad);
    float bv[2];
#pragma unroll
    for (int dt = 0; dt < 2; ++dt) bv[dt] = bias[c0w + dt * 16 + l15];
    {   // stage A tile (32 x 256) as bf16; thread: 32 elems
        int row = tid >> 3, c0 = (tid & 7) * 32;
        short8 o[4];
        if (AIN == 0) {
            const fx4* s4 = (const fx4*)((const float*)Ain + (size_t)(r0 + row) * DD + c0);
#pragma unroll
            for (int j = 0; j < 4; ++j) {
                fx4 v0 = s4[2 * j], v1 = s4[2 * j + 1];
#pragma unroll
                for (int i = 0; i < 4; ++i) {
                    o[j][i]     = (short)f2bf(v0[i]);
                    o[j][i + 4] = (short)f2bf(v1[i]);
                }
            }
        } else {
            const short8* s8 = (const short8*)((const unsigned short*)Ain + (size_t)(r0 + row) * DD + c0);
#pragma unroll
            for (int j = 0; j < 4; ++j) o[j] = s8[j];
        }
        short8* d = (short8*)(As + row * 264 + c0);
#pragma unroll
        for (int j = 0; j < 4; ++j) d[j] = o[j];
    }
    __syncthreads();
    fx4 acc[2][2];
#pragma unroll
    for (int mt = 0; mt < 2; ++mt)
#pragma unroll
        for (int dt = 0; dt < 2; ++dt) acc[mt][dt] = (fx4){0.f, 0.f, 0.f, 0.f};
#pragma unroll
    for (int kc = 0; kc < 8; ++kc) {
        short8 a0 = *(const short8*)(As + l15 * 264 + kc * 32 + 8 * quad);
        short8 a1 = *(const short8*)(As + (16 + l15) * 264 + kc * 32 + 8 * quad);
#pragma unroll
        for (int dt = 0; dt < 2; ++dt) {
            acc[0][dt] = __builtin_amdgcn_mfma_f32_16x16x32_bf16(a0, wf[kc][dt], acc[0][dt], 0, 0, 0);
            acc[1][dt] = __builtin_amdgcn_mfma_f32_16x16x32_bf16(a1, wf[kc][dt], acc[1][dt], 0, 0, 0);
        }
    }
#pragma unroll
    for (int mt = 0; mt < 2; ++mt)
#pragma unroll
        for (int r = 0; r < 4; ++r) {
            const size_t grow = r0 + mt * 16 + 4 * quad + r;
#pragma unroll
            for (int dt = 0; dt < 2; ++dt) {
                float v = acc[mt][dt][r] + bv[dt];
                if (EP == 1) v = fmaxf(v, 0.0f);
                ((unsigned short*)Cout)[grow * DD + c0w + dt * 16 + l15] = f2bf(v);
            }
        }
}

// Fused QKV projections: grid (512, 3); y selects {Q->Qp, K->Kp, K->Vp}.
__global__ __launch_bounds__(256, 4) void qkv_mfma(
        const float* __restrict__ Q, const float* __restrict__ K,
        const unsigned short* __restrict__ WT5,
        const float* __restrict__ bq, const float* __restrict__ bk,
        const float* __restrict__ bv,
        unsigned short* __restrict__ Qp, unsigned short* __restrict__ Kp,
        unsigned short* __restrict__ Vp) {
    const int z = blockIdx.y;
    const float* A = (z == 0) ? Q : K;
    const float* bias = (z == 0) ? bq : (z == 1) ? bk : bv;
    unsigned short* C = (z == 0) ? Qp : (z == 1) ? Kp : Vp;
    gemm32_body<0, 0>(A, WT5 + z * 65536, bias, C, blockIdx.x);
}

// FFN1: H1 = relu(O @ W1 + b1), O fp32.
__global__ __launch_bounds__(256, 4) void ffn1_mfma(
        const float* __restrict__ O, const unsigned short* __restrict__ WT1,
        const float* __restrict__ b1, unsigned short* __restrict__ H1) {
    gemm32_body<0, 1>(O, WT1, b1, H1, blockIdx.x);
}

// ---------------------------------------------------------------------------
// FFN2 + residual + LayerNorm fused: out = LN(R + A@W2 + b2), fp32 out.
// Block = 16 rows x 256 cols, 8 waves (wave = 16x32), W-frags hoisted.
// ---------------------------------------------------------------------------
__global__ __launch_bounds__(512, 4) void gemm_ffn2_ln(
        const unsigned short* __restrict__ Ain, const unsigned short* __restrict__ WT,
        const float* __restrict__ bias, const float* __restrict__ R,
        const float* __restrict__ g, const float* __restrict__ be,
        float* __restrict__ out) {
    __shared__ unsigned short As[16 * 264];
    __shared__ float lnb[2][8][16];
    const int tid = threadIdx.x;
    const int lane = tid & 63, w = tid >> 6;          // w in 0..7
    const int l15 = lane & 15, quad = lane >> 4;
    const int r0 = blockIdx.x * 16;
    const int c0w = w * 32;
    short8 wf[8][2];
#pragma unroll
    for (int kc = 0; kc < 8; ++kc)
#pragma unroll
        for (int dt = 0; dt < 2; ++dt)
            wf[kc][dt] = *(const short8*)(WT + (size_t)(c0w + dt * 16 + l15) * DD + kc * 32 + 8 * quad);
    float bv[2], gv[2], ev[2];
#pragma unroll
    for (int dt = 0; dt < 2; ++dt) {
        int col = c0w + dt * 16 + l15;
        bv[dt] = bias[col]; gv[dt] = g[col]; ev[dt] = be[col];
    }
    {   // stage A: 512 threads x 16B
        int row = tid >> 5, c0 = (tid & 31) * 8;
        *(short8*)(As + row * 264 + c0) = *(const short8*)(Ain + (size_t)(r0 + row) * DD + c0);
    }
    __syncthreads();
    fx4 acc[2];
#pragma unroll
    for (int i = 0; i < 2; ++i) acc[i] = (fx4){0.f, 0.f, 0.f, 0.f};
#pragma unroll
    for (int kc = 0; kc < 8; ++kc) {
        short8 a = *(const short8*)(As + l15 * 264 + kc * 32 + 8 * quad);
#pragma unroll
        for (int dt = 0; dt < 2; ++dt)
            acc[dt] = __builtin_amdgcn_mfma_f32_16x16x32_bf16(a, wf[kc][dt], acc[dt], 0, 0, 0);
    }
    float v[4][2], p1[4], p2[4];
#pragma unroll
    for (int r = 0; r < 4; ++r) {
        p1[r] = 0.f; p2[r] = 0.f;
        const size_t grow = r0 + 4 * quad + r;
#pragma unroll
        for (int dt = 0; dt < 2; ++dt) {
            float x = acc[dt][r] + bv[dt] + R[grow * DD + c0w + dt * 16 + l15];
            v[r][dt] = x; p1[r] += x; p2[r] += x * x;
        }
    }
#pragma unroll
    for (int r = 0; r < 4; ++r) {
#pragma unroll
        for (int off = 1; off <= 8; off <<= 1) {
            p1[r] += __shfl_xor(p1[r], off);
            p2[r] += __shfl_xor(p2[r], off);
        }
    }
    if (l15 == 0) {
#pragma unroll
        for (int r = 0; r < 4; ++r) {
            lnb[0][w][4 * quad + r] = p1[r];
            lnb[1][w][4 * quad + r] = p2[r];
        }
    }
    __syncthreads();
#pragma unroll
    for (int r = 0; r < 4; ++r) {
        const int row = 4 * quad + r;
        float s1 = 0.f, s2 = 0.f;
#pragma unroll
        for (int ww = 0; ww < 8; ++ww) { s1 += lnb[0][ww][row]; s2 += lnb[1][ww][row]; }
        float mean = s1 * (1.0f / 256.0f);
        float var  = s2 * (1.0f / 256.0f) - mean * mean;
        float rstd = rsqrtf(var + 1e-5f);
        const size_t grow = r0 + row;
#pragma unroll
        for (int dt = 0; dt < 2; ++dt)
            out[grow * DD + c0w + dt * 16 + l15] = (v[r][dt] - mean) * rstd * gv[dt] + ev[dt];
    }
}

// ---------------------------------------------------------------------------
// Flash attention, O^T form, no-max softmax. r14: key-split halves.
// Block = 64 q-rows x 1024 keys (kh half), grid 1024 -> 4 blocks/CU.
// 4 waves = 4 q-subtiles; each wave sweeps its half's 32 key-tiles from
// double-buffered, XOR-swizzled LDS (one barrier/tile). Outputs UNNORMALIZED
// partial O^T to Od[kh] and per-(row,head) partial l to Lp[kh]; the merge
// (sum, 1/l, +Qp residual) happens in ln_rows.
// ---------------------------------------------------------------------------
__global__ __launch_bounds__(256, 2) void attn_mfma(
        const unsigned short* __restrict__ Qp, const unsigned short* __restrict__ KT,
        const unsigned short* __restrict__ VT2, float* __restrict__ Od0,
        float* __restrict__ Od1, float* __restrict__ Lp) {
    __shared__ unsigned short kbuf[2][2048];  // K tile double buffer (4KB ea)
    __shared__ unsigned short vbuf[2][2048];  // V tile double buffer
    __shared__ unsigned int pbuf[4][256];     // per-wave P exchange, pitch 16 dw
    const int tid = threadIdx.x;
    const int lane = tid & 63, w = tid >> 6;  // w = q-subtile
    const int l15 = lane & 15, quad = lane >> 4;
    const int gb = blockIdx.x;                // 0..1023
    const int bh = ((gb & 7) << 1) | ((gb >> 9) & 1);   // XCD-locality swizzle
    const int qc = (gb >> 3) & 31;
    const int kh = (gb >> 8) & 1;                       // key half
    const int h  = bh & 3;
    const int b  = bh >> 2;
    const int qrow = qc * 64 + w * 16;
    const int sw = 4 * ((l15 >> 1) & 3);                // pbuf bank swizzle

    short8 aq0, aq1;
    {
        const unsigned short* qptr = Qp + ((size_t)(b * NN + qrow + l15) * DD + h * DHH + 8 * quad);
        aq0 = *(const short8*)qptr;
        aq1 = *(const short8*)(qptr + 32);
    }
    fx4 od0 = (fx4){0.f, 0.f, 0.f, 0.f};
    fx4 od1 = (fx4){0.f, 0.f, 0.f, 0.f};
    fx4 od2 = (fx4){0.f, 0.f, 0.f, 0.f};
    fx4 od3 = (fx4){0.f, 0.f, 0.f, 0.f};
    float lsum = 0.0f;

    unsigned int* pw = &pbuf[w][0];
    const int wcol = (2 * quad) ^ sw;         // write cols (pairs t=2q,2q+1 / +8)
    const int rcol = (4 * quad) ^ sw;         // read col group (t=4Q..4Q+3)
    const unsigned short* ktb = KT  + (size_t)(bh * 64 + kh * 32) * 2048 + tid * 8;
    const unsigned short* vtb = VT2 + (size_t)(bh * 64 + kh * 32) * 2048 + tid * 8;
    // K/V tile swizzle: element e -> e ^ (((e>>6)&3)<<3)  (byte[5:4]^=byte[8:7])
    const int ew = (tid * 8) ^ (((tid >> 3) & 3) << 3);          // stage-write dst
    const int fo = (l15 * 32 + 8 * quad) ^ (((l15 >> 1) & 3) << 3); // frag-read base

    // prologue: stage tile 0 into buffer 0
    {
        uint4v kr = *(const uint4v*)ktb;
        uint4v vr = *(const uint4v*)vtb;
        *(uint4v*)&kbuf[0][ew] = kr;
        *(uint4v*)&vbuf[0][ew] = vr;
    }
    __syncthreads();

    for (int t = 0; t < 32; ++t) {
        const int cur = t & 1;
        const int tn = (t < 31) ? t + 1 : 31;           // clamp (last redundant)
        // issue next-tile global loads FIRST (T14 async split: write after compute)
        uint4v kr = *(const uint4v*)(ktb + (size_t)tn * 2048);
        uint4v vr = *(const uint4v*)(vtb + (size_t)tn * 2048);

        // ---- compute tile t from LDS ----
        const unsigned short* kb = &kbuf[cur][fo];
        short8 ck0 = *(const short8*)(kb);          // keys l15,    d 8q..8q+7
        short8 ck1 = *(const short8*)(kb + 1024);   // keys l15,    d 32+8q..
        short8 ck2 = *(const short8*)(kb + 512);    // keys 16+l15, d 8q..
        short8 ck3 = *(const short8*)(kb + 1536);   // keys 16+l15, d 32+8q..
        const unsigned short* vb = &vbuf[cur][fo];
        short8 cv0 = *(const short8*)(vb);          // d l15,    keys 8q..8q+7
        short8 cv1 = *(const short8*)(vb + 512);    // d 16+l15
        short8 cv2 = *(const short8*)(vb + 1024);   // d 32+l15
        short8 cv3 = *(const short8*)(vb + 1536);   // d 48+l15

        const fx4 z_ = (fx4){0.f, 0.f, 0.f, 0.f};
        fx4 s0 = __builtin_amdgcn_mfma_f32_16x16x32_bf16(ck0, aq0, z_, 0, 0, 0);
        s0     = __builtin_amdgcn_mfma_f32_16x16x32_bf16(ck1, aq1, s0, 0, 0, 0);
        fx4 s1 = __builtin_amdgcn_mfma_f32_16x16x32_bf16(ck2, aq0, z_, 0, 0, 0);
        s1     = __builtin_amdgcn_mfma_f32_16x16x32_bf16(ck3, aq1, s1, 0, 0, 0);
        s0[0] = __expf(s0[0] * 0.125f); s0[1] = __expf(s0[1] * 0.125f);
        s0[2] = __expf(s0[2] * 0.125f); s0[3] = __expf(s0[3] * 0.125f);
        s1[0] = __expf(s1[0] * 0.125f); s1[1] = __expf(s1[1] * 0.125f);
        s1[2] = __expf(s1[2] * 0.125f); s1[3] = __expf(s1[3] * 0.125f);
        lsum += s0[0] + s0[1] + s0[2] + s0[3];
        lsum += s1[0] + s1[1] + s1[2] + s1[3];
        uint2v w1_ = (uint2v){packbf(s0[0], s0[1]), packbf(s0[2], s0[3])};
        uint2v w2_ = (uint2v){packbf(s1[0], s1[1]), packbf(s1[2], s1[3])};
        *(uint2v*)(pw + l15 * 16 + wcol)       = w1_;   // pairs t=2q,2q+1
        *(uint2v*)(pw + l15 * 16 + (wcol ^ 8)) = w2_;   // pairs t=8+2q,8+2q+1
        short8 bp = *(const short8*)(pw + l15 * 16 + rcol);  // keys 8*quad..+7
        od0 = __builtin_amdgcn_mfma_f32_16x16x32_bf16(cv0, bp, od0, 0, 0, 0);
        od1 = __builtin_amdgcn_mfma_f32_16x16x32_bf16(cv1, bp, od1, 0, 0, 0);
        od2 = __builtin_amdgcn_mfma_f32_16x16x32_bf16(cv2, bp, od2, 0, 0, 0);
        od3 = __builtin_amdgcn_mfma_f32_16x16x32_bf16(cv3, bp, od3, 0, 0, 0);

        // ---- land next tile into the other buffer, then sync ----
        *(uint4v*)&kbuf[cur ^ 1][ew] = kr;
        *(uint4v*)&vbuf[cur ^ 1][ew] = vr;
        __syncthreads();
    }

    // per-q partial l (sum over quads); write UNNORMALIZED partials
    lsum += __shfl_xor(lsum, 16);
    lsum += __shfl_xor(lsum, 32);
    const size_t grow = (size_t)(b * NN) + qrow + l15;
    float* obase = ((kh == 0) ? Od0 : Od1) + grow * DD + h * DHH;
    *(fx4*)(obase + 0 * 16 + 4 * quad) = od0;
    *(fx4*)(obase + 1 * 16 + 4 * quad) = od1;
    *(fx4*)(obase + 2 * 16 + 4 * quad) = od2;
    *(fx4*)(obase + 3 * 16 + 4 * quad) = od3;
    if (quad == 0) Lp[(size_t)kh * 32768 + grow * 4 + h] = lsum;
}

// merge kh partials + residual + LayerNorm: Y = LN((od0+od1)/l + Qp)*g+be.
// In-place safe: reads Od1 row then writes Y to the same row (Y aliases Od1).
__global__ __launch_bounds__(64) void ln_rows(
        const float* __restrict__ Od0, const float* __restrict__ Od1,
        const float* __restrict__ Lp, const unsigned short* __restrict__ Qp,
        const float* __restrict__ g, const float* __restrict__ be,
        float* __restrict__ Y) {
    const int lane = threadIdx.x;
    const size_t row = blockIdx.x;
    const int h = lane >> 4;                       // 4 heads x 16 lanes
    fx4 m0 = ((const fx4*)(Od0 + row * DD))[lane];
    fx4 m1 = ((const fx4*)(Od1 + row * DD))[lane];
    const float inv = 1.0f / (Lp[row * 4 + h] + Lp[32768 + row * 4 + h]);
    shortx4 qv = ((const shortx4*)(Qp + row * DD))[lane];
    fx4 v;
#pragma unroll
    for (int i = 0; i < 4; ++i)
        v[i] = (m0[i] + m1[i]) * inv + bf2f((unsigned short)qv[i]);
    float s1 = v[0]+v[1]+v[2]+v[3];
    float s2 = v[0]*v[0]+v[1]*v[1]+v[2]*v[2]+v[3]*v[3];
#pragma unroll
    for (int off = 32; off >= 1; off >>= 1) {
        s1 += __shfl_xor(s1, off); s2 += __shfl_xor(s2, off);
    }
    float mean = s1 * (1.0f/256.0f);
    float var  = s2 * (1.0f/256.0f) - mean * mean;
    float rstd = rsqrtf(var + 1e-5f);
    fx4 gv = ((const fx4*)g)[lane];
    fx4 ev = ((const fx4*)be)[lane];
    fx4 o;
#pragma unroll
    for (int i = 0; i < 4; ++i) o[i] = (v[i]-mean)*rstd*gv[i] + ev[i];
    ((fx4*)(Y + row * DD))[lane] = o;
}

extern "C" void kernel_launch(void* const* d_in, const int* in_sizes, int n_in,
                              void* d_out, int out_size, void* d_ws, size_t ws_size,
                              hipStream_t stream) {
    (void)in_sizes; (void)n_in; (void)out_size; (void)ws_size;
    const float* Q     = (const float*)d_in[0];
    const float* K     = (const float*)d_in[1];
    const float* Wq    = (const float*)d_in[2];
    const float* bq    = (const float*)d_in[3];
    const float* Wk    = (const float*)d_in[4];
    const float* bk    = (const float*)d_in[5];
    const float* Wv    = (const float*)d_in[6];
    const float* bv    = (const float*)d_in[7];
    const float* W1    = (const float*)d_in[8];
    const float* b1    = (const float*)d_in[9];
    const float* W2    = (const float*)d_in[10];
    const float* b2    = (const float*)d_in[11];
    const float* g0    = (const float*)d_in[12];
    const float* beta0 = (const float*)d_in[13];
    const float* g1    = (const float*)d_in[14];
    const float* beta1 = (const float*)d_in[15];

    // Workspace: [0,4)Mi Qp bf16 (later H1 bf16); [4,8)Mi Kp (dead after
    // kt_prep -> reused for Lp partials, 256KB); [8,12)Mi Vp (reused as KT);
    // [12,16)Mi VT2; [16,24)Mi Od0 f32; [24,32)Mi Od1 f32 (ln_rows writes O
    // in-place over Od1); [32Mi,+640K) WT x5
    char* ws = (char*)d_ws;
    unsigned short* Qp  = (unsigned short*)(ws);
    unsigned short* Kp  = (unsigned short*)(ws + (4u  << 20));
    unsigned short* Vp  = (unsigned short*)(ws + (8u  << 20));
    unsigned short* KT  = Vp;                       // overlays Vp (dead after vt_prep)
    unsigned short* VT2 = (unsigned short*)(ws + (12u << 20));
    float*          Od0 = (float*)(ws + (16u << 20));
    float*          Od1 = (float*)(ws + (24u << 20));
    float*          O   = Od1;                      // ln_rows output, in-place
    float*          Lp  = (float*)(ws + (4u << 20));  // overlays Kp (dead)
    unsigned short* WT5 = (unsigned short*)(ws + (32u << 20));
    unsigned short* H1  = Qp;
    float*          out = (float*)d_out;

    const unsigned short* WT1 = WT5 + 3 * 65536;
    const unsigned short* WT2 = WT5 + 4 * 65536;

    const int M = BB * NN;                        // 8192 rows

    wt_prep<<<dim3(4, 4, 5), 256, 0, stream>>>(Wq, Wk, Wv, W1, W2, WT5);
    qkv_mfma<<<dim3(M / 16, 3), 256, 0, stream>>>(Q, K, WT5, bq, bk, bv, Qp, Kp, Vp);
    vt_prep<<<dim3(128, 4), 256, 0, stream>>>(Vp, VT2);
    kt_prep<<<1024, 256, 0, stream>>>(Kp, KT);    // overwrites Vp slot (Vp dead)
    attn_mfma<<<1024, 256, 0, stream>>>(Qp, KT, VT2, Od0, Od1, Lp);
    ln_rows<<<M, 64, 0, stream>>>(Od0, Od1, Lp, Qp, g0, beta0, O);
    ffn1_mfma<<<M / 16, 256, 0, stream>>>(O, WT1, b1, H1);
    gemm_ffn2_ln<<<M / 16, 512, 0, stream>>>(H1, WT2, b2, O, g1, beta1, out);
}

// Round 9
// 177.221 us; speedup vs baseline: 1.2230x; 1.0088x over previous
//
#include <hip/hip_runtime.h>

// MAB block, MFMA bf16, round 15: key-QUARTER split -> 8 blocks/CU (100% occ).
// r14 post-mortem: key-half split worked (attn ~51.5 -> <43.6us, total -14.3);
// attn no longer in top-5 (harness fill memsets at ~44us mask everything
// below). r14 block uses 20KB LDS -> HW admits 8 blocks/CU but grid 1024
// supplies only 4. r15: kq quarters (grid 2048, 16 tiles/block); LDS-stage
// traffic unchanged (268MB; each block stages only its quarter); 8 blocks/CU
// = 32 waves/CU. Merge: 4 unnormalized Od partials + Lp[4], ln_rows sums.
// LDS floor ~21us (1.47GB @ 69TB/s); predict attn ~26-31us.

typedef float fx4 __attribute__((ext_vector_type(4)));
typedef short short8 __attribute__((ext_vector_type(8)));
typedef short shortx4 __attribute__((ext_vector_type(4)));
typedef unsigned int uint2v __attribute__((ext_vector_type(2)));
typedef unsigned int uint4v __attribute__((ext_vector_type(4)));

#define BB  4
#define NN  2048
#define DD  256
#define HH  4
#define DHH 64

__device__ __forceinline__ float bf2f(unsigned short u) {
    union { unsigned int i; float f; } v; v.i = ((unsigned int)u) << 16; return v.f;
}
__device__ __forceinline__ unsigned short f2bf(float f) {
    union { float f; unsigned int i; } v; v.f = f;
    unsigned int r = v.i + 0x7FFF + ((v.i >> 16) & 1);   // RNE
    return (unsigned short)(r >> 16);
}
__device__ __forceinline__ unsigned int fbits(float f) {
    union { float f; unsigned int i; } v; v.f = f; return v.i;
}
__device__ __forceinline__ unsigned int packbf(float lo, float hi) {
    unsigned int a = fbits(lo), b = fbits(hi);
    a = (a + 0x7FFF + ((a >> 16) & 1)) >> 16;
    b = (b + 0x7FFF + ((b >> 16) & 1)) & 0xFFFF0000u;
    return a | b;
}

// ---------------------------------------------------------------------------
// Weight prep: WT[n][k] = bf16(W[k][n]) for the 5 weight matrices (256x256).
// ---------------------------------------------------------------------------
__global__ __launch_bounds__(256) void wt_prep(
        const float* __restrict__ w0, const float* __restrict__ w1,
        const float* __restrict__ w2, const float* __restrict__ w3,
        const float* __restrict__ w4, unsigned short* __restrict__ dst) {
    __shared__ unsigned short T[64 * 73];
    const int tid = threadIdx.x;
    const int z = blockIdx.z;
    const float* W = (z == 0) ? w0 : (z == 1) ? w1 : (z == 2) ? w2 : (z == 3) ? w3 : w4;
    unsigned short* WT = dst + z * 65536;
    const int nb = blockIdx.x * 64, kb = blockIdx.y * 64;
    {
        int kl = tid >> 2, c0 = (tid & 3) * 16;
        const float* src = W + (size_t)(kb + kl) * DD + nb + c0;
#pragma unroll
        for (int i = 0; i < 16; ++i) T[kl * 73 + c0 + i] = f2bf(src[i]);
    }
    __syncthreads();
    {
        int nl = tid >> 2, k0 = (tid & 3) * 16;
        short8 o0, o1;
#pragma unroll
        for (int i = 0; i < 8; ++i) {
            o0[i] = (short)T[(k0 + i) * 73 + nl];
            o1[i] = (short)T[(k0 + 8 + i) * 73 + nl];
        }
        short8* d = (short8*)(WT + (size_t)(nb + nl) * DD + kb + k0);
        d[0] = o0; d[1] = o1;
    }
}

// ---------------------------------------------------------------------------
// V tile-transpose: VT2[bh][tile][d64][key32] <- Vp[b*2048+key][h*64+d].
// grid(128,4): b = bx>>5, keyb = (bx&31)*64 (2 tiles), hb = by.
// ---------------------------------------------------------------------------
__global__ __launch_bounds__(256) void vt_prep(
        const unsigned short* __restrict__ Vp, unsigned short* __restrict__ VT2) {
    __shared__ unsigned short T[64 * 73];
    const int tid = threadIdx.x;
    const int hb = blockIdx.y;
    const int b = blockIdx.x >> 5;
    const int keyb = (blockIdx.x & 31) * 64;
    const int bh = b * HH + hb;
    {
        int kl = tid >> 2, c0 = (tid & 3) * 16;
        const short8* src = (const short8*)(Vp + (size_t)(b * NN + keyb + kl) * DD + hb * DHH + c0);
        short8 v0 = src[0], v1 = src[1];
#pragma unroll
        for (int i = 0; i < 8; ++i) {
            T[kl * 73 + c0 + i]     = (unsigned short)v0[i];
            T[kl * 73 + c0 + 8 + i] = (unsigned short)v1[i];
        }
    }
    __syncthreads();
    {
        int dl = tid >> 2, k0 = (tid & 3) * 16;          // d row, key chunk (16)
        short8 o0, o1;
#pragma unroll
        for (int i = 0; i < 8; ++i) {
            o0[i] = (short)T[(k0 + i) * 73 + dl];
            o1[i] = (short)T[(k0 + 8 + i) * 73 + dl];
        }
        const int gkey = keyb + k0;                       // multiple of 16
        const int tl = gkey >> 5;                         // tile index
        const int kin = gkey & 31;                        // 0 or 16
        short8* d = (short8*)(VT2 + ((size_t)(bh * 64 + tl) * 64 + dl) * 32 + kin);
        d[0] = o0; d[1] = o1;
    }
}

// ---------------------------------------------------------------------------
// K tile-permute: KT[bh][tile][dhalf][key32][d32] <- Kp[b*2048+key][h*64+d].
// Pure 16B-chunk permutation; grid 1024 = bh*64 + tile, 256 threads.
// ---------------------------------------------------------------------------
__global__ __launch_bounds__(256) void kt_prep(
        const unsigned short* __restrict__ Kp, unsigned short* __restrict__ KT) {
    const int bh = blockIdx.x >> 6;
    const int tl = blockIdx.x & 63;
    const int b = bh >> 2, h = bh & 3;
    const int tid = threadIdx.x;
    const int key = tid >> 3, p = tid & 7;
    short8 v = *(const short8*)(Kp + (size_t)(b * NN + tl * 32 + key) * DD + h * DHH + p * 8);
    unsigned short* dst = KT + (size_t)(bh * 64 + tl) * 2048
                        + (p >> 2) * 1024 + key * 32 + (p & 3) * 8;
    *(short8*)dst = v;
}

// ---------------------------------------------------------------------------
// 32-row GEMM body: C[r0..r0+32, c-half] = A @ W + bias. 4 waves, wave =
// 32 rows x 32 cols. W-frags hoisted. AIN: 0 fp32 A, 1 bf16 A.
// EP: 0 bias->bf16, 1 relu->bf16.
// ---------------------------------------------------------------------------
template<int AIN, int EP>
__device__ __forceinline__ void gemm32_body(
        const void* __restrict__ Ain, const unsigned short* __restrict__ WT,
        const float* __restrict__ bias, void* __restrict__ Cout, int bx) {
    __shared__ unsigned short As[32 * 264];
    const int tid = threadIdx.x;
    const int lane = tid & 63, w = tid >> 6;
    const int l15 = lane & 15, quad = lane >> 4;
    const int r0 = (bx >> 1) * 32;
    const int c0w = (bx & 1) * 128 + w * 32;
    short8 wf[8][2];
#pragma unroll
    for (int kc = 0; kc < 8; ++kc)
#pragma unroll
        for (int dt = 0; dt < 2; ++dt)
            wf[kc][dt] = *(const short8*)(WT + (size_t)(c0w + dt * 16 + l15) * DD + kc * 32 + 8 * quad);
    float bv[2];
#pragma unroll
    for (int dt = 0; dt < 2; ++dt) bv[dt] = bias[c0w + dt * 16 + l15];
    {   // stage A tile (32 x 256) as bf16; thread: 32 elems
        int row = tid >> 3, c0 = (tid & 7) * 32;
        short8 o[4];
        if (AIN == 0) {
            const fx4* s4 = (const fx4*)((const float*)Ain + (size_t)(r0 + row) * DD + c0);
#pragma unroll
            for (int j = 0; j < 4; ++j) {
                fx4 v0 = s4[2 * j], v1 = s4[2 * j + 1];
#pragma unroll
                for (int i = 0; i < 4; ++i) {
                    o[j][i]     = (short)f2bf(v0[i]);
                    o[j][i + 4] = (short)f2bf(v1[i]);
                }
            }
        } else {
            const short8* s8 = (const short8*)((const unsigned short*)Ain + (size_t)(r0 + row) * DD + c0);
#pragma unroll
            for (int j = 0; j < 4; ++j) o[j] = s8[j];
        }
        short8* d = (short8*)(As + row * 264 + c0);
#pragma unroll
        for (int j = 0; j < 4; ++j) d[j] = o[j];
    }
    __syncthreads();
    fx4 acc[2][2];
#pragma unroll
    for (int mt = 0; mt < 2; ++mt)
#pragma unroll
        for (int dt = 0; dt < 2; ++dt) acc[mt][dt] = (fx4){0.f, 0.f, 0.f, 0.f};
#pragma unroll
    for (int kc = 0; kc < 8; ++kc) {
        short8 a0 = *(const short8*)(As + l15 * 264 + kc * 32 + 8 * quad);
        short8 a1 = *(const short8*)(As + (16 + l15) * 264 + kc * 32 + 8 * quad);
#pragma unroll
        for (int dt = 0; dt < 2; ++dt) {
            acc[0][dt] = __builtin_amdgcn_mfma_f32_16x16x32_bf16(a0, wf[kc][dt], acc[0][dt], 0, 0, 0);
            acc[1][dt] = __builtin_amdgcn_mfma_f32_16x16x32_bf16(a1, wf[kc][dt], acc[1][dt], 0, 0, 0);
        }
    }
#pragma unroll
    for (int mt = 0; mt < 2; ++mt)
#pragma unroll
        for (int r = 0; r < 4; ++r) {
            const size_t grow = r0 + mt * 16 + 4 * quad + r;
#pragma unroll
            for (int dt = 0; dt < 2; ++dt) {
                float v = acc[mt][dt][r] + bv[dt];
                if (EP == 1) v = fmaxf(v, 0.0f);
                ((unsigned short*)Cout)[grow * DD + c0w + dt * 16 + l15] = f2bf(v);
            }
        }
}

// Fused QKV projections: grid (512, 3); y selects {Q->Qp, K->Kp, K->Vp}.
__global__ __launch_bounds__(256, 4) void qkv_mfma(
        const float* __restrict__ Q, const float* __restrict__ K,
        const unsigned short* __restrict__ WT5,
        const float* __restrict__ bq, const float* __restrict__ bk,
        const float* __restrict__ bv,
        unsigned short* __restrict__ Qp, unsigned short* __restrict__ Kp,
        unsigned short* __restrict__ Vp) {
    const int z = blockIdx.y;
    const float* A = (z == 0) ? Q : K;
    const float* bias = (z == 0) ? bq : (z == 1) ? bk : bv;
    unsigned short* C = (z == 0) ? Qp : (z == 1) ? Kp : Vp;
    gemm32_body<0, 0>(A, WT5 + z * 65536, bias, C, blockIdx.x);
}

// FFN1: H1 = relu(O @ W1 + b1), O fp32.
__global__ __launch_bounds__(256, 4) void ffn1_mfma(
        const float* __restrict__ O, const unsigned short* __restrict__ WT1,
        const float* __restrict__ b1, unsigned short* __restrict__ H1) {
    gemm32_body<0, 1>(O, WT1, b1, H1, blockIdx.x);
}

// ---------------------------------------------------------------------------
// FFN2 + residual + LayerNorm fused: out = LN(R + A@W2 + b2), fp32 out.
// Block = 16 rows x 256 cols, 8 waves (wave = 16x32), W-frags hoisted.
// ---------------------------------------------------------------------------
__global__ __launch_bounds__(512, 4) void gemm_ffn2_ln(
        const unsigned short* __restrict__ Ain, const unsigned short* __restrict__ WT,
        const float* __restrict__ bias, const float* __restrict__ R,
        const float* __restrict__ g, const float* __restrict__ be,
        float* __restrict__ out) {
    __shared__ unsigned short As[16 * 264];
    __shared__ float lnb[2][8][16];
    const int tid = threadIdx.x;
    const int lane = tid & 63, w = tid >> 6;          // w in 0..7
    const int l15 = lane & 15, quad = lane >> 4;
    const int r0 = blockIdx.x * 16;
    const int c0w = w * 32;
    short8 wf[8][2];
#pragma unroll
    for (int kc = 0; kc < 8; ++kc)
#pragma unroll
        for (int dt = 0; dt < 2; ++dt)
            wf[kc][dt] = *(const short8*)(WT + (size_t)(c0w + dt * 16 + l15) * DD + kc * 32 + 8 * quad);
    float bv[2], gv[2], ev[2];
#pragma unroll
    for (int dt = 0; dt < 2; ++dt) {
        int col = c0w + dt * 16 + l15;
        bv[dt] = bias[col]; gv[dt] = g[col]; ev[dt] = be[col];
    }
    {   // stage A: 512 threads x 16B
        int row = tid >> 5, c0 = (tid & 31) * 8;
        *(short8*)(As + row * 264 + c0) = *(const short8*)(Ain + (size_t)(r0 + row) * DD + c0);
    }
    __syncthreads();
    fx4 acc[2];
#pragma unroll
    for (int i = 0; i < 2; ++i) acc[i] = (fx4){0.f, 0.f, 0.f, 0.f};
#pragma unroll
    for (int kc = 0; kc < 8; ++kc) {
        short8 a = *(const short8*)(As + l15 * 264 + kc * 32 + 8 * quad);
#pragma unroll
        for (int dt = 0; dt < 2; ++dt)
            acc[dt] = __builtin_amdgcn_mfma_f32_16x16x32_bf16(a, wf[kc][dt], acc[dt], 0, 0, 0);
    }
    float v[4][2], p1[4], p2[4];
#pragma unroll
    for (int r = 0; r < 4; ++r) {
        p1[r] = 0.f; p2[r] = 0.f;
        const size_t grow = r0 + 4 * quad + r;
#pragma unroll
        for (int dt = 0; dt < 2; ++dt) {
            float x = acc[dt][r] + bv[dt] + R[grow * DD + c0w + dt * 16 + l15];
            v[r][dt] = x; p1[r] += x; p2[r] += x * x;
        }
    }
#pragma unroll
    for (int r = 0; r < 4; ++r) {
#pragma unroll
        for (int off = 1; off <= 8; off <<= 1) {
            p1[r] += __shfl_xor(p1[r], off);
            p2[r] += __shfl_xor(p2[r], off);
        }
    }
    if (l15 == 0) {
#pragma unroll
        for (int r = 0; r < 4; ++r) {
            lnb[0][w][4 * quad + r] = p1[r];
            lnb[1][w][4 * quad + r] = p2[r];
        }
    }
    __syncthreads();
#pragma unroll
    for (int r = 0; r < 4; ++r) {
        const int row = 4 * quad + r;
        float s1 = 0.f, s2 = 0.f;
#pragma unroll
        for (int ww = 0; ww < 8; ++ww) { s1 += lnb[0][ww][row]; s2 += lnb[1][ww][row]; }
        float mean = s1 * (1.0f / 256.0f);
        float var  = s2 * (1.0f / 256.0f) - mean * mean;
        float rstd = rsqrtf(var + 1e-5f);
        const size_t grow = r0 + row;
#pragma unroll
        for (int dt = 0; dt < 2; ++dt)
            out[grow * DD + c0w + dt * 16 + l15] = (v[r][dt] - mean) * rstd * gv[dt] + ev[dt];
    }
}

// ---------------------------------------------------------------------------
// Flash attention, O^T form, no-max softmax. r15: key-QUARTER split.
// Block = 64 q-rows x 512 keys (kq quarter), grid 2048 -> 8 blocks/CU
// (LDS 20KB x 8 = 160KB, VGPR 32 -> 32 waves/CU = 100%).
// 4 waves = 4 q-subtiles; each wave sweeps its quarter's 16 key-tiles from
// double-buffered, XOR-swizzled LDS (one barrier/tile). Outputs UNNORMALIZED
// partial O^T to Od[kq] and per-(row,head) partial l to Lp[kq]; the merge
// (sum, 1/l, +Qp residual) happens in ln_rows.
// ---------------------------------------------------------------------------
__global__ __launch_bounds__(256, 2) void attn_mfma(
        const unsigned short* __restrict__ Qp, const unsigned short* __restrict__ KT,
        const unsigned short* __restrict__ VT2, float* __restrict__ Od,
        float* __restrict__ Lp) {
    __shared__ unsigned short kbuf[2][2048];  // K tile double buffer (4KB ea)
    __shared__ unsigned short vbuf[2][2048];  // V tile double buffer
    __shared__ unsigned int pbuf[4][256];     // per-wave P exchange, pitch 16 dw
    const int tid = threadIdx.x;
    const int lane = tid & 63, w = tid >> 6;  // w = q-subtile
    const int l15 = lane & 15, quad = lane >> 4;
    const int gb = blockIdx.x;                // 0..2047
    const int bh = ((gb & 7) << 1) | ((gb >> 10) & 1);  // XCD-locality swizzle
    const int qc = (gb >> 3) & 31;
    const int kq = (gb >> 8) & 3;                       // key quarter
    const int h  = bh & 3;
    const int b  = bh >> 2;
    const int qrow = qc * 64 + w * 16;
    const int sw = 4 * ((l15 >> 1) & 3);                // pbuf bank swizzle

    short8 aq0, aq1;
    {
        const unsigned short* qptr = Qp + ((size_t)(b * NN + qrow + l15) * DD + h * DHH + 8 * quad);
        aq0 = *(const short8*)qptr;
        aq1 = *(const short8*)(qptr + 32);
    }
    fx4 od0 = (fx4){0.f, 0.f, 0.f, 0.f};
    fx4 od1 = (fx4){0.f, 0.f, 0.f, 0.f};
    fx4 od2 = (fx4){0.f, 0.f, 0.f, 0.f};
    fx4 od3 = (fx4){0.f, 0.f, 0.f, 0.f};
    float lsum = 0.0f;

    unsigned int* pw = &pbuf[w][0];
    const int wcol = (2 * quad) ^ sw;         // write cols (pairs t=2q,2q+1 / +8)
    const int rcol = (4 * quad) ^ sw;         // read col group (t=4Q..4Q+3)
    const unsigned short* ktb = KT  + (size_t)(bh * 64 + kq * 16) * 2048 + tid * 8;
    const unsigned short* vtb = VT2 + (size_t)(bh * 64 + kq * 16) * 2048 + tid * 8;
    // K/V tile swizzle: element e -> e ^ (((e>>6)&3)<<3)  (byte[5:4]^=byte[8:7])
    const int ew = (tid * 8) ^ (((tid >> 3) & 3) << 3);          // stage-write dst
    const int fo = (l15 * 32 + 8 * quad) ^ (((l15 >> 1) & 3) << 3); // frag-read base

    // prologue: stage tile 0 into buffer 0
    {
        uint4v kr = *(const uint4v*)ktb;
        uint4v vr = *(const uint4v*)vtb;
        *(uint4v*)&kbuf[0][ew] = kr;
        *(uint4v*)&vbuf[0][ew] = vr;
    }
    __syncthreads();

    for (int t = 0; t < 16; ++t) {
        const int cur = t & 1;
        const int tn = (t < 15) ? t + 1 : 15;           // clamp (last redundant)
        // issue next-tile global loads FIRST (T14 async split: write after compute)
        uint4v kr = *(const uint4v*)(ktb + (size_t)tn * 2048);
        uint4v vr = *(const uint4v*)(vtb + (size_t)tn * 2048);

        // ---- compute tile t from LDS ----
        const unsigned short* kb = &kbuf[cur][fo];
        short8 ck0 = *(const short8*)(kb);          // keys l15,    d 8q..8q+7
        short8 ck1 = *(const short8*)(kb + 1024);   // keys l15,    d 32+8q..
        short8 ck2 = *(const short8*)(kb + 512);    // keys 16+l15, d 8q..
        short8 ck3 = *(const short8*)(kb + 1536);   // keys 16+l15, d 32+8q..
        const unsigned short* vb = &vbuf[cur][fo];
        short8 cv0 = *(const short8*)(vb);          // d l15,    keys 8q..8q+7
        short8 cv1 = *(const short8*)(vb + 512);    // d 16+l15
        short8 cv2 = *(const short8*)(vb + 1024);   // d 32+l15
        short8 cv3 = *(const short8*)(vb + 1536);   // d 48+l15

        const fx4 z_ = (fx4){0.f, 0.f, 0.f, 0.f};
        fx4 s0 = __builtin_amdgcn_mfma_f32_16x16x32_bf16(ck0, aq0, z_, 0, 0, 0);
        s0     = __builtin_amdgcn_mfma_f32_16x16x32_bf16(ck1, aq1, s0, 0, 0, 0);
        fx4 s1 = __builtin_amdgcn_mfma_f32_16x16x32_bf16(ck2, aq0, z_, 0, 0, 0);
        s1     = __builtin_amdgcn_mfma_f32_16x16x32_bf16(ck3, aq1, s1, 0, 0, 0);
        s0[0] = __expf(s0[0] * 0.125f); s0[1] = __expf(s0[1] * 0.125f);
        s0[2] = __expf(s0[2] * 0.125f); s0[3] = __expf(s0[3] * 0.125f);
        s1[0] = __expf(s1[0] * 0.125f); s1[1] = __expf(s1[1] * 0.125f);
        s1[2] = __expf(s1[2] * 0.125f); s1[3] = __expf(s1[3] * 0.125f);
        lsum += s0[0] + s0[1] + s0[2] + s0[3];
        lsum += s1[0] + s1[1] + s1[2] + s1[3];
        uint2v w1_ = (uint2v){packbf(s0[0], s0[1]), packbf(s0[2], s0[3])};
        uint2v w2_ = (uint2v){packbf(s1[0], s1[1]), packbf(s1[2], s1[3])};
        *(uint2v*)(pw + l15 * 16 + wcol)       = w1_;   // pairs t=2q,2q+1
        *(uint2v*)(pw + l15 * 16 + (wcol ^ 8)) = w2_;   // pairs t=8+2q,8+2q+1
        short8 bp = *(const short8*)(pw + l15 * 16 + rcol);  // keys 8*quad..+7
        od0 = __builtin_amdgcn_mfma_f32_16x16x32_bf16(cv0, bp, od0, 0, 0, 0);
        od1 = __builtin_amdgcn_mfma_f32_16x16x32_bf16(cv1, bp, od1, 0, 0, 0);
        od2 = __builtin_amdgcn_mfma_f32_16x16x32_bf16(cv2, bp, od2, 0, 0, 0);
        od3 = __builtin_amdgcn_mfma_f32_16x16x32_bf16(cv3, bp, od3, 0, 0, 0);

        // ---- land next tile into the other buffer, then sync ----
        *(uint4v*)&kbuf[cur ^ 1][ew] = kr;
        *(uint4v*)&vbuf[cur ^ 1][ew] = vr;
        __syncthreads();
    }

    // per-q partial l (sum over quads); write UNNORMALIZED partials
    lsum += __shfl_xor(lsum, 16);
    lsum += __shfl_xor(lsum, 32);
    const size_t grow = (size_t)(b * NN) + qrow + l15;
    float* obase = Od + (size_t)kq * 2097152 + grow * DD + h * DHH;
    *(fx4*)(obase + 0 * 16 + 4 * quad) = od0;
    *(fx4*)(obase + 1 * 16 + 4 * quad) = od1;
    *(fx4*)(obase + 2 * 16 + 4 * quad) = od2;
    *(fx4*)(obase + 3 * 16 + 4 * quad) = od3;
    if (quad == 0) Lp[(size_t)kq * 32768 + grow * 4 + h] = lsum;
}

// merge kq partials + residual + LayerNorm: Y = LN(sum(od)/sum(l) + Qp)*g+be.
__global__ __launch_bounds__(64) void ln_rows(
        const float* __restrict__ Od, const float* __restrict__ Lp,
        const unsigned short* __restrict__ Qp,
        const float* __restrict__ g, const float* __restrict__ be,
        float* __restrict__ Y) {
    const int lane = threadIdx.x;
    const size_t row = blockIdx.x;
    const int h = lane >> 4;                       // 4 heads x 16 lanes
    fx4 m0 = ((const fx4*)(Od + row * DD))[lane];
    fx4 m1 = ((const fx4*)(Od + 1 * 2097152 + row * DD))[lane];
    fx4 m2 = ((const fx4*)(Od + 2 * 2097152 + row * DD))[lane];
    fx4 m3 = ((const fx4*)(Od + 3 * 2097152 + row * DD))[lane];
    const float inv = 1.0f / (Lp[row * 4 + h] + Lp[32768 + row * 4 + h]
                            + Lp[65536 + row * 4 + h] + Lp[98304 + row * 4 + h]);
    shortx4 qv = ((const shortx4*)(Qp + row * DD))[lane];
    fx4 v;
#pragma unroll
    for (int i = 0; i < 4; ++i)
        v[i] = (m0[i] + m1[i] + m2[i] + m3[i]) * inv + bf2f((unsigned short)qv[i]);
    float s1 = v[0]+v[1]+v[2]+v[3];
    float s2 = v[0]*v[0]+v[1]*v[1]+v[2]*v[2]+v[3]*v[3];
#pragma unroll
    for (int off = 32; off >= 1; off >>= 1) {
        s1 += __shfl_xor(s1, off); s2 += __shfl_xor(s2, off);
    }
    float mean = s1 * (1.0f/256.0f);
    float var  = s2 * (1.0f/256.0f) - mean * mean;
    float rstd = rsqrtf(var + 1e-5f);
    fx4 gv = ((const fx4*)g)[lane];
    fx4 ev = ((const fx4*)be)[lane];
    fx4 o;
#pragma unroll
    for (int i = 0; i < 4; ++i) o[i] = (v[i]-mean)*rstd*gv[i] + ev[i];
    ((fx4*)(Y + row * DD))[lane] = o;
}

extern "C" void kernel_launch(void* const* d_in, const int* in_sizes, int n_in,
                              void* d_out, int out_size, void* d_ws, size_t ws_size,
                              hipStream_t stream) {
    (void)in_sizes; (void)n_in; (void)out_size; (void)ws_size;
    const float* Q     = (const float*)d_in[0];
    const float* K     = (const float*)d_in[1];
    const float* Wq    = (const float*)d_in[2];
    const float* bq    = (const float*)d_in[3];
    const float* Wk    = (const float*)d_in[4];
    const float* bk    = (const float*)d_in[5];
    const float* Wv    = (const float*)d_in[6];
    const float* bv    = (const float*)d_in[7];
    const float* W1    = (const float*)d_in[8];
    const float* b1    = (const float*)d_in[9];
    const float* W2    = (const float*)d_in[10];
    const float* b2    = (const float*)d_in[11];
    const float* g0    = (const float*)d_in[12];
    const float* beta0 = (const float*)d_in[13];
    const float* g1    = (const float*)d_in[14];
    const float* beta1 = (const float*)d_in[15];

    // Workspace: [0,4)Mi Qp bf16 (later H1 bf16); [4,8)Mi Kp (dead after
    // kt_prep -> Lp partials, 512KB); [8,12)Mi Vp (reused as KT);
    // [12,16)Mi VT2; [16,48)Mi Od[4] f32 partials; [48,56)Mi O f32;
    // [56Mi,+640K) WT x5
    char* ws = (char*)d_ws;
    unsigned short* Qp  = (unsigned short*)(ws);
    unsigned short* Kp  = (unsigned short*)(ws + (4u  << 20));
    unsigned short* Vp  = (unsigned short*)(ws + (8u  << 20));
    unsigned short* KT  = Vp;                       // overlays Vp (dead after vt_prep)
    unsigned short* VT2 = (unsigned short*)(ws + (12u << 20));
    float*          Od  = (float*)(ws + (16u << 20));   // 4 x 8MB partials
    float*          O   = (float*)(ws + (48u << 20));
    float*          Lp  = (float*)(ws + (4u << 20));    // overlays Kp (dead)
    unsigned short* WT5 = (unsigned short*)(ws + (56u << 20));
    unsigned short* H1  = Qp;
    float*          out = (float*)d_out;

    const unsigned short* WT1 = WT5 + 3 * 65536;
    const unsigned short* WT2 = WT5 + 4 * 65536;

    const int M = BB * NN;                        // 8192 rows

    wt_prep<<<dim3(4, 4, 5), 256, 0, stream>>>(Wq, Wk, Wv, W1, W2, WT5);
    qkv_mfma<<<dim3(M / 16, 3), 256, 0, stream>>>(Q, K, WT5, bq, bk, bv, Qp, Kp, Vp);
    vt_prep<<<dim3(128, 4), 256, 0, stream>>>(Vp, VT2);
    kt_prep<<<1024, 256, 0, stream>>>(Kp, KT);    // overwrites Vp slot (Vp dead)
    attn_mfma<<<2048, 256, 0, stream>>>(Qp, KT, VT2, Od, Lp);
    ln_rows<<<M, 64, 0, stream>>>(Od, Lp, Qp, g0, beta0, O);
    ffn1_mfma<<<M / 16, 256, 0, stream>>>(O, WT1, b1, H1);
    gemm_ffn2_ln<<<M / 16, 512, 0, stream>>>(H1, WT2, b2, O, g1, beta1, out);
}